// Round 7
// baseline (345.885 us; speedup 1.0000x reference)
//
#include <hip/hip_runtime.h>
#include <math.h>

constexpr int Nn  = 65536;    // nodes
constexpr int Ne  = 1048576;  // edges
constexpr int Bg  = 256;      // graphs
constexpr int DIN = 32;
constexpr int D   = 64;

constexpr int NB   = 256;     // dst buckets (dst>>8)
constexpr int BCAP = 6144;    // bucket stream capacity (mean 4096, +36 sigma)

typedef __attribute__((ext_vector_type(8))) short bf16x8;
typedef __attribute__((ext_vector_type(8))) unsigned short u16x8;
typedef __attribute__((ext_vector_type(4))) float f32x4;

__device__ __forceinline__ float sigf(float x) { return 1.0f / (1.0f + expf(-x)); }

// ---- bf16 split helpers (RNE) ----
__device__ __forceinline__ unsigned short bf16_rne(float f) {
  unsigned u = __float_as_uint(f);
  unsigned r = u + 0x7FFFu + ((u >> 16) & 1u);
  return (unsigned short)(r >> 16);
}
__device__ __forceinline__ float bf16_tof(unsigned short h) {
  return __uint_as_float(((unsigned)h) << 16);
}
__device__ __forceinline__ void split2(float f, unsigned short& hi, unsigned short& lo) {
  hi = bf16_rne(f);
  lo = bf16_rne(f - bf16_tof(hi));
}
__device__ __forceinline__ float recon(unsigned short hi, unsigned short lo) {
  return bf16_tof(hi) + bf16_tof(lo);
}

#define MFMA(a, b, c) __builtin_amdgcn_mfma_f32_16x16x32_bf16(a, b, c, 0, 0, 0)

// ---------------------------------------------------------------------------
// Prep.  GRU weights chunk-major (5 chunks x 12nt x 64lane x 8j / plane):
//   chunks 0,1 = Wfold = Wih[:, :64] @ W_conv   (fused conv-linear)
//   chunk  2   = Wih[:, 64:96]  (x part)
//   chunks 3,4 = Whh
// Also: W_mlp pack, LSTM/W1 transposes, graphptr, rp[Nn], vfold.
// ---------------------------------------------------------------------------
__global__ void k_prepw(const float* __restrict__ W_mlp, const float* __restrict__ W_conv,
                        const float* __restrict__ gWih, const float* __restrict__ gWhh,
                        const float* __restrict__ b_conv,
                        const float* __restrict__ lW_ih, const float* __restrict__ lW_hh,
                        const float* __restrict__ W1,
                        unsigned short* __restrict__ mlp_h, unsigned short* __restrict__ mlp_l,
                        unsigned short* __restrict__ gw_h,  unsigned short* __restrict__ gw_l,
                        float* __restrict__ WihT, float* __restrict__ WhhT,
                        float* __restrict__ W1T, float* __restrict__ vfold,
                        const int* __restrict__ batch, int* __restrict__ gp,
                        int* __restrict__ rp) {
  int idx = blockIdx.x * 256 + threadIdx.x;
  if (idx < 30720) {  // GRU weights, chunk-major
    int c = idx / 6144, rem = idx % 6144;
    int nt = rem >> 9, lane = (rem >> 3) & 63, j = rem & 7;
    int n = nt * 16 + (lane & 15);
    int kk = c * 32 + (lane >> 4) * 8 + j;   // for c<3: k index into [S|x]
    float v;
    if (c < 2) {        // Wfold[n][kk] = sum_o Wih[n][o] * W_conv[o][kk]
      float s = 0.f;
      for (int o = 0; o < 64; ++o) s = fmaf(gWih[n * 96 + o], W_conv[o * 64 + kk], s);
      v = s;
    } else if (c == 2) {
      v = gWih[n * 96 + kk];                 // kk in 64..95 (x columns)
    } else {
      v = gWhh[n * 64 + (c - 3) * 32 + (lane >> 4) * 8 + j];
    }
    unsigned short hi, lo; split2(v, hi, lo);
    gw_h[idx] = hi; gw_l[idx] = lo;
    return;
  }
  if (idx < 32768) {  // W_mlp (KS=1)
    int lp = idx - 30720;
    int nt = lp >> 9, lane = (lp >> 3) & 63, j = lp & 7;
    int n = nt * 16 + (lane & 15);
    unsigned short hi, lo;
    split2(W_mlp[n * 32 + (lane >> 4) * 8 + j], hi, lo);
    mlp_h[lp] = hi; mlp_l[lp] = lo;
    return;
  }
  int t = idx - 32768;
  if (t < 32768) {                 // lstm W_ih [256][128] -> WihT [128][256]
    int row = t / 128, k = t % 128;
    WihT[k * 256 + row] = lW_ih[t];
  } else if (t < 49152) {          // lstm W_hh [256][64] -> WhhT [64][256]
    int j = t - 32768;
    int row = j / 64, k = j % 64;
    WhhT[k * 256 + row] = lW_hh[j];
  } else if (t < 57344) {          // W1 [64][128] -> W1T [128][64]
    int j = t - 49152;
    int row = j / 128, k = j % 128;
    W1T[k * 64 + row] = W1[j];
  } else if (t < 57344 + Bg + 1) { // graphptr + rp[Nn]
    int g = t - 57344;
    if (g == 0) rp[Nn] = Ne;
    int lo = 0, hi = Nn;
    while (lo < hi) {
      int mid = (lo + hi) >> 1;
      if (batch[mid] < g) lo = mid + 1; else hi = mid;
    }
    gp[g] = lo;
  } else if (t < 57344 + 257 + 192) { // vfold[192]
    int g = t - 57344 - 257;
    float s = 0.f;
    for (int o = 0; o < 64; ++o) s = fmaf(gWih[g * 96 + o], b_conv[o], s);
    vfold[g] = s;
  }
}

// ---------------------------------------------------------------------------
// conv1: h = x @ W_mlp^T + b  (K=32, N=64). Splits x in-kernel; also fills
// inp96 x-columns (64..95).  h stored as planes only.
// ---------------------------------------------------------------------------
__global__ __launch_bounds__(256) void k_conv1(const float* __restrict__ x,
                                               const unsigned short* __restrict__ Wh,
                                               const unsigned short* __restrict__ Wl,
                                               const float* __restrict__ bias,
                                               unsigned short* __restrict__ hph,
                                               unsigned short* __restrict__ hpl,
                                               unsigned short* __restrict__ Aih,
                                               unsigned short* __restrict__ Ail) {
  int wave = threadIdx.x >> 6, lane = threadIdx.x & 63;
  int quad = lane >> 4;
  int n0w = blockIdx.x * 64 + wave * 16;
  int rowA = n0w + (lane & 15);
  const float4* xp = (const float4*)&x[(size_t)rowA * 32 + quad * 8];
  float4 xa = xp[0], xb = xp[1];
  float xv[8] = {xa.x, xa.y, xa.z, xa.w, xb.x, xb.y, xb.z, xb.w};
  bf16x8 ah, al;
#pragma unroll
  for (int j = 0; j < 8; ++j) {
    unsigned short hi, lo; split2(xv[j], hi, lo);
    ah[j] = (short)hi; al[j] = (short)lo;
  }
  *(bf16x8*)&Aih[(size_t)rowA * 96 + 64 + quad * 8] = ah;
  *(bf16x8*)&Ail[(size_t)rowA * 96 + 64 + quad * 8] = al;

  f32x4 acc[4] = {};
#pragma unroll
  for (int nt = 0; nt < 4; ++nt) {
    bf16x8 bh = *(const bf16x8*)&Wh[(nt * 64 + lane) * 8];
    bf16x8 bl = *(const bf16x8*)&Wl[(nt * 64 + lane) * 8];
    acc[nt] = MFMA(ah, bh, acc[nt]);
    acc[nt] = MFMA(ah, bl, acc[nt]);
    acc[nt] = MFMA(al, bh, acc[nt]);
  }
  int col0 = lane & 15;
#pragma unroll
  for (int nt = 0; nt < 4; ++nt) {
    float bv = bias[nt * 16 + col0];
#pragma unroll
    for (int r = 0; r < 4; ++r) {
      int node = n0w + quad * 4 + r;
      float v = acc[nt][r] + bv;
      size_t o = (size_t)node * 64 + nt * 16 + col0;
      unsigned short hi, lo; split2(v, hi, lo);
      hph[o] = hi; hpl[o] = lo;
    }
  }
}

// ---------------------------------------------------------------------------
// Aggregate v4: one wave per node; lane l owns edge-slot (l>>3) and columns
// (l&7)*8..+7.  Each load instruction is u16x8 (16 B/lane, 1 KB/wave) and
// covers 8 EDGES at once.  Edge-slot partials combined by fixed-order
// xor-shuffle tree.
// ---------------------------------------------------------------------------
__global__ __launch_bounds__(256) void k_aggr(const unsigned short* __restrict__ Hh,
                                              const int* __restrict__ rp,
                                              const int* __restrict__ srcs,
                                              unsigned short* __restrict__ Sh,
                                              unsigned short* __restrict__ Sl) {
  int wave = threadIdx.x >> 6, lane = threadIdx.x & 63;
  int node = blockIdx.x * 4 + wave;
  int s = rp[node], e = rp[node + 1];
  int n = e - s;
  const int* sp = srcs + s;
  int col8 = (lane & 7) * 8;
  int eslot = lane >> 3;
  float acc8[8] = {};
  int k = 0;
  for (; k + 16 <= n; k += 16) {
    int sA = sp[k + eslot];
    int sB = sp[k + 8 + eslot];
    u16x8 a = *(const u16x8*)&Hh[(size_t)sA * 64 + col8];
    u16x8 b = *(const u16x8*)&Hh[(size_t)sB * 64 + col8];
#pragma unroll
    for (int j = 0; j < 8; ++j) acc8[j] += bf16_tof(a[j]);
#pragma unroll
    for (int j = 0; j < 8; ++j) acc8[j] += bf16_tof(b[j]);
  }
  for (; k < n; k += 8) {
    if (k + eslot < n) {
      int sA = sp[k + eslot];
      u16x8 a = *(const u16x8*)&Hh[(size_t)sA * 64 + col8];
#pragma unroll
      for (int j = 0; j < 8; ++j) acc8[j] += bf16_tof(a[j]);
    }
  }
  // combine the 8 edge-slot partials (fixed-order tree over lanes l^8,l^16,l^32)
#pragma unroll
  for (int m = 8; m <= 32; m <<= 1) {
#pragma unroll
    for (int j = 0; j < 8; ++j) acc8[j] += __shfl_xor(acc8[j], m);
  }
  if (lane < 8) {
    u16x8 hv, lv;
#pragma unroll
    for (int j = 0; j < 8; ++j) {
      unsigned short hi, lo; split2(acc8[j], hi, lo);
      hv[j] = hi; lv[j] = lo;
    }
    *(u16x8*)&Sh[(size_t)node * 64 + col8] = hv;
    *(u16x8*)&Sl[(size_t)node * 64 + col8] = lv;
  }
}

// ---------------------------------------------------------------------------
// Fused GRU v9: gather moved out to k_aggr; chunks 0,1 read the S planes
// (Sh/Sl) exactly like the Whh chunks read Hh/Hl.  Keeps the proven
// 5-chunk double-buffered-LDS K-loop and epilogue.
// ---------------------------------------------------------------------------
__global__ __launch_bounds__(256, 2) void k_gru(const unsigned short* __restrict__ Aih,
                                                const unsigned short* __restrict__ Ail,
                                                const unsigned short* __restrict__ Hh,
                                                const unsigned short* __restrict__ Hl,
                                                const unsigned short* __restrict__ Sh,
                                                const unsigned short* __restrict__ Sl,
                                                const unsigned short* __restrict__ gw_h,
                                                const unsigned short* __restrict__ gw_l,
                                                const float* __restrict__ b_ih,
                                                const float* __restrict__ b_hh,
                                                const float* __restrict__ vfold,
                                                const int* __restrict__ rp,
                                                unsigned short* __restrict__ nph,
                                                unsigned short* __restrict__ npl) {
  __shared__ unsigned short sW[2][12288];  // per buf: hi[0..6143] | lo[6144..]
  int tid = threadIdx.x;
  int wave = tid >> 6, lane = tid & 63;
  int quad = lane >> 4;
  int n0w = blockIdx.x * 128 + wave * 32;
  int rowA0 = n0w + (lane & 15);          // tile0 A-row; tile1 = +16

  f32x4 acc0[12] = {}, acc1[12] = {};     // gi r,z,n (gh r,z folded into 0..7)
  f32x4 aN0[4] = {}, aN1[4] = {};         // gh n-gate

  // prologue: weights chunk 0
  bf16x8 gvh[3], gvl[3];
#pragma unroll
  for (int j = 0; j < 3; ++j) {
    gvh[j] = *(const bf16x8*)&gw_h[(tid + j * 256) * 8];
    gvl[j] = *(const bf16x8*)&gw_l[(tid + j * 256) * 8];
  }
#pragma unroll
  for (int j = 0; j < 3; ++j) {
    *(bf16x8*)&sW[0][(tid + j * 256) * 8] = gvh[j];
    *(bf16x8*)&sW[0][6144 + (tid + j * 256) * 8] = gvl[j];
  }
  __syncthreads();

#pragma unroll
  for (int c = 0; c < 5; ++c) {
    const int buf = c & 1;
    if (c < 4) {  // prefetch chunk c+1 weights
#pragma unroll
      for (int j = 0; j < 3; ++j) {
        gvh[j] = *(const bf16x8*)&gw_h[(c + 1) * 6144 + (tid + j * 256) * 8];
        gvl[j] = *(const bf16x8*)&gw_l[(c + 1) * 6144 + (tid + j * 256) * 8];
      }
    }
    // A fragments
    bf16x8 a0h, a0l, a1h, a1l;
    if (c < 2) {            // aggregated S planes from k_aggr
      size_t b0 = (size_t)rowA0 * 64 + c * 32 + quad * 8;
      size_t b1 = (size_t)(rowA0 + 16) * 64 + c * 32 + quad * 8;
      a0h = *(const bf16x8*)&Sh[b0]; a0l = *(const bf16x8*)&Sl[b0];
      a1h = *(const bf16x8*)&Sh[b1]; a1l = *(const bf16x8*)&Sl[b1];
    } else if (c == 2) {    // x columns from conv1 prep
      size_t b0 = (size_t)rowA0 * 96 + 64 + quad * 8;
      size_t b1 = (size_t)(rowA0 + 16) * 96 + 64 + quad * 8;
      a0h = *(const bf16x8*)&Aih[b0]; a0l = *(const bf16x8*)&Ail[b0];
      a1h = *(const bf16x8*)&Aih[b1]; a1l = *(const bf16x8*)&Ail[b1];
    } else {                // h planes (Whh chunks)
      size_t b0 = (size_t)rowA0 * 64 + (c - 3) * 32 + quad * 8;
      size_t b1 = (size_t)(rowA0 + 16) * 64 + (c - 3) * 32 + quad * 8;
      a0h = *(const bf16x8*)&Hh[b0]; a0l = *(const bf16x8*)&Hl[b0];
      a1h = *(const bf16x8*)&Hh[b1]; a1l = *(const bf16x8*)&Hl[b1];
    }
    const unsigned short* sw = sW[buf];
#pragma unroll
    for (int nt = 0; nt < 12; ++nt) {
      bf16x8 bh = *(const bf16x8*)&sw[(nt * 64 + lane) * 8];
      bf16x8 bl = *(const bf16x8*)&sw[6144 + (nt * 64 + lane) * 8];
      if (c < 3 || nt < 8) {
        acc0[nt] = MFMA(a0h, bh, acc0[nt]);
        acc0[nt] = MFMA(a0h, bl, acc0[nt]);
        acc0[nt] = MFMA(a0l, bh, acc0[nt]);
        acc1[nt] = MFMA(a1h, bh, acc1[nt]);
        acc1[nt] = MFMA(a1h, bl, acc1[nt]);
        acc1[nt] = MFMA(a1l, bh, acc1[nt]);
      } else {
        aN0[nt - 8] = MFMA(a0h, bh, aN0[nt - 8]);
        aN0[nt - 8] = MFMA(a0h, bl, aN0[nt - 8]);
        aN0[nt - 8] = MFMA(a0l, bh, aN0[nt - 8]);
        aN1[nt - 8] = MFMA(a1h, bh, aN1[nt - 8]);
        aN1[nt - 8] = MFMA(a1h, bl, aN1[nt - 8]);
        aN1[nt - 8] = MFMA(a1l, bh, aN1[nt - 8]);
      }
    }
    if (c < 4) {
#pragma unroll
      for (int j = 0; j < 3; ++j) {
        *(bf16x8*)&sW[1 - buf][(tid + j * 256) * 8] = gvh[j];
        *(bf16x8*)&sW[1 - buf][6144 + (tid + j * 256) * 8] = gvl[j];
      }
    }
    __syncthreads();
  }

  // epilogue: GRU nonlinearity + deg*vfold (folded conv bias) + plane store
  int col0 = lane & 15;
#pragma unroll
  for (int tile = 0; tile < 2; ++tile) {
    int nb = n0w + tile * 16;
#pragma unroll
    for (int r = 0; r < 4; ++r) {
      int node = nb + quad * 4 + r;
      float degf = (float)(rp[node + 1] - rp[node]);
#pragma unroll
      for (int nt = 0; nt < 4; ++nt) {
        int g = nt * 16 + col0;
        size_t o = (size_t)node * 64 + g;
        float br  = b_ih[g] + b_hh[g] + degf * vfold[g];
        float bz  = b_ih[64 + g] + b_hh[64 + g] + degf * vfold[64 + g];
        float bin = b_ih[128 + g] + degf * vfold[128 + g];
        float bhn = b_hh[128 + g];
        float gr = tile ? acc1[nt][r]     : acc0[nt][r];
        float gz = tile ? acc1[nt + 4][r] : acc0[nt + 4][r];
        float gn = tile ? acc1[nt + 8][r] : acc0[nt + 8][r];
        float hn = tile ? aN1[nt][r]      : aN0[nt][r];
        float rr = sigf(gr + br);
        float zz = sigf(gz + bz);
        float nn = tanhf(gn + bin + rr * (hn + bhn));
        float h_old = recon(Hh[o], Hl[o]);
        float hv = (1.f - zz) * nn + zz * h_old;
        unsigned short hi, lo; split2(hv, hi, lo);
        nph[o] = hi; npl[o] = lo;
      }
    }
  }
}

// ---------------------------------------------------------------------------
// CSR build v3: two-level bucket sort by dst.
// ---------------------------------------------------------------------------
__global__ __launch_bounds__(256) void k_bucket(const int* __restrict__ eidx,
                                                int* __restrict__ gcur,     // [NB*16]
                                                int* __restrict__ payload) {// [NB*BCAP]
  __shared__ int lcnt[NB];
  __shared__ int lcur[NB];
  int t = threadIdx.x;
  int e0 = blockIdx.x * 4096;
  lcnt[t] = 0;
  __syncthreads();
  int ds[16], ss[16];
#pragma unroll
  for (int i = 0; i < 16; ++i) {
    int e = e0 + i * 256 + t;
    ds[i] = eidx[Ne + e];
    ss[i] = eidx[e];
    atomicAdd(&lcnt[ds[i] >> 8], 1);
  }
  __syncthreads();
  lcur[t] = atomicAdd(&gcur[t * 16], lcnt[t]);  // reserve contiguous run
  __syncthreads();
#pragma unroll
  for (int i = 0; i < 16; ++i) {
    int b = ds[i] >> 8;
    int p = atomicAdd(&lcur[b], 1);
    if (p < BCAP) payload[b * BCAP + p] = (ss[i] << 8) | (ds[i] & 255);
  }
}

// One block per bucket: inline scan of gcur -> base, LDS hist -> rp slice,
// place srcs via LDS cursors (scatter window owned by one CU).
__global__ __launch_bounds__(256) void k_placeB(const int* __restrict__ gcur,
                                                const int* __restrict__ payload,
                                                int* __restrict__ rp,
                                                int* __restrict__ srcs) {
  __shared__ int sAll[NB];
  __shared__ int hst[NB];
  __shared__ int cur[NB];
  int b = blockIdx.x, t = threadIdx.x;
  sAll[t] = gcur[t * 16];
  hst[t] = 0;
  __syncthreads();
  int cnt = min(sAll[b], BCAP);
  for (int off = 1; off < NB; off <<= 1) {
    int v = (t >= off) ? sAll[t - off] : 0;
    __syncthreads();
    sAll[t] += v;
    __syncthreads();
  }
  int base = sAll[b] - gcur[b * 16];  // exclusive prefix (true counts)
  const int* pay = &payload[b * BCAP];
  for (int i = t; i < cnt; i += 256) atomicAdd(&hst[pay[i] & 255], 1);
  __syncthreads();
  int c = hst[t];
  cur[t] = c;
  __syncthreads();
  for (int off = 1; off < NB; off <<= 1) {
    int v = (t >= off) ? cur[t - off] : 0;
    __syncthreads();
    cur[t] += v;
    __syncthreads();
  }
  int excl = cur[t] - c;
  rp[b * 256 + t] = base + excl;
  cur[t] = base + excl;
  __syncthreads();
  for (int i = t; i < cnt; i += 256) {
    int pl = pay[i];
    int p = atomicAdd(&cur[pl & 255], 1);
    srcs[p] = pl >> 8;
  }
}

// ---------------------------------------------------------------------------
// Fused Set2Set v6: all 3 iterations + head, one launch, 768 threads
// (12 waves = 3/SIMD; v5's 8 waves = 2/SIMD left VALUBusy at 17% -- pure
// dependent-chain latency with nothing to interleave).  NEW exp-once pass:
// eL[] is exponentiated in place (one expf per node instead of one per
// node per lane), with asum accumulated there; phase C becomes a pure
// fmaf dot.  h rows staged in 112 KB dynamic LDS as before.
// ---------------------------------------------------------------------------
constexpr int LCAP = 448;
constexpr int S2T  = 768;   // threads (12 waves)
__global__ __launch_bounds__(S2T) void k_s2s(const unsigned short* __restrict__ hph,
                                             const unsigned short* __restrict__ hpl,
                                             const int* __restrict__ gp,
                                             const float* __restrict__ WihT,
                                             const float* __restrict__ WhhT,
                                             const float* __restrict__ b_ih,
                                             const float* __restrict__ b_hh,
                                             const float* __restrict__ W1T,
                                             const float* __restrict__ b1,
                                             const float* __restrict__ W2,
                                             const float* __restrict__ b2,
                                             float* __restrict__ outp) {
  extern __shared__ float hL[];   // [LCAP][64] f32 staged h
  int g = blockIdx.x;
  int t = threadIdx.x;
  int w = t >> 6, lane = t & 63;
  __shared__ float qstar_s[128];  // [q | r] carried across iterations
  __shared__ float hs[64], cs[64], gates[256];
  __shared__ float eL[LCAP];
  __shared__ float red[12];
  __shared__ float partial[12][64];
  __shared__ float asum_p[12];
  __shared__ float emax_sh;
  __shared__ float l4[4];
  __shared__ float hid[64];

  if (t < 128) qstar_s[t] = 0.f;
  if (t < 64) { hs[t] = 0.f; cs[t] = 0.f; }
  int s = gp[g], e = gp[g + 1];
  int cnt = e - s;

  // ---- stage h rows once: hL[j] = recon(hph[s*64+j], hpl[s*64+j]) ----
  {
    int total = cnt * 64;
    for (int j = t * 4; j < total; j += S2T * 4) {
      ushort4 hh = *(const ushort4*)&hph[(size_t)s * 64 + j];
      ushort4 ll = *(const ushort4*)&hpl[(size_t)s * 64 + j];
      float4 v;
      v.x = recon(hh.x, ll.x); v.y = recon(hh.y, ll.y);
      v.z = recon(hh.z, ll.z); v.w = recon(hh.w, ll.w);
      *(float4*)&hL[j] = v;
    }
  }

  for (int it = 0; it < 3; ++it) {
    __syncthreads();   // state + staged hL visible

    // ---- LSTM cell (first 4 waves) ----
    if (t < 256) {
      float acc = b_ih[t] + b_hh[t];
      for (int k = 0; k < 128; ++k) acc = fmaf(WihT[k * 256 + t], qstar_s[k], acc);
      for (int k = 0; k < 64; ++k)  acc = fmaf(WhhT[k * 256 + t], hs[k], acc);
      gates[t] = acc;
    }
    __syncthreads();
    if (t < 64) {
      float ig = sigf(gates[t]),        fg = sigf(gates[64 + t]);
      float gg = tanhf(gates[128 + t]), og = sigf(gates[192 + t]);
      float c = fg * cs[t] + ig * gg;
      float q = og * tanhf(c);
      cs[t] = c;
      hs[t] = q;
      qstar_s[t] = q;
    }
    __syncthreads();

    // ---- attention phase A: e_i = h[i].q  (LDS reads, 12 waves x 4 nodes)
    int c4 = (lane & 15) * 4;
    float4 qv = {qstar_s[c4], qstar_s[c4 + 1], qstar_s[c4 + 2], qstar_s[c4 + 3]};
    for (int i0 = s + w * 4; i0 < e; i0 += 48) {
      int node = i0 + (lane >> 4);
      float p = 0.f;
      if (node < e) {
        float4 hv = *(const float4*)&hL[(node - s) * 64 + c4];
        p = hv.x * qv.x + hv.y * qv.y + hv.z * qv.z + hv.w * qv.w;
      }
      p += __shfl_xor(p, 1); p += __shfl_xor(p, 2);
      p += __shfl_xor(p, 4); p += __shfl_xor(p, 8);
      if (node < e && (lane & 15) == 0) eL[node - s] = p;
    }
    __syncthreads();

    // ---- phase B: segment max ----
    float m = -INFINITY;
    for (int i = t; i < cnt; i += S2T) m = fmaxf(m, eL[i]);
#pragma unroll
    for (int o = 32; o >= 1; o >>= 1) m = fmaxf(m, __shfl_xor(m, o));
    if (lane == 0) red[w] = m;
    __syncthreads();
    if (t == 0) {
      float mm = -INFINITY;
      for (int q = 0; q < 12; ++q) mm = fmaxf(mm, red[q]);
      emax_sh = isfinite(mm) ? mm : 0.f;
    }
    __syncthreads();
    float emax = emax_sh;

    // ---- phase B2: exp-once (eL[i] <- exp(eL[i]-emax)) + asum partials ----
    float asl = 0.f;
    for (int i = t; i < cnt; i += S2T) {
      float a = expf(eL[i] - emax);
      eL[i] = a;
      asl += a;
    }
#pragma unroll
    for (int o = 32; o >= 1; o >>= 1) asl += __shfl_xor(asl, o);
    if (lane == 0) asum_p[w] = asl;
    __syncthreads();

    // ---- phase C: weighted feature sum (pure fmaf dot over LDS) ----
    float acc = 0.f;
    for (int i = s + w; i < e; i += 12) {
      acc = fmaf(eL[i - s], hL[(i - s) * 64 + lane], acc);
    }
    partial[w][lane] = acc;
    __syncthreads();
    if (t < 64) {
      float r = 0.f, as = 0.f;
      for (int q = 0; q < 12; ++q) { r += partial[q][t]; as += asum_p[q]; }
      float rv = (cnt > 0) ? r / fmaxf(as, 1e-16f) : 0.f;
      qstar_s[64 + t] = rv;
    }
  }
  __syncthreads();

  // ---- head ----
  if (t < 64) {
    float a1 = b1[t];
    for (int k = 0; k < 64; ++k)   a1 = fmaf(W1T[k * 64 + t], qstar_s[k], a1);
    for (int k = 64; k < 128; ++k) a1 = fmaf(W1T[k * 64 + t], qstar_s[k], a1);
    hid[t] = fmaxf(a1, 0.f);
  }
  __syncthreads();
  if (t < 4) {
    float lg = b2[t];
    for (int d = 0; d < 64; ++d) lg = fmaf(W2[t * 64 + d], hid[d], lg);
    l4[t] = lg;
  }
  __syncthreads();
  if (t < 4) {
    float mx = fmaxf(fmaxf(l4[0], l4[1]), fmaxf(l4[2], l4[3]));
    float ssum = expf(l4[0] - mx) + expf(l4[1] - mx) + expf(l4[2] - mx) + expf(l4[3] - mx);
    outp[g * 4 + t] = l4[t] - mx - logf(ssum);
  }
}

// ---------------------------------------------------------------------------
extern "C" void kernel_launch(void* const* d_in, const int* in_sizes, int n_in,
                              void* d_out, int out_size, void* d_ws, size_t ws_size,
                              hipStream_t stream) {
  const float* x        = (const float*)d_in[0];
  const int*   eidx     = (const int*)d_in[1];
  const int*   batch    = (const int*)d_in[2];
  const float* W_mlp    = (const float*)d_in[3];
  const float* b_mlp    = (const float*)d_in[4];
  const float* W_conv   = (const float*)d_in[5];
  const float* b_conv   = (const float*)d_in[6];
  const float* gW_ih    = (const float*)d_in[7];
  const float* gW_hh    = (const float*)d_in[8];
  const float* gb_ih    = (const float*)d_in[9];
  const float* gb_hh    = (const float*)d_in[10];
  const float* lW_ih    = (const float*)d_in[11];
  const float* lW_hh    = (const float*)d_in[12];
  const float* lb_ih    = (const float*)d_in[13];
  const float* lb_hh    = (const float*)d_in[14];
  const float* W1       = (const float*)d_in[15];
  const float* b1       = (const float*)d_in[16];
  const float* W2       = (const float*)d_in[17];
  const float* b2       = (const float*)d_in[18];
  float* outp = (float*)d_out;

  // ---- workspace layout ----
  char* ws = (char*)d_ws;
  size_t off = 0;
  auto alloc = [&](size_t bytes) { size_t r = off; off = (off + bytes + 255) & ~(size_t)255; return r; };
  unsigned short* hpAh = (unsigned short*)(ws + alloc((size_t)Nn * 64 * 2));
  unsigned short* hpAl = (unsigned short*)(ws + alloc((size_t)Nn * 64 * 2));
  unsigned short* hpBh = (unsigned short*)(ws + alloc((size_t)Nn * 64 * 2));
  unsigned short* hpBl = (unsigned short*)(ws + alloc((size_t)Nn * 64 * 2));
  unsigned short* Aih  = (unsigned short*)(ws + alloc((size_t)Nn * 96 * 2));
  unsigned short* Ail  = (unsigned short*)(ws + alloc((size_t)Nn * 96 * 2));
  unsigned short* Sh   = (unsigned short*)(ws + alloc((size_t)Nn * 64 * 2));
  unsigned short* Sl   = (unsigned short*)(ws + alloc((size_t)Nn * 64 * 2));
  int*   rp    = (int*)(ws + alloc((size_t)(Nn + 1) * 4));
  int*   srcs  = (int*)(ws + alloc((size_t)Ne * 4));
  int*   gcur  = (int*)(ws + alloc((size_t)NB * 16 * 4));
  int*   payload = (int*)(ws + alloc((size_t)NB * BCAP * 4));
  int*   gp    = (int*)(ws + alloc((size_t)(Bg + 1) * 4));
  float* WihT  = (float*)(ws + alloc((size_t)128 * 256 * 4));
  float* WhhT  = (float*)(ws + alloc((size_t)64 * 256 * 4));
  float* W1T   = (float*)(ws + alloc((size_t)128 * 64 * 4));
  float* vfold = (float*)(ws + alloc(192 * 4));
  unsigned short* mlp_h = (unsigned short*)(ws + alloc(2048 * 2));
  unsigned short* mlp_l = (unsigned short*)(ws + alloc(2048 * 2));
  unsigned short* gw_h  = (unsigned short*)(ws + alloc(30720 * 2));
  unsigned short* gw_l  = (unsigned short*)(ws + alloc(30720 * 2));
  (void)in_sizes; (void)n_in; (void)out_size; (void)ws_size;

  hipMemsetAsync(gcur, 0, (size_t)NB * 16 * 4, stream);

  // CSR build (bucket sort) + prep (incl. W_conv folding)
  k_bucket<<<Ne / 4096, 256, 0, stream>>>(eidx, gcur, payload);
  k_placeB<<<NB, 256, 0, stream>>>(gcur, payload, rp, srcs);
  k_prepw<<<355, 256, 0, stream>>>(W_mlp, W_conv, gW_ih, gW_hh, b_conv,
                                   lW_ih, lW_hh, W1,
                                   mlp_h, mlp_l, gw_h, gw_l,
                                   WihT, WhhT, W1T, vfold, batch, gp, rp);

  // conv1 (+ x-column planes)
  k_conv1<<<Nn / 64, 256, 0, stream>>>(x, mlp_h, mlp_l, b_mlp, hpAh, hpAl, Aih, Ail);

  unsigned short *cph = hpAh, *cpl = hpAl, *nph = hpBh, *npl = hpBl;
  for (int step = 0; step < 2; ++step) {
    k_aggr<<<Nn / 4, 256, 0, stream>>>(cph, rp, srcs, Sh, Sl);
    k_gru<<<Nn / 128, 256, 0, stream>>>(Aih, Ail, cph, cpl, Sh, Sl, gw_h, gw_l,
                                        gb_ih, gb_hh, vfold, rp, nph, npl);
    unsigned short* tu;
    tu = cph; cph = nph; nph = tu;
    tu = cpl; cpl = npl; npl = tu;
  }

  // Set2Set: all 3 iterations + head, one launch, 768 threads, 112 KB dyn LDS
  const size_t dynLds = (size_t)LCAP * 64 * sizeof(float);  // 114688 B
  static bool attr_set = false;
  if (!attr_set) {
    hipFuncSetAttribute((const void*)k_s2s,
                        hipFuncAttributeMaxDynamicSharedMemorySize,
                        (int)dynLds);
    attr_set = true;
  }
  k_s2s<<<Bg, S2T, dynLds, stream>>>(cph, cpl, gp, WihT, WhhT,
                                     lb_ih, lb_hh, W1T, b1, W2, b2, outp);
}

// Round 8
// 301.186 us; speedup vs baseline: 1.1484x; 1.1484x over previous
//
#include <hip/hip_runtime.h>
#include <math.h>

constexpr int Nn  = 65536;    // nodes
constexpr int Ne  = 1048576;  // edges
constexpr int Bg  = 256;      // graphs
constexpr int DIN = 32;
constexpr int D   = 64;

constexpr int NB   = 256;     // dst buckets (dst>>8)
constexpr int BCAP = 6144;    // bucket stream capacity (mean 4096, +36 sigma)

typedef __attribute__((ext_vector_type(8))) short bf16x8;
typedef __attribute__((ext_vector_type(8))) unsigned short u16x8;
typedef __attribute__((ext_vector_type(4))) float f32x4;

__device__ __forceinline__ float sigf(float x) { return 1.0f / (1.0f + expf(-x)); }

// ---- bf16 split helpers (RNE) ----
__device__ __forceinline__ unsigned short bf16_rne(float f) {
  unsigned u = __float_as_uint(f);
  unsigned r = u + 0x7FFFu + ((u >> 16) & 1u);
  return (unsigned short)(r >> 16);
}
__device__ __forceinline__ float bf16_tof(unsigned short h) {
  return __uint_as_float(((unsigned)h) << 16);
}
__device__ __forceinline__ void split2(float f, unsigned short& hi, unsigned short& lo) {
  hi = bf16_rne(f);
  lo = bf16_rne(f - bf16_tof(hi));
}
__device__ __forceinline__ float recon(unsigned short hi, unsigned short lo) {
  return bf16_tof(hi) + bf16_tof(lo);
}

#define MFMA(a, b, c) __builtin_amdgcn_mfma_f32_16x16x32_bf16(a, b, c, 0, 0, 0)

// ---------------------------------------------------------------------------
// Prep.  GRU weights chunk-major (5 chunks x 12nt x 64lane x 8j / plane):
//   chunks 0,1 = Wfold = Wih[:, :64] @ W_conv   (fused conv-linear)
//   chunk  2   = Wih[:, 64:96]  (x part)
//   chunks 3,4 = Whh
// Also: W_mlp pack, LSTM/W1 transposes, graphptr, rp[Nn], vfold.
// ---------------------------------------------------------------------------
__global__ void k_prepw(const float* __restrict__ W_mlp, const float* __restrict__ W_conv,
                        const float* __restrict__ gWih, const float* __restrict__ gWhh,
                        const float* __restrict__ b_conv,
                        const float* __restrict__ lW_ih, const float* __restrict__ lW_hh,
                        const float* __restrict__ W1,
                        unsigned short* __restrict__ mlp_h, unsigned short* __restrict__ mlp_l,
                        unsigned short* __restrict__ gw_h,  unsigned short* __restrict__ gw_l,
                        float* __restrict__ WihT, float* __restrict__ WhhT,
                        float* __restrict__ W1T, float* __restrict__ vfold,
                        const int* __restrict__ batch, int* __restrict__ gp,
                        int* __restrict__ rp) {
  int idx = blockIdx.x * 256 + threadIdx.x;
  if (idx < 30720) {  // GRU weights, chunk-major
    int c = idx / 6144, rem = idx % 6144;
    int nt = rem >> 9, lane = (rem >> 3) & 63, j = rem & 7;
    int n = nt * 16 + (lane & 15);
    int kk = c * 32 + (lane >> 4) * 8 + j;   // for c<3: k index into [S|x]
    float v;
    if (c < 2) {        // Wfold[n][kk] = sum_o Wih[n][o] * W_conv[o][kk]
      float s = 0.f;
      for (int o = 0; o < 64; ++o) s = fmaf(gWih[n * 96 + o], W_conv[o * 64 + kk], s);
      v = s;
    } else if (c == 2) {
      v = gWih[n * 96 + kk];                 // kk in 64..95 (x columns)
    } else {
      v = gWhh[n * 64 + (c - 3) * 32 + (lane >> 4) * 8 + j];
    }
    unsigned short hi, lo; split2(v, hi, lo);
    gw_h[idx] = hi; gw_l[idx] = lo;
    return;
  }
  if (idx < 32768) {  // W_mlp (KS=1)
    int lp = idx - 30720;
    int nt = lp >> 9, lane = (lp >> 3) & 63, j = lp & 7;
    int n = nt * 16 + (lane & 15);
    unsigned short hi, lo;
    split2(W_mlp[n * 32 + (lane >> 4) * 8 + j], hi, lo);
    mlp_h[lp] = hi; mlp_l[lp] = lo;
    return;
  }
  int t = idx - 32768;
  if (t < 32768) {                 // lstm W_ih [256][128] -> WihT [128][256]
    int row = t / 128, k = t % 128;
    WihT[k * 256 + row] = lW_ih[t];
  } else if (t < 49152) {          // lstm W_hh [256][64] -> WhhT [64][256]
    int j = t - 32768;
    int row = j / 64, k = j % 64;
    WhhT[k * 256 + row] = lW_hh[j];
  } else if (t < 57344) {          // W1 [64][128] -> W1T [128][64]
    int j = t - 49152;
    int row = j / 128, k = j % 128;
    W1T[k * 64 + row] = W1[j];
  } else if (t < 57344 + Bg + 1) { // graphptr + rp[Nn]
    int g = t - 57344;
    if (g == 0) rp[Nn] = Ne;
    int lo = 0, hi = Nn;
    while (lo < hi) {
      int mid = (lo + hi) >> 1;
      if (batch[mid] < g) lo = mid + 1; else hi = mid;
    }
    gp[g] = lo;
  } else if (t < 57344 + 257 + 192) { // vfold[192]
    int g = t - 57344 - 257;
    float s = 0.f;
    for (int o = 0; o < 64; ++o) s = fmaf(gWih[g * 96 + o], b_conv[o], s);
    vfold[g] = s;
  }
}

// ---------------------------------------------------------------------------
// conv1: h = x @ W_mlp^T + b  (K=32, N=64). Splits x in-kernel; also fills
// inp96 x-columns (64..95).  h stored as planes only.
// ---------------------------------------------------------------------------
__global__ __launch_bounds__(256) void k_conv1(const float* __restrict__ x,
                                               const unsigned short* __restrict__ Wh,
                                               const unsigned short* __restrict__ Wl,
                                               const float* __restrict__ bias,
                                               unsigned short* __restrict__ hph,
                                               unsigned short* __restrict__ hpl,
                                               unsigned short* __restrict__ Aih,
                                               unsigned short* __restrict__ Ail) {
  int wave = threadIdx.x >> 6, lane = threadIdx.x & 63;
  int quad = lane >> 4;
  int n0w = blockIdx.x * 64 + wave * 16;
  int rowA = n0w + (lane & 15);
  const float4* xp = (const float4*)&x[(size_t)rowA * 32 + quad * 8];
  float4 xa = xp[0], xb = xp[1];
  float xv[8] = {xa.x, xa.y, xa.z, xa.w, xb.x, xb.y, xb.z, xb.w};
  bf16x8 ah, al;
#pragma unroll
  for (int j = 0; j < 8; ++j) {
    unsigned short hi, lo; split2(xv[j], hi, lo);
    ah[j] = (short)hi; al[j] = (short)lo;
  }
  *(bf16x8*)&Aih[(size_t)rowA * 96 + 64 + quad * 8] = ah;
  *(bf16x8*)&Ail[(size_t)rowA * 96 + 64 + quad * 8] = al;

  f32x4 acc[4] = {};
#pragma unroll
  for (int nt = 0; nt < 4; ++nt) {
    bf16x8 bh = *(const bf16x8*)&Wh[(nt * 64 + lane) * 8];
    bf16x8 bl = *(const bf16x8*)&Wl[(nt * 64 + lane) * 8];
    acc[nt] = MFMA(ah, bh, acc[nt]);
    acc[nt] = MFMA(ah, bl, acc[nt]);
    acc[nt] = MFMA(al, bh, acc[nt]);
  }
  int col0 = lane & 15;
#pragma unroll
  for (int nt = 0; nt < 4; ++nt) {
    float bv = bias[nt * 16 + col0];
#pragma unroll
    for (int r = 0; r < 4; ++r) {
      int node = n0w + quad * 4 + r;
      float v = acc[nt][r] + bv;
      size_t o = (size_t)node * 64 + nt * 16 + col0;
      unsigned short hi, lo; split2(v, hi, lo);
      hph[o] = hi; hpl[o] = lo;
    }
  }
}

// ---------------------------------------------------------------------------
// Aggregate v4: one wave per node; lane l owns edge-slot (l>>3) and columns
// (l&7)*8..+7.  Each load instruction is u16x8 (16 B/lane, 1 KB/wave) and
// covers 8 EDGES at once.  Edge-slot partials combined by fixed-order
// xor-shuffle tree.
// ---------------------------------------------------------------------------
__global__ __launch_bounds__(256) void k_aggr(const unsigned short* __restrict__ Hh,
                                              const int* __restrict__ rp,
                                              const int* __restrict__ srcs,
                                              unsigned short* __restrict__ Sh,
                                              unsigned short* __restrict__ Sl) {
  int wave = threadIdx.x >> 6, lane = threadIdx.x & 63;
  int node = blockIdx.x * 4 + wave;
  int s = rp[node], e = rp[node + 1];
  int n = e - s;
  const int* sp = srcs + s;
  int col8 = (lane & 7) * 8;
  int eslot = lane >> 3;
  float acc8[8] = {};
  int k = 0;
  for (; k + 16 <= n; k += 16) {
    int sA = sp[k + eslot];
    int sB = sp[k + 8 + eslot];
    u16x8 a = *(const u16x8*)&Hh[(size_t)sA * 64 + col8];
    u16x8 b = *(const u16x8*)&Hh[(size_t)sB * 64 + col8];
#pragma unroll
    for (int j = 0; j < 8; ++j) acc8[j] += bf16_tof(a[j]);
#pragma unroll
    for (int j = 0; j < 8; ++j) acc8[j] += bf16_tof(b[j]);
  }
  for (; k < n; k += 8) {
    if (k + eslot < n) {
      int sA = sp[k + eslot];
      u16x8 a = *(const u16x8*)&Hh[(size_t)sA * 64 + col8];
#pragma unroll
      for (int j = 0; j < 8; ++j) acc8[j] += bf16_tof(a[j]);
    }
  }
  // combine the 8 edge-slot partials (fixed-order tree over lanes l^8,l^16,l^32)
#pragma unroll
  for (int m = 8; m <= 32; m <<= 1) {
#pragma unroll
    for (int j = 0; j < 8; ++j) acc8[j] += __shfl_xor(acc8[j], m);
  }
  if (lane < 8) {
    u16x8 hv, lv;
#pragma unroll
    for (int j = 0; j < 8; ++j) {
      unsigned short hi, lo; split2(acc8[j], hi, lo);
      hv[j] = hi; lv[j] = lo;
    }
    *(u16x8*)&Sh[(size_t)node * 64 + col8] = hv;
    *(u16x8*)&Sl[(size_t)node * 64 + col8] = lv;
  }
}

// ---------------------------------------------------------------------------
// Fused GRU v9: gather moved out to k_aggr; chunks 0,1 read the S planes
// (Sh/Sl) exactly like the Whh chunks read Hh/Hl.  Keeps the proven
// 5-chunk double-buffered-LDS K-loop and epilogue.
// ---------------------------------------------------------------------------
__global__ __launch_bounds__(256, 2) void k_gru(const unsigned short* __restrict__ Aih,
                                                const unsigned short* __restrict__ Ail,
                                                const unsigned short* __restrict__ Hh,
                                                const unsigned short* __restrict__ Hl,
                                                const unsigned short* __restrict__ Sh,
                                                const unsigned short* __restrict__ Sl,
                                                const unsigned short* __restrict__ gw_h,
                                                const unsigned short* __restrict__ gw_l,
                                                const float* __restrict__ b_ih,
                                                const float* __restrict__ b_hh,
                                                const float* __restrict__ vfold,
                                                const int* __restrict__ rp,
                                                unsigned short* __restrict__ nph,
                                                unsigned short* __restrict__ npl) {
  __shared__ unsigned short sW[2][12288];  // per buf: hi[0..6143] | lo[6144..]
  int tid = threadIdx.x;
  int wave = tid >> 6, lane = tid & 63;
  int quad = lane >> 4;
  int n0w = blockIdx.x * 128 + wave * 32;
  int rowA0 = n0w + (lane & 15);          // tile0 A-row; tile1 = +16

  f32x4 acc0[12] = {}, acc1[12] = {};     // gi r,z,n (gh r,z folded into 0..7)
  f32x4 aN0[4] = {}, aN1[4] = {};         // gh n-gate

  // prologue: weights chunk 0
  bf16x8 gvh[3], gvl[3];
#pragma unroll
  for (int j = 0; j < 3; ++j) {
    gvh[j] = *(const bf16x8*)&gw_h[(tid + j * 256) * 8];
    gvl[j] = *(const bf16x8*)&gw_l[(tid + j * 256) * 8];
  }
#pragma unroll
  for (int j = 0; j < 3; ++j) {
    *(bf16x8*)&sW[0][(tid + j * 256) * 8] = gvh[j];
    *(bf16x8*)&sW[0][6144 + (tid + j * 256) * 8] = gvl[j];
  }
  __syncthreads();

#pragma unroll
  for (int c = 0; c < 5; ++c) {
    const int buf = c & 1;
    if (c < 4) {  // prefetch chunk c+1 weights
#pragma unroll
      for (int j = 0; j < 3; ++j) {
        gvh[j] = *(const bf16x8*)&gw_h[(c + 1) * 6144 + (tid + j * 256) * 8];
        gvl[j] = *(const bf16x8*)&gw_l[(c + 1) * 6144 + (tid + j * 256) * 8];
      }
    }
    // A fragments
    bf16x8 a0h, a0l, a1h, a1l;
    if (c < 2) {            // aggregated S planes from k_aggr
      size_t b0 = (size_t)rowA0 * 64 + c * 32 + quad * 8;
      size_t b1 = (size_t)(rowA0 + 16) * 64 + c * 32 + quad * 8;
      a0h = *(const bf16x8*)&Sh[b0]; a0l = *(const bf16x8*)&Sl[b0];
      a1h = *(const bf16x8*)&Sh[b1]; a1l = *(const bf16x8*)&Sl[b1];
    } else if (c == 2) {    // x columns from conv1 prep
      size_t b0 = (size_t)rowA0 * 96 + 64 + quad * 8;
      size_t b1 = (size_t)(rowA0 + 16) * 96 + 64 + quad * 8;
      a0h = *(const bf16x8*)&Aih[b0]; a0l = *(const bf16x8*)&Ail[b0];
      a1h = *(const bf16x8*)&Aih[b1]; a1l = *(const bf16x8*)&Ail[b1];
    } else {                // h planes (Whh chunks)
      size_t b0 = (size_t)rowA0 * 64 + (c - 3) * 32 + quad * 8;
      size_t b1 = (size_t)(rowA0 + 16) * 64 + (c - 3) * 32 + quad * 8;
      a0h = *(const bf16x8*)&Hh[b0]; a0l = *(const bf16x8*)&Hl[b0];
      a1h = *(const bf16x8*)&Hh[b1]; a1l = *(const bf16x8*)&Hl[b1];
    }
    const unsigned short* sw = sW[buf];
#pragma unroll
    for (int nt = 0; nt < 12; ++nt) {
      bf16x8 bh = *(const bf16x8*)&sw[(nt * 64 + lane) * 8];
      bf16x8 bl = *(const bf16x8*)&sw[6144 + (nt * 64 + lane) * 8];
      if (c < 3 || nt < 8) {
        acc0[nt] = MFMA(a0h, bh, acc0[nt]);
        acc0[nt] = MFMA(a0h, bl, acc0[nt]);
        acc0[nt] = MFMA(a0l, bh, acc0[nt]);
        acc1[nt] = MFMA(a1h, bh, acc1[nt]);
        acc1[nt] = MFMA(a1h, bl, acc1[nt]);
        acc1[nt] = MFMA(a1l, bh, acc1[nt]);
      } else {
        aN0[nt - 8] = MFMA(a0h, bh, aN0[nt - 8]);
        aN0[nt - 8] = MFMA(a0h, bl, aN0[nt - 8]);
        aN0[nt - 8] = MFMA(a0l, bh, aN0[nt - 8]);
        aN1[nt - 8] = MFMA(a1h, bh, aN1[nt - 8]);
        aN1[nt - 8] = MFMA(a1h, bl, aN1[nt - 8]);
        aN1[nt - 8] = MFMA(a1l, bh, aN1[nt - 8]);
      }
    }
    if (c < 4) {
#pragma unroll
      for (int j = 0; j < 3; ++j) {
        *(bf16x8*)&sW[1 - buf][(tid + j * 256) * 8] = gvh[j];
        *(bf16x8*)&sW[1 - buf][6144 + (tid + j * 256) * 8] = gvl[j];
      }
    }
    __syncthreads();
  }

  // epilogue: GRU nonlinearity + deg*vfold (folded conv bias) + plane store
  int col0 = lane & 15;
#pragma unroll
  for (int tile = 0; tile < 2; ++tile) {
    int nb = n0w + tile * 16;
#pragma unroll
    for (int r = 0; r < 4; ++r) {
      int node = nb + quad * 4 + r;
      float degf = (float)(rp[node + 1] - rp[node]);
#pragma unroll
      for (int nt = 0; nt < 4; ++nt) {
        int g = nt * 16 + col0;
        size_t o = (size_t)node * 64 + g;
        float br  = b_ih[g] + b_hh[g] + degf * vfold[g];
        float bz  = b_ih[64 + g] + b_hh[64 + g] + degf * vfold[64 + g];
        float bin = b_ih[128 + g] + degf * vfold[128 + g];
        float bhn = b_hh[128 + g];
        float gr = tile ? acc1[nt][r]     : acc0[nt][r];
        float gz = tile ? acc1[nt + 4][r] : acc0[nt + 4][r];
        float gn = tile ? acc1[nt + 8][r] : acc0[nt + 8][r];
        float hn = tile ? aN1[nt][r]      : aN0[nt][r];
        float rr = sigf(gr + br);
        float zz = sigf(gz + bz);
        float nn = tanhf(gn + bin + rr * (hn + bhn));
        float h_old = recon(Hh[o], Hl[o]);
        float hv = (1.f - zz) * nn + zz * h_old;
        unsigned short hi, lo; split2(hv, hi, lo);
        nph[o] = hi; npl[o] = lo;
      }
    }
  }
}

// ---------------------------------------------------------------------------
// CSR build v3: two-level bucket sort by dst.
// ---------------------------------------------------------------------------
__global__ __launch_bounds__(256) void k_bucket(const int* __restrict__ eidx,
                                                int* __restrict__ gcur,     // [NB*16]
                                                int* __restrict__ payload) {// [NB*BCAP]
  __shared__ int lcnt[NB];
  __shared__ int lcur[NB];
  int t = threadIdx.x;
  int e0 = blockIdx.x * 4096;
  lcnt[t] = 0;
  __syncthreads();
  int ds[16], ss[16];
#pragma unroll
  for (int i = 0; i < 16; ++i) {
    int e = e0 + i * 256 + t;
    ds[i] = eidx[Ne + e];
    ss[i] = eidx[e];
    atomicAdd(&lcnt[ds[i] >> 8], 1);
  }
  __syncthreads();
  lcur[t] = atomicAdd(&gcur[t * 16], lcnt[t]);  // reserve contiguous run
  __syncthreads();
#pragma unroll
  for (int i = 0; i < 16; ++i) {
    int b = ds[i] >> 8;
    int p = atomicAdd(&lcur[b], 1);
    if (p < BCAP) payload[b * BCAP + p] = (ss[i] << 8) | (ds[i] & 255);
  }
}

// One block per bucket: inline scan of gcur -> base, LDS hist -> rp slice,
// place srcs via LDS cursors (scatter window owned by one CU).
__global__ __launch_bounds__(256) void k_placeB(const int* __restrict__ gcur,
                                                const int* __restrict__ payload,
                                                int* __restrict__ rp,
                                                int* __restrict__ srcs) {
  __shared__ int sAll[NB];
  __shared__ int hst[NB];
  __shared__ int cur[NB];
  int b = blockIdx.x, t = threadIdx.x;
  sAll[t] = gcur[t * 16];
  hst[t] = 0;
  __syncthreads();
  int cnt = min(sAll[b], BCAP);
  for (int off = 1; off < NB; off <<= 1) {
    int v = (t >= off) ? sAll[t - off] : 0;
    __syncthreads();
    sAll[t] += v;
    __syncthreads();
  }
  int base = sAll[b] - gcur[b * 16];  // exclusive prefix (true counts)
  const int* pay = &payload[b * BCAP];
  for (int i = t; i < cnt; i += 256) atomicAdd(&hst[pay[i] & 255], 1);
  __syncthreads();
  int c = hst[t];
  cur[t] = c;
  __syncthreads();
  for (int off = 1; off < NB; off <<= 1) {
    int v = (t >= off) ? cur[t - off] : 0;
    __syncthreads();
    cur[t] += v;
    __syncthreads();
  }
  int excl = cur[t] - c;
  rp[b * 256 + t] = base + excl;
  cur[t] = base + excl;
  __syncthreads();
  for (int i = t; i < cnt; i += 256) {
    int pl = pay[i];
    int p = atomicAdd(&cur[pl & 255], 1);
    srcs[p] = pl >> 8;
  }
}

// ---------------------------------------------------------------------------
// Fused Set2Set v7: round-6 structure (512 thr, measured 56 us) + two
// latency fixes, output bitwise identical to round 6:
//  - hL row stride padded 64 -> 68 floats: phase A's ds_read_b128 had lanes
//    0/16/32/48 on the same banks (row stride 256 B) = 4-way conflict
//    (SQ_LDS_BANK_CONFLICT 1.57M); +4 floats rotates banks per row.
//  - per-wave emax: max is order-invariant, every wave computes the exact
//    same value independently -> red[]/emax_sh reduction and 2 barriers
//    removed (7 -> 5 per iteration).
// (v6's 768-thr + exp-once regressed: scratch spill, WRITE_SIZE 4.6 MB.)
// ---------------------------------------------------------------------------
constexpr int LCAP = 448;
constexpr int LPAD = 68;    // padded hL row stride in floats
constexpr int S2T  = 512;   // threads (8 waves)
__global__ __launch_bounds__(S2T) void k_s2s(const unsigned short* __restrict__ hph,
                                             const unsigned short* __restrict__ hpl,
                                             const int* __restrict__ gp,
                                             const float* __restrict__ WihT,
                                             const float* __restrict__ WhhT,
                                             const float* __restrict__ b_ih,
                                             const float* __restrict__ b_hh,
                                             const float* __restrict__ W1T,
                                             const float* __restrict__ b1,
                                             const float* __restrict__ W2,
                                             const float* __restrict__ b2,
                                             float* __restrict__ outp) {
  extern __shared__ float hL[];   // [LCAP][LPAD] f32 staged h
  int g = blockIdx.x;
  int t = threadIdx.x;
  int w = t >> 6, lane = t & 63;
  __shared__ float qstar_s[128];  // [q | r] carried across iterations
  __shared__ float hs[64], cs[64], gates[256];
  __shared__ float eL[LCAP];
  __shared__ float partial[8][64];
  __shared__ float asum_p[8];
  __shared__ float l4[4];
  __shared__ float hid[64];

  if (t < 128) qstar_s[t] = 0.f;
  if (t < 64) { hs[t] = 0.f; cs[t] = 0.f; }
  int s = gp[g], e = gp[g + 1];
  int cnt = e - s;

  // ---- stage h rows once: hL[nd*LPAD+col] = recon(hph, hpl) ----
  {
    int total = cnt * 64;
    for (int j = t * 4; j < total; j += S2T * 4) {
      int nd = j >> 6, col = j & 63;
      ushort4 hh = *(const ushort4*)&hph[(size_t)s * 64 + j];
      ushort4 ll = *(const ushort4*)&hpl[(size_t)s * 64 + j];
      float4 v;
      v.x = recon(hh.x, ll.x); v.y = recon(hh.y, ll.y);
      v.z = recon(hh.z, ll.z); v.w = recon(hh.w, ll.w);
      *(float4*)&hL[nd * LPAD + col] = v;
    }
  }

  for (int it = 0; it < 3; ++it) {
    __syncthreads();   // state + staged hL visible

    // ---- LSTM cell (first 4 waves) ----
    if (t < 256) {
      float acc = b_ih[t] + b_hh[t];
      for (int k = 0; k < 128; ++k) acc = fmaf(WihT[k * 256 + t], qstar_s[k], acc);
      for (int k = 0; k < 64; ++k)  acc = fmaf(WhhT[k * 256 + t], hs[k], acc);
      gates[t] = acc;
    }
    __syncthreads();
    if (t < 64) {
      float ig = sigf(gates[t]),        fg = sigf(gates[64 + t]);
      float gg = tanhf(gates[128 + t]), og = sigf(gates[192 + t]);
      float c = fg * cs[t] + ig * gg;
      float q = og * tanhf(c);
      cs[t] = c;
      hs[t] = q;
      qstar_s[t] = q;
    }
    __syncthreads();

    // ---- attention phase A: e_i = h[i].q  (padded LDS, conflict-free) ----
    int c4 = (lane & 15) * 4;
    float4 qv = {qstar_s[c4], qstar_s[c4 + 1], qstar_s[c4 + 2], qstar_s[c4 + 3]};
    for (int i0 = s + w * 4; i0 < e; i0 += 32) {
      int node = i0 + (lane >> 4);
      float p = 0.f;
      if (node < e) {
        float4 hv = *(const float4*)&hL[(node - s) * LPAD + c4];
        p = hv.x * qv.x + hv.y * qv.y + hv.z * qv.z + hv.w * qv.w;
      }
      p += __shfl_xor(p, 1); p += __shfl_xor(p, 2);
      p += __shfl_xor(p, 4); p += __shfl_xor(p, 8);
      if (node < e && (lane & 15) == 0) eL[node - s] = p;
    }
    __syncthreads();

    // ---- phase B: segment max, per-wave (max is order-invariant ->
    //      every wave independently computes the identical exact value) ----
    float m = -INFINITY;
    for (int i = lane; i < cnt; i += 64) m = fmaxf(m, eL[i]);
#pragma unroll
    for (int o = 32; o >= 1; o >>= 1) m = fmaxf(m, __shfl_xor(m, o));
    float emax = isfinite(m) ? m : 0.f;

    // ---- phase C: softmax-weighted feature sum (padded LDS) ----
    float acc = 0.f, asum = 0.f;
    for (int i = s + w; i < e; i += 8) {
      float a = expf(eL[i - s] - emax);
      asum += a;
      acc = fmaf(a, hL[(i - s) * LPAD + lane], acc);
    }
    partial[w][lane] = acc;
    if (lane == 0) asum_p[w] = asum;
    __syncthreads();
    if (t < 64) {
      float r = 0.f, as = 0.f;
      for (int q = 0; q < 8; ++q) { r += partial[q][t]; as += asum_p[q]; }
      float rv = (cnt > 0) ? r / fmaxf(as, 1e-16f) : 0.f;
      qstar_s[64 + t] = rv;
    }
  }
  __syncthreads();

  // ---- head ----
  if (t < 64) {
    float a1 = b1[t];
    for (int k = 0; k < 64; ++k)   a1 = fmaf(W1T[k * 64 + t], qstar_s[k], a1);
    for (int k = 64; k < 128; ++k) a1 = fmaf(W1T[k * 64 + t], qstar_s[k], a1);
    hid[t] = fmaxf(a1, 0.f);
  }
  __syncthreads();
  if (t < 4) {
    float lg = b2[t];
    for (int d = 0; d < 64; ++d) lg = fmaf(W2[t * 64 + d], hid[d], lg);
    l4[t] = lg;
  }
  __syncthreads();
  if (t < 4) {
    float mx = fmaxf(fmaxf(l4[0], l4[1]), fmaxf(l4[2], l4[3]));
    float ssum = expf(l4[0] - mx) + expf(l4[1] - mx) + expf(l4[2] - mx) + expf(l4[3] - mx);
    outp[g * 4 + t] = l4[t] - mx - logf(ssum);
  }
}

// ---------------------------------------------------------------------------
extern "C" void kernel_launch(void* const* d_in, const int* in_sizes, int n_in,
                              void* d_out, int out_size, void* d_ws, size_t ws_size,
                              hipStream_t stream) {
  const float* x        = (const float*)d_in[0];
  const int*   eidx     = (const int*)d_in[1];
  const int*   batch    = (const int*)d_in[2];
  const float* W_mlp    = (const float*)d_in[3];
  const float* b_mlp    = (const float*)d_in[4];
  const float* W_conv   = (const float*)d_in[5];
  const float* b_conv   = (const float*)d_in[6];
  const float* gW_ih    = (const float*)d_in[7];
  const float* gW_hh    = (const float*)d_in[8];
  const float* gb_ih    = (const float*)d_in[9];
  const float* gb_hh    = (const float*)d_in[10];
  const float* lW_ih    = (const float*)d_in[11];
  const float* lW_hh    = (const float*)d_in[12];
  const float* lb_ih    = (const float*)d_in[13];
  const float* lb_hh    = (const float*)d_in[14];
  const float* W1       = (const float*)d_in[15];
  const float* b1       = (const float*)d_in[16];
  const float* W2       = (const float*)d_in[17];
  const float* b2       = (const float*)d_in[18];
  float* outp = (float*)d_out;

  // ---- workspace layout ----
  char* ws = (char*)d_ws;
  size_t off = 0;
  auto alloc = [&](size_t bytes) { size_t r = off; off = (off + bytes + 255) & ~(size_t)255; return r; };
  unsigned short* hpAh = (unsigned short*)(ws + alloc((size_t)Nn * 64 * 2));
  unsigned short* hpAl = (unsigned short*)(ws + alloc((size_t)Nn * 64 * 2));
  unsigned short* hpBh = (unsigned short*)(ws + alloc((size_t)Nn * 64 * 2));
  unsigned short* hpBl = (unsigned short*)(ws + alloc((size_t)Nn * 64 * 2));
  unsigned short* Aih  = (unsigned short*)(ws + alloc((size_t)Nn * 96 * 2));
  unsigned short* Ail  = (unsigned short*)(ws + alloc((size_t)Nn * 96 * 2));
  unsigned short* Sh   = (unsigned short*)(ws + alloc((size_t)Nn * 64 * 2));
  unsigned short* Sl   = (unsigned short*)(ws + alloc((size_t)Nn * 64 * 2));
  int*   rp    = (int*)(ws + alloc((size_t)(Nn + 1) * 4));
  int*   srcs  = (int*)(ws + alloc((size_t)Ne * 4));
  int*   gcur  = (int*)(ws + alloc((size_t)NB * 16 * 4));
  int*   payload = (int*)(ws + alloc((size_t)NB * BCAP * 4));
  int*   gp    = (int*)(ws + alloc((size_t)(Bg + 1) * 4));
  float* WihT  = (float*)(ws + alloc((size_t)128 * 256 * 4));
  float* WhhT  = (float*)(ws + alloc((size_t)64 * 256 * 4));
  float* W1T   = (float*)(ws + alloc((size_t)128 * 64 * 4));
  float* vfold = (float*)(ws + alloc(192 * 4));
  unsigned short* mlp_h = (unsigned short*)(ws + alloc(2048 * 2));
  unsigned short* mlp_l = (unsigned short*)(ws + alloc(2048 * 2));
  unsigned short* gw_h  = (unsigned short*)(ws + alloc(30720 * 2));
  unsigned short* gw_l  = (unsigned short*)(ws + alloc(30720 * 2));
  (void)in_sizes; (void)n_in; (void)out_size; (void)ws_size;

  hipMemsetAsync(gcur, 0, (size_t)NB * 16 * 4, stream);

  // CSR build (bucket sort) + prep (incl. W_conv folding)
  k_bucket<<<Ne / 4096, 256, 0, stream>>>(eidx, gcur, payload);
  k_placeB<<<NB, 256, 0, stream>>>(gcur, payload, rp, srcs);
  k_prepw<<<355, 256, 0, stream>>>(W_mlp, W_conv, gW_ih, gW_hh, b_conv,
                                   lW_ih, lW_hh, W1,
                                   mlp_h, mlp_l, gw_h, gw_l,
                                   WihT, WhhT, W1T, vfold, batch, gp, rp);

  // conv1 (+ x-column planes)
  k_conv1<<<Nn / 64, 256, 0, stream>>>(x, mlp_h, mlp_l, b_mlp, hpAh, hpAl, Aih, Ail);

  unsigned short *cph = hpAh, *cpl = hpAl, *nph = hpBh, *npl = hpBl;
  for (int step = 0; step < 2; ++step) {
    k_aggr<<<Nn / 4, 256, 0, stream>>>(cph, rp, srcs, Sh, Sl);
    k_gru<<<Nn / 128, 256, 0, stream>>>(Aih, Ail, cph, cpl, Sh, Sl, gw_h, gw_l,
                                        gb_ih, gb_hh, vfold, rp, nph, npl);
    unsigned short* tu;
    tu = cph; cph = nph; nph = tu;
    tu = cpl; cpl = npl; npl = tu;
  }

  // Set2Set: all 3 iterations + head, one launch, 512 threads,
  // 448*68*4 = 121856 B dynamic LDS (padded rows)
  const size_t dynLds = (size_t)LCAP * LPAD * sizeof(float);
  static bool attr_set = false;
  if (!attr_set) {
    hipFuncSetAttribute((const void*)k_s2s,
                        hipFuncAttributeMaxDynamicSharedMemorySize,
                        (int)dynLds);
    attr_set = true;
  }
  k_s2s<<<Bg, S2T, dynLds, stream>>>(cph, cpl, gp, WihT, WhhT,
                                     lb_ih, lb_hh, W1T, b1, W2, b2, outp);
}

// Round 9
// 291.177 us; speedup vs baseline: 1.1879x; 1.0344x over previous
//
#include <hip/hip_runtime.h>
#include <math.h>

constexpr int Nn  = 65536;    // nodes
constexpr int Ne  = 1048576;  // edges
constexpr int Bg  = 256;      // graphs
constexpr int DIN = 32;
constexpr int D   = 64;

constexpr int NB   = 256;     // dst buckets (dst>>8)
constexpr int BCAP = 6144;    // bucket stream capacity (mean 4096, +36 sigma)

typedef __attribute__((ext_vector_type(8))) short bf16x8;
typedef __attribute__((ext_vector_type(8))) unsigned short u16x8;
typedef __attribute__((ext_vector_type(4))) float f32x4;

__device__ __forceinline__ float sigf(float x) { return 1.0f / (1.0f + expf(-x)); }

// ---- bf16 split helpers (RNE) ----
__device__ __forceinline__ unsigned short bf16_rne(float f) {
  unsigned u = __float_as_uint(f);
  unsigned r = u + 0x7FFFu + ((u >> 16) & 1u);
  return (unsigned short)(r >> 16);
}
__device__ __forceinline__ float bf16_tof(unsigned short h) {
  return __uint_as_float(((unsigned)h) << 16);
}
__device__ __forceinline__ void split2(float f, unsigned short& hi, unsigned short& lo) {
  hi = bf16_rne(f);
  lo = bf16_rne(f - bf16_tof(hi));
}
__device__ __forceinline__ float recon(unsigned short hi, unsigned short lo) {
  return bf16_tof(hi) + bf16_tof(lo);
}

#define MFMA(a, b, c) __builtin_amdgcn_mfma_f32_16x16x32_bf16(a, b, c, 0, 0, 0)

// ---------------------------------------------------------------------------
// Prep.  GRU weights chunk-major (5 chunks x 12nt x 64lane x 8j / plane):
//   chunks 0,1 = Wfold = Wih[:, :64] @ W_conv   (fused conv-linear)
//   chunk  2   = Wih[:, 64:96]  (x part)
//   chunks 3,4 = Whh
// Also: W_mlp pack, LSTM/W1 transposes, graphptr, rp[Nn], vfold.
// ---------------------------------------------------------------------------
__global__ void k_prepw(const float* __restrict__ W_mlp, const float* __restrict__ W_conv,
                        const float* __restrict__ gWih, const float* __restrict__ gWhh,
                        const float* __restrict__ b_conv,
                        const float* __restrict__ lW_ih, const float* __restrict__ lW_hh,
                        const float* __restrict__ W1,
                        unsigned short* __restrict__ mlp_h, unsigned short* __restrict__ mlp_l,
                        unsigned short* __restrict__ gw_h,  unsigned short* __restrict__ gw_l,
                        float* __restrict__ WihT, float* __restrict__ WhhT,
                        float* __restrict__ W1T, float* __restrict__ vfold,
                        const int* __restrict__ batch, int* __restrict__ gp,
                        int* __restrict__ rp) {
  int idx = blockIdx.x * 256 + threadIdx.x;
  if (idx < 30720) {  // GRU weights, chunk-major
    int c = idx / 6144, rem = idx % 6144;
    int nt = rem >> 9, lane = (rem >> 3) & 63, j = rem & 7;
    int n = nt * 16 + (lane & 15);
    int kk = c * 32 + (lane >> 4) * 8 + j;   // for c<3: k index into [S|x]
    float v;
    if (c < 2) {        // Wfold[n][kk] = sum_o Wih[n][o] * W_conv[o][kk]
      float s = 0.f;
      for (int o = 0; o < 64; ++o) s = fmaf(gWih[n * 96 + o], W_conv[o * 64 + kk], s);
      v = s;
    } else if (c == 2) {
      v = gWih[n * 96 + kk];                 // kk in 64..95 (x columns)
    } else {
      v = gWhh[n * 64 + (c - 3) * 32 + (lane >> 4) * 8 + j];
    }
    unsigned short hi, lo; split2(v, hi, lo);
    gw_h[idx] = hi; gw_l[idx] = lo;
    return;
  }
  if (idx < 32768) {  // W_mlp (KS=1)
    int lp = idx - 30720;
    int nt = lp >> 9, lane = (lp >> 3) & 63, j = lp & 7;
    int n = nt * 16 + (lane & 15);
    unsigned short hi, lo;
    split2(W_mlp[n * 32 + (lane >> 4) * 8 + j], hi, lo);
    mlp_h[lp] = hi; mlp_l[lp] = lo;
    return;
  }
  int t = idx - 32768;
  if (t < 32768) {                 // lstm W_ih [256][128] -> WihT [128][256]
    int row = t / 128, k = t % 128;
    WihT[k * 256 + row] = lW_ih[t];
  } else if (t < 49152) {          // lstm W_hh [256][64] -> WhhT [64][256]
    int j = t - 32768;
    int row = j / 64, k = j % 64;
    WhhT[k * 256 + row] = lW_hh[j];
  } else if (t < 57344) {          // W1 [64][128] -> W1T [128][64]
    int j = t - 49152;
    int row = j / 128, k = j % 128;
    W1T[k * 64 + row] = W1[j];
  } else if (t < 57344 + Bg + 1) { // graphptr + rp[Nn]
    int g = t - 57344;
    if (g == 0) rp[Nn] = Ne;
    int lo = 0, hi = Nn;
    while (lo < hi) {
      int mid = (lo + hi) >> 1;
      if (batch[mid] < g) lo = mid + 1; else hi = mid;
    }
    gp[g] = lo;
  } else if (t < 57344 + 257 + 192) { // vfold[192]
    int g = t - 57344 - 257;
    float s = 0.f;
    for (int o = 0; o < 64; ++o) s = fmaf(gWih[g * 96 + o], b_conv[o], s);
    vfold[g] = s;
  }
}

// ---------------------------------------------------------------------------
// conv1: h = x @ W_mlp^T + b  (K=32, N=64). Splits x in-kernel; also fills
// inp96 x-columns (64..95).  h stored as planes only.
// ---------------------------------------------------------------------------
__global__ __launch_bounds__(256) void k_conv1(const float* __restrict__ x,
                                               const unsigned short* __restrict__ Wh,
                                               const unsigned short* __restrict__ Wl,
                                               const float* __restrict__ bias,
                                               unsigned short* __restrict__ hph,
                                               unsigned short* __restrict__ hpl,
                                               unsigned short* __restrict__ Aih,
                                               unsigned short* __restrict__ Ail) {
  int wave = threadIdx.x >> 6, lane = threadIdx.x & 63;
  int quad = lane >> 4;
  int n0w = blockIdx.x * 64 + wave * 16;
  int rowA = n0w + (lane & 15);
  const float4* xp = (const float4*)&x[(size_t)rowA * 32 + quad * 8];
  float4 xa = xp[0], xb = xp[1];
  float xv[8] = {xa.x, xa.y, xa.z, xa.w, xb.x, xb.y, xb.z, xb.w};
  bf16x8 ah, al;
#pragma unroll
  for (int j = 0; j < 8; ++j) {
    unsigned short hi, lo; split2(xv[j], hi, lo);
    ah[j] = (short)hi; al[j] = (short)lo;
  }
  *(bf16x8*)&Aih[(size_t)rowA * 96 + 64 + quad * 8] = ah;
  *(bf16x8*)&Ail[(size_t)rowA * 96 + 64 + quad * 8] = al;

  f32x4 acc[4] = {};
#pragma unroll
  for (int nt = 0; nt < 4; ++nt) {
    bf16x8 bh = *(const bf16x8*)&Wh[(nt * 64 + lane) * 8];
    bf16x8 bl = *(const bf16x8*)&Wl[(nt * 64 + lane) * 8];
    acc[nt] = MFMA(ah, bh, acc[nt]);
    acc[nt] = MFMA(ah, bl, acc[nt]);
    acc[nt] = MFMA(al, bh, acc[nt]);
  }
  int col0 = lane & 15;
#pragma unroll
  for (int nt = 0; nt < 4; ++nt) {
    float bv = bias[nt * 16 + col0];
#pragma unroll
    for (int r = 0; r < 4; ++r) {
      int node = n0w + quad * 4 + r;
      float v = acc[nt][r] + bv;
      size_t o = (size_t)node * 64 + nt * 16 + col0;
      unsigned short hi, lo; split2(v, hi, lo);
      hph[o] = hi; hpl[o] = lo;
    }
  }
}

// ---------------------------------------------------------------------------
// Fused GRU (round-1 v8, measured 52 us/step): aggregate gather fused in,
// 4-deep edge batching (all loads issued before accumulation, accumulation
// strictly in edge order).  The round-2..8 split (k_aggr + S planes) was a
// net regression: budget arithmetic put aggr+gru at ~78 us/step vs 52 fused.
// (256,2): VGPR 128 fits 2 blocks/CU.
// ---------------------------------------------------------------------------
__global__ __launch_bounds__(256, 2) void k_gru(const unsigned short* __restrict__ Aih,
                                                const unsigned short* __restrict__ Ail,
                                                const unsigned short* __restrict__ Hh,
                                                const unsigned short* __restrict__ Hl,
                                                const unsigned short* __restrict__ gw_h,
                                                const unsigned short* __restrict__ gw_l,
                                                const float* __restrict__ b_ih,
                                                const float* __restrict__ b_hh,
                                                const float* __restrict__ vfold,
                                                const int* __restrict__ rp,
                                                const int* __restrict__ srcs,
                                                unsigned short* __restrict__ nph,
                                                unsigned short* __restrict__ npl) {
  __shared__ unsigned short sW[2][12288];  // per buf: hi[0..6143] | lo[6144..]
  int tid = threadIdx.x;
  int wave = tid >> 6, lane = tid & 63;
  int quad = lane >> 4;
  int n0w = blockIdx.x * 128 + wave * 32;
  int rowA0 = n0w + (lane & 15);          // tile0 A-row; tile1 = +16

  // ---- fused aggregate: gather S fragments for chunks 0,1, both tiles ----
  bf16x8 fh[2][2], fl[2][2];  // [tile][chunk]
  const size_t q8 = (size_t)(quad * 8);
#pragma unroll
  for (int tile = 0; tile < 2; ++tile) {
    int row = rowA0 + tile * 16;
    int s = rp[row], e = rp[row + 1];
    int n = e - s;
    const int* sp = srcs + s;
    float acc0[8] = {}, acc1[8] = {};
    int i = 0;
    // 4-deep batched main loop: all loads issued before any accumulation,
    // accumulation strictly in edge order (bitwise == serial version).
    for (; i + 4 <= n; i += 4) {
      int s0 = sp[i], s1 = sp[i + 1], s2 = sp[i + 2], s3 = sp[i + 3];
      u16x8 a0 = *(const u16x8*)&Hh[(size_t)s0 * 64 + q8];
      u16x8 b0 = *(const u16x8*)&Hh[(size_t)s0 * 64 + 32 + q8];
      u16x8 a1 = *(const u16x8*)&Hh[(size_t)s1 * 64 + q8];
      u16x8 b1 = *(const u16x8*)&Hh[(size_t)s1 * 64 + 32 + q8];
      u16x8 a2 = *(const u16x8*)&Hh[(size_t)s2 * 64 + q8];
      u16x8 b2 = *(const u16x8*)&Hh[(size_t)s2 * 64 + 32 + q8];
      u16x8 a3 = *(const u16x8*)&Hh[(size_t)s3 * 64 + q8];
      u16x8 b3 = *(const u16x8*)&Hh[(size_t)s3 * 64 + 32 + q8];
#pragma unroll
      for (int j = 0; j < 8; ++j) {
        acc0[j] += bf16_tof(a0[j]);
        acc1[j] += bf16_tof(b0[j]);
      }
#pragma unroll
      for (int j = 0; j < 8; ++j) {
        acc0[j] += bf16_tof(a1[j]);
        acc1[j] += bf16_tof(b1[j]);
      }
#pragma unroll
      for (int j = 0; j < 8; ++j) {
        acc0[j] += bf16_tof(a2[j]);
        acc1[j] += bf16_tof(b2[j]);
      }
#pragma unroll
      for (int j = 0; j < 8; ++j) {
        acc0[j] += bf16_tof(a3[j]);
        acc1[j] += bf16_tof(b3[j]);
      }
    }
    for (; i < n; ++i) {
      int src = sp[i];
      u16x8 v0 = *(const u16x8*)&Hh[(size_t)src * 64 + q8];
      u16x8 v1 = *(const u16x8*)&Hh[(size_t)src * 64 + 32 + q8];
#pragma unroll
      for (int j = 0; j < 8; ++j) {
        acc0[j] += bf16_tof(v0[j]);
        acc1[j] += bf16_tof(v1[j]);
      }
    }
#pragma unroll
    for (int j = 0; j < 8; ++j) {
      unsigned short hi, lo;
      split2(acc0[j], hi, lo);
      fh[tile][0][j] = (short)hi; fl[tile][0][j] = (short)lo;
      split2(acc1[j], hi, lo);
      fh[tile][1][j] = (short)hi; fl[tile][1][j] = (short)lo;
    }
  }

  f32x4 acc0[12] = {}, acc1[12] = {};     // gi r,z,n (gh r,z folded into 0..7)
  f32x4 aN0[4] = {}, aN1[4] = {};         // gh n-gate

  // prologue: weights chunk 0
  bf16x8 gvh[3], gvl[3];
#pragma unroll
  for (int j = 0; j < 3; ++j) {
    gvh[j] = *(const bf16x8*)&gw_h[(tid + j * 256) * 8];
    gvl[j] = *(const bf16x8*)&gw_l[(tid + j * 256) * 8];
  }
#pragma unroll
  for (int j = 0; j < 3; ++j) {
    *(bf16x8*)&sW[0][(tid + j * 256) * 8] = gvh[j];
    *(bf16x8*)&sW[0][6144 + (tid + j * 256) * 8] = gvl[j];
  }
  __syncthreads();

#pragma unroll
  for (int c = 0; c < 5; ++c) {
    const int buf = c & 1;
    if (c < 4) {  // prefetch chunk c+1 weights
#pragma unroll
      for (int j = 0; j < 3; ++j) {
        gvh[j] = *(const bf16x8*)&gw_h[(c + 1) * 6144 + (tid + j * 256) * 8];
        gvl[j] = *(const bf16x8*)&gw_l[(c + 1) * 6144 + (tid + j * 256) * 8];
      }
    }
    // A fragments
    bf16x8 a0h, a0l, a1h, a1l;
    if (c < 2) {            // gathered S fragments (registers)
      a0h = fh[0][c]; a0l = fl[0][c];
      a1h = fh[1][c]; a1l = fl[1][c];
    } else if (c == 2) {    // x columns from conv1 prep
      size_t b0 = (size_t)rowA0 * 96 + 64 + quad * 8;
      size_t b1 = (size_t)(rowA0 + 16) * 96 + 64 + quad * 8;
      a0h = *(const bf16x8*)&Aih[b0]; a0l = *(const bf16x8*)&Ail[b0];
      a1h = *(const bf16x8*)&Aih[b1]; a1l = *(const bf16x8*)&Ail[b1];
    } else {                // h planes (Whh chunks)
      size_t b0 = (size_t)rowA0 * 64 + (c - 3) * 32 + quad * 8;
      size_t b1 = (size_t)(rowA0 + 16) * 64 + (c - 3) * 32 + quad * 8;
      a0h = *(const bf16x8*)&Hh[b0]; a0l = *(const bf16x8*)&Hl[b0];
      a1h = *(const bf16x8*)&Hh[b1]; a1l = *(const bf16x8*)&Hl[b1];
    }
    const unsigned short* sw = sW[buf];
#pragma unroll
    for (int nt = 0; nt < 12; ++nt) {
      bf16x8 bh = *(const bf16x8*)&sw[(nt * 64 + lane) * 8];
      bf16x8 bl = *(const bf16x8*)&sw[6144 + (nt * 64 + lane) * 8];
      if (c < 3 || nt < 8) {
        acc0[nt] = MFMA(a0h, bh, acc0[nt]);
        acc0[nt] = MFMA(a0h, bl, acc0[nt]);
        acc0[nt] = MFMA(a0l, bh, acc0[nt]);
        acc1[nt] = MFMA(a1h, bh, acc1[nt]);
        acc1[nt] = MFMA(a1h, bl, acc1[nt]);
        acc1[nt] = MFMA(a1l, bh, acc1[nt]);
      } else {
        aN0[nt - 8] = MFMA(a0h, bh, aN0[nt - 8]);
        aN0[nt - 8] = MFMA(a0h, bl, aN0[nt - 8]);
        aN0[nt - 8] = MFMA(a0l, bh, aN0[nt - 8]);
        aN1[nt - 8] = MFMA(a1h, bh, aN1[nt - 8]);
        aN1[nt - 8] = MFMA(a1h, bl, aN1[nt - 8]);
        aN1[nt - 8] = MFMA(a1l, bh, aN1[nt - 8]);
      }
    }
    if (c < 4) {
#pragma unroll
      for (int j = 0; j < 3; ++j) {
        *(bf16x8*)&sW[1 - buf][(tid + j * 256) * 8] = gvh[j];
        *(bf16x8*)&sW[1 - buf][6144 + (tid + j * 256) * 8] = gvl[j];
      }
    }
    __syncthreads();
  }

  // epilogue: GRU nonlinearity + deg*vfold (folded conv bias) + plane store
  int col0 = lane & 15;
#pragma unroll
  for (int tile = 0; tile < 2; ++tile) {
    int nb = n0w + tile * 16;
#pragma unroll
    for (int r = 0; r < 4; ++r) {
      int node = nb + quad * 4 + r;
      float degf = (float)(rp[node + 1] - rp[node]);
#pragma unroll
      for (int nt = 0; nt < 4; ++nt) {
        int g = nt * 16 + col0;
        size_t o = (size_t)node * 64 + g;
        float br  = b_ih[g] + b_hh[g] + degf * vfold[g];
        float bz  = b_ih[64 + g] + b_hh[64 + g] + degf * vfold[64 + g];
        float bin = b_ih[128 + g] + degf * vfold[128 + g];
        float bhn = b_hh[128 + g];
        float gr = tile ? acc1[nt][r]     : acc0[nt][r];
        float gz = tile ? acc1[nt + 4][r] : acc0[nt + 4][r];
        float gn = tile ? acc1[nt + 8][r] : acc0[nt + 8][r];
        float hn = tile ? aN1[nt][r]      : aN0[nt][r];
        float rr = sigf(gr + br);
        float zz = sigf(gz + bz);
        float nn = tanhf(gn + bin + rr * (hn + bhn));
        float h_old = recon(Hh[o], Hl[o]);
        float hv = (1.f - zz) * nn + zz * h_old;
        unsigned short hi, lo; split2(hv, hi, lo);
        nph[o] = hi; npl[o] = lo;
      }
    }
  }
}

// ---------------------------------------------------------------------------
// CSR build v3: two-level bucket sort by dst.
// ---------------------------------------------------------------------------
__global__ __launch_bounds__(256) void k_bucket(const int* __restrict__ eidx,
                                                int* __restrict__ gcur,     // [NB*16]
                                                int* __restrict__ payload) {// [NB*BCAP]
  __shared__ int lcnt[NB];
  __shared__ int lcur[NB];
  int t = threadIdx.x;
  int e0 = blockIdx.x * 4096;
  lcnt[t] = 0;
  __syncthreads();
  int ds[16], ss[16];
#pragma unroll
  for (int i = 0; i < 16; ++i) {
    int e = e0 + i * 256 + t;
    ds[i] = eidx[Ne + e];
    ss[i] = eidx[e];
    atomicAdd(&lcnt[ds[i] >> 8], 1);
  }
  __syncthreads();
  lcur[t] = atomicAdd(&gcur[t * 16], lcnt[t]);  // reserve contiguous run
  __syncthreads();
#pragma unroll
  for (int i = 0; i < 16; ++i) {
    int b = ds[i] >> 8;
    int p = atomicAdd(&lcur[b], 1);
    if (p < BCAP) payload[b * BCAP + p] = (ss[i] << 8) | (ds[i] & 255);
  }
}

// One block per bucket: inline scan of gcur -> base, LDS hist -> rp slice,
// place srcs via LDS cursors (scatter window owned by one CU).
__global__ __launch_bounds__(256) void k_placeB(const int* __restrict__ gcur,
                                                const int* __restrict__ payload,
                                                int* __restrict__ rp,
                                                int* __restrict__ srcs) {
  __shared__ int sAll[NB];
  __shared__ int hst[NB];
  __shared__ int cur[NB];
  int b = blockIdx.x, t = threadIdx.x;
  sAll[t] = gcur[t * 16];
  hst[t] = 0;
  __syncthreads();
  int cnt = min(sAll[b], BCAP);
  for (int off = 1; off < NB; off <<= 1) {
    int v = (t >= off) ? sAll[t - off] : 0;
    __syncthreads();
    sAll[t] += v;
    __syncthreads();
  }
  int base = sAll[b] - gcur[b * 16];  // exclusive prefix (true counts)
  const int* pay = &payload[b * BCAP];
  for (int i = t; i < cnt; i += 256) atomicAdd(&hst[pay[i] & 255], 1);
  __syncthreads();
  int c = hst[t];
  cur[t] = c;
  __syncthreads();
  for (int off = 1; off < NB; off <<= 1) {
    int v = (t >= off) ? cur[t - off] : 0;
    __syncthreads();
    cur[t] += v;
    __syncthreads();
  }
  int excl = cur[t] - c;
  rp[b * 256 + t] = base + excl;
  cur[t] = base + excl;
  __syncthreads();
  for (int i = t; i < cnt; i += 256) {
    int pl = pay[i];
    int p = atomicAdd(&cur[pl & 255], 1);
    srcs[p] = pl >> 8;
  }
}

// ---------------------------------------------------------------------------
// Fused Set2Set (round-8, measured 56.7 us): all 3 iterations + head, one
// launch, 512 threads, h rows staged to f32 in dynamic LDS, per-wave emax.
// At its dependent-chain floor for this structure -- left untouched.
// ---------------------------------------------------------------------------
constexpr int LCAP = 448;
constexpr int LPAD = 68;    // padded hL row stride in floats
constexpr int S2T  = 512;   // threads (8 waves)
__global__ __launch_bounds__(S2T) void k_s2s(const unsigned short* __restrict__ hph,
                                             const unsigned short* __restrict__ hpl,
                                             const int* __restrict__ gp,
                                             const float* __restrict__ WihT,
                                             const float* __restrict__ WhhT,
                                             const float* __restrict__ b_ih,
                                             const float* __restrict__ b_hh,
                                             const float* __restrict__ W1T,
                                             const float* __restrict__ b1,
                                             const float* __restrict__ W2,
                                             const float* __restrict__ b2,
                                             float* __restrict__ outp) {
  extern __shared__ float hL[];   // [LCAP][LPAD] f32 staged h
  int g = blockIdx.x;
  int t = threadIdx.x;
  int w = t >> 6, lane = t & 63;
  __shared__ float qstar_s[128];  // [q | r] carried across iterations
  __shared__ float hs[64], cs[64], gates[256];
  __shared__ float eL[LCAP];
  __shared__ float partial[8][64];
  __shared__ float asum_p[8];
  __shared__ float l4[4];
  __shared__ float hid[64];

  if (t < 128) qstar_s[t] = 0.f;
  if (t < 64) { hs[t] = 0.f; cs[t] = 0.f; }
  int s = gp[g], e = gp[g + 1];
  int cnt = e - s;

  // ---- stage h rows once: hL[nd*LPAD+col] = recon(hph, hpl) ----
  {
    int total = cnt * 64;
    for (int j = t * 4; j < total; j += S2T * 4) {
      int nd = j >> 6, col = j & 63;
      ushort4 hh = *(const ushort4*)&hph[(size_t)s * 64 + j];
      ushort4 ll = *(const ushort4*)&hpl[(size_t)s * 64 + j];
      float4 v;
      v.x = recon(hh.x, ll.x); v.y = recon(hh.y, ll.y);
      v.z = recon(hh.z, ll.z); v.w = recon(hh.w, ll.w);
      *(float4*)&hL[nd * LPAD + col] = v;
    }
  }

  for (int it = 0; it < 3; ++it) {
    __syncthreads();   // state + staged hL visible

    // ---- LSTM cell (first 4 waves) ----
    if (t < 256) {
      float acc = b_ih[t] + b_hh[t];
      for (int k = 0; k < 128; ++k) acc = fmaf(WihT[k * 256 + t], qstar_s[k], acc);
      for (int k = 0; k < 64; ++k)  acc = fmaf(WhhT[k * 256 + t], hs[k], acc);
      gates[t] = acc;
    }
    __syncthreads();
    if (t < 64) {
      float ig = sigf(gates[t]),        fg = sigf(gates[64 + t]);
      float gg = tanhf(gates[128 + t]), og = sigf(gates[192 + t]);
      float c = fg * cs[t] + ig * gg;
      float q = og * tanhf(c);
      cs[t] = c;
      hs[t] = q;
      qstar_s[t] = q;
    }
    __syncthreads();

    // ---- attention phase A: e_i = h[i].q ----
    int c4 = (lane & 15) * 4;
    float4 qv = {qstar_s[c4], qstar_s[c4 + 1], qstar_s[c4 + 2], qstar_s[c4 + 3]};
    for (int i0 = s + w * 4; i0 < e; i0 += 32) {
      int node = i0 + (lane >> 4);
      float p = 0.f;
      if (node < e) {
        float4 hv = *(const float4*)&hL[(node - s) * LPAD + c4];
        p = hv.x * qv.x + hv.y * qv.y + hv.z * qv.z + hv.w * qv.w;
      }
      p += __shfl_xor(p, 1); p += __shfl_xor(p, 2);
      p += __shfl_xor(p, 4); p += __shfl_xor(p, 8);
      if (node < e && (lane & 15) == 0) eL[node - s] = p;
    }
    __syncthreads();

    // ---- phase B: segment max, per-wave (order-invariant) ----
    float m = -INFINITY;
    for (int i = lane; i < cnt; i += 64) m = fmaxf(m, eL[i]);
#pragma unroll
    for (int o = 32; o >= 1; o >>= 1) m = fmaxf(m, __shfl_xor(m, o));
    float emax = isfinite(m) ? m : 0.f;

    // ---- phase C: softmax-weighted feature sum ----
    float acc = 0.f, asum = 0.f;
    for (int i = s + w; i < e; i += 8) {
      float a = expf(eL[i - s] - emax);
      asum += a;
      acc = fmaf(a, hL[(i - s) * LPAD + lane], acc);
    }
    partial[w][lane] = acc;
    if (lane == 0) asum_p[w] = asum;
    __syncthreads();
    if (t < 64) {
      float r = 0.f, as = 0.f;
      for (int q = 0; q < 8; ++q) { r += partial[q][t]; as += asum_p[q]; }
      float rv = (cnt > 0) ? r / fmaxf(as, 1e-16f) : 0.f;
      qstar_s[64 + t] = rv;
    }
  }
  __syncthreads();

  // ---- head ----
  if (t < 64) {
    float a1 = b1[t];
    for (int k = 0; k < 64; ++k)   a1 = fmaf(W1T[k * 64 + t], qstar_s[k], a1);
    for (int k = 64; k < 128; ++k) a1 = fmaf(W1T[k * 64 + t], qstar_s[k], a1);
    hid[t] = fmaxf(a1, 0.f);
  }
  __syncthreads();
  if (t < 4) {
    float lg = b2[t];
    for (int d = 0; d < 64; ++d) lg = fmaf(W2[t * 64 + d], hid[d], lg);
    l4[t] = lg;
  }
  __syncthreads();
  if (t < 4) {
    float mx = fmaxf(fmaxf(l4[0], l4[1]), fmaxf(l4[2], l4[3]));
    float ssum = expf(l4[0] - mx) + expf(l4[1] - mx) + expf(l4[2] - mx) + expf(l4[3] - mx);
    outp[g * 4 + t] = l4[t] - mx - logf(ssum);
  }
}

// ---------------------------------------------------------------------------
extern "C" void kernel_launch(void* const* d_in, const int* in_sizes, int n_in,
                              void* d_out, int out_size, void* d_ws, size_t ws_size,
                              hipStream_t stream) {
  const float* x        = (const float*)d_in[0];
  const int*   eidx     = (const int*)d_in[1];
  const int*   batch    = (const int*)d_in[2];
  const float* W_mlp    = (const float*)d_in[3];
  const float* b_mlp    = (const float*)d_in[4];
  const float* W_conv   = (const float*)d_in[5];
  const float* b_conv   = (const float*)d_in[6];
  const float* gW_ih    = (const float*)d_in[7];
  const float* gW_hh    = (const float*)d_in[8];
  const float* gb_ih    = (const float*)d_in[9];
  const float* gb_hh    = (const float*)d_in[10];
  const float* lW_ih    = (const float*)d_in[11];
  const float* lW_hh    = (const float*)d_in[12];
  const float* lb_ih    = (const float*)d_in[13];
  const float* lb_hh    = (const float*)d_in[14];
  const float* W1       = (const float*)d_in[15];
  const float* b1       = (const float*)d_in[16];
  const float* W2       = (const float*)d_in[17];
  const float* b2       = (const float*)d_in[18];
  float* outp = (float*)d_out;

  // ---- workspace layout ----
  char* ws = (char*)d_ws;
  size_t off = 0;
  auto alloc = [&](size_t bytes) { size_t r = off; off = (off + bytes + 255) & ~(size_t)255; return r; };
  unsigned short* hpAh = (unsigned short*)(ws + alloc((size_t)Nn * 64 * 2));
  unsigned short* hpAl = (unsigned short*)(ws + alloc((size_t)Nn * 64 * 2));
  unsigned short* hpBh = (unsigned short*)(ws + alloc((size_t)Nn * 64 * 2));
  unsigned short* hpBl = (unsigned short*)(ws + alloc((size_t)Nn * 64 * 2));
  unsigned short* Aih  = (unsigned short*)(ws + alloc((size_t)Nn * 96 * 2));
  unsigned short* Ail  = (unsigned short*)(ws + alloc((size_t)Nn * 96 * 2));
  int*   rp    = (int*)(ws + alloc((size_t)(Nn + 1) * 4));
  int*   srcs  = (int*)(ws + alloc((size_t)Ne * 4));
  int*   gcur  = (int*)(ws + alloc((size_t)NB * 16 * 4));
  int*   payload = (int*)(ws + alloc((size_t)NB * BCAP * 4));
  int*   gp    = (int*)(ws + alloc((size_t)(Bg + 1) * 4));
  float* WihT  = (float*)(ws + alloc((size_t)128 * 256 * 4));
  float* WhhT  = (float*)(ws + alloc((size_t)64 * 256 * 4));
  float* W1T   = (float*)(ws + alloc((size_t)128 * 64 * 4));
  float* vfold = (float*)(ws + alloc(192 * 4));
  unsigned short* mlp_h = (unsigned short*)(ws + alloc(2048 * 2));
  unsigned short* mlp_l = (unsigned short*)(ws + alloc(2048 * 2));
  unsigned short* gw_h  = (unsigned short*)(ws + alloc(30720 * 2));
  unsigned short* gw_l  = (unsigned short*)(ws + alloc(30720 * 2));
  (void)in_sizes; (void)n_in; (void)out_size; (void)ws_size;

  hipMemsetAsync(gcur, 0, (size_t)NB * 16 * 4, stream);

  // CSR build (bucket sort) + prep (incl. W_conv folding)
  k_bucket<<<Ne / 4096, 256, 0, stream>>>(eidx, gcur, payload);
  k_placeB<<<NB, 256, 0, stream>>>(gcur, payload, rp, srcs);
  k_prepw<<<355, 256, 0, stream>>>(W_mlp, W_conv, gW_ih, gW_hh, b_conv,
                                   lW_ih, lW_hh, W1,
                                   mlp_h, mlp_l, gw_h, gw_l,
                                   WihT, WhhT, W1T, vfold, batch, gp, rp);

  // conv1 (+ x-column planes)
  k_conv1<<<Nn / 64, 256, 0, stream>>>(x, mlp_h, mlp_l, b_mlp, hpAh, hpAl, Aih, Ail);

  unsigned short *cph = hpAh, *cpl = hpAl, *nph = hpBh, *npl = hpBl;
  for (int step = 0; step < 2; ++step) {
    k_gru<<<Nn / 128, 256, 0, stream>>>(Aih, Ail, cph, cpl, gw_h, gw_l,
                                        gb_ih, gb_hh, vfold, rp, srcs, nph, npl);
    unsigned short* tu;
    tu = cph; cph = nph; nph = tu;
    tu = cpl; cpl = npl; npl = tu;
  }

  // Set2Set: all 3 iterations + head, one launch, 512 threads,
  // 448*68*4 = 121856 B dynamic LDS (padded rows)
  const size_t dynLds = (size_t)LCAP * LPAD * sizeof(float);
  static bool attr_set = false;
  if (!attr_set) {
    hipFuncSetAttribute((const void*)k_s2s,
                        hipFuncAttributeMaxDynamicSharedMemorySize,
                        (int)dynLds);
    attr_set = true;
  }
  k_s2s<<<Bg, S2T, dynLds, stream>>>(cph, cpl, gp, WihT, WhhT,
                                     lb_ih, lb_hh, W1T, b1, W2, b2, outp);
}

// Round 10
// 277.245 us; speedup vs baseline: 1.2476x; 1.0503x over previous
//
#include <hip/hip_runtime.h>
#include <math.h>

constexpr int Nn  = 65536;    // nodes
constexpr int Ne  = 1048576;  // edges
constexpr int Bg  = 256;      // graphs
constexpr int DIN = 32;
constexpr int D   = 64;

constexpr int NB   = 256;     // dst buckets (dst>>8)
constexpr int BCAP = 6144;    // bucket stream capacity (mean 4096, +36 sigma)

typedef __attribute__((ext_vector_type(8))) short bf16x8;
typedef __attribute__((ext_vector_type(8))) unsigned short u16x8;
typedef __attribute__((ext_vector_type(4))) float f32x4;

__device__ __forceinline__ float sigf(float x) { return 1.0f / (1.0f + expf(-x)); }

// ---- bf16 split helpers (RNE) ----
__device__ __forceinline__ unsigned short bf16_rne(float f) {
  unsigned u = __float_as_uint(f);
  unsigned r = u + 0x7FFFu + ((u >> 16) & 1u);
  return (unsigned short)(r >> 16);
}
__device__ __forceinline__ float bf16_tof(unsigned short h) {
  return __uint_as_float(((unsigned)h) << 16);
}
__device__ __forceinline__ void split2(float f, unsigned short& hi, unsigned short& lo) {
  hi = bf16_rne(f);
  lo = bf16_rne(f - bf16_tof(hi));
}
__device__ __forceinline__ float recon(unsigned short hi, unsigned short lo) {
  return bf16_tof(hi) + bf16_tof(lo);
}

#define MFMA(a, b, c) __builtin_amdgcn_mfma_f32_16x16x32_bf16(a, b, c, 0, 0, 0)

// ---------------------------------------------------------------------------
// Prep.  GRU weights chunk-major (5 chunks x 12nt x 64lane x 8j / plane):
//   chunks 0,1 = Wfold = Wih[:, :64] @ W_conv   (fused conv-linear)
//   chunk  2   = Wih[:, 64:96]  (x part)
//   chunks 3,4 = Whh
// Also: W_mlp pack, LSTM/W1 transposes, graphptr, rp[Nn], vfold.
// ---------------------------------------------------------------------------
__global__ void k_prepw(const float* __restrict__ W_mlp, const float* __restrict__ W_conv,
                        const float* __restrict__ gWih, const float* __restrict__ gWhh,
                        const float* __restrict__ b_conv,
                        const float* __restrict__ lW_ih, const float* __restrict__ lW_hh,
                        const float* __restrict__ W1,
                        unsigned short* __restrict__ mlp_h, unsigned short* __restrict__ mlp_l,
                        unsigned short* __restrict__ gw_h,  unsigned short* __restrict__ gw_l,
                        float* __restrict__ WihT, float* __restrict__ WhhT,
                        float* __restrict__ W1T, float* __restrict__ vfold,
                        const int* __restrict__ batch, int* __restrict__ gp,
                        int* __restrict__ rp) {
  int idx = blockIdx.x * 256 + threadIdx.x;
  if (idx < 30720) {  // GRU weights, chunk-major
    int c = idx / 6144, rem = idx % 6144;
    int nt = rem >> 9, lane = (rem >> 3) & 63, j = rem & 7;
    int n = nt * 16 + (lane & 15);
    int kk = c * 32 + (lane >> 4) * 8 + j;   // for c<3: k index into [S|x]
    float v;
    if (c < 2) {        // Wfold[n][kk] = sum_o Wih[n][o] * W_conv[o][kk]
      float s = 0.f;
      for (int o = 0; o < 64; ++o) s = fmaf(gWih[n * 96 + o], W_conv[o * 64 + kk], s);
      v = s;
    } else if (c == 2) {
      v = gWih[n * 96 + kk];                 // kk in 64..95 (x columns)
    } else {
      v = gWhh[n * 64 + (c - 3) * 32 + (lane >> 4) * 8 + j];
    }
    unsigned short hi, lo; split2(v, hi, lo);
    gw_h[idx] = hi; gw_l[idx] = lo;
    return;
  }
  if (idx < 32768) {  // W_mlp (KS=1)
    int lp = idx - 30720;
    int nt = lp >> 9, lane = (lp >> 3) & 63, j = lp & 7;
    int n = nt * 16 + (lane & 15);
    unsigned short hi, lo;
    split2(W_mlp[n * 32 + (lane >> 4) * 8 + j], hi, lo);
    mlp_h[lp] = hi; mlp_l[lp] = lo;
    return;
  }
  int t = idx - 32768;
  if (t < 32768) {                 // lstm W_ih [256][128] -> WihT [128][256]
    int row = t / 128, k = t % 128;
    WihT[k * 256 + row] = lW_ih[t];
  } else if (t < 49152) {          // lstm W_hh [256][64] -> WhhT [64][256]
    int j = t - 32768;
    int row = j / 64, k = j % 64;
    WhhT[k * 256 + row] = lW_hh[j];
  } else if (t < 57344) {          // W1 [64][128] -> W1T [128][64]
    int j = t - 49152;
    int row = j / 128, k = j % 128;
    W1T[k * 64 + row] = W1[j];
  } else if (t < 57344 + Bg + 1) { // graphptr + rp[Nn]
    int g = t - 57344;
    if (g == 0) rp[Nn] = Ne;
    int lo = 0, hi = Nn;
    while (lo < hi) {
      int mid = (lo + hi) >> 1;
      if (batch[mid] < g) lo = mid + 1; else hi = mid;
    }
    gp[g] = lo;
  } else if (t < 57344 + 257 + 192) { // vfold[192]
    int g = t - 57344 - 257;
    float s = 0.f;
    for (int o = 0; o < 64; ++o) s = fmaf(gWih[g * 96 + o], b_conv[o], s);
    vfold[g] = s;
  }
}

// ---------------------------------------------------------------------------
// conv1: h = x @ W_mlp^T + b  (K=32, N=64). Splits x in-kernel; also fills
// inp96 x-columns (64..95).  h stored as planes only.
// ---------------------------------------------------------------------------
__global__ __launch_bounds__(256) void k_conv1(const float* __restrict__ x,
                                               const unsigned short* __restrict__ Wh,
                                               const unsigned short* __restrict__ Wl,
                                               const float* __restrict__ bias,
                                               unsigned short* __restrict__ hph,
                                               unsigned short* __restrict__ hpl,
                                               unsigned short* __restrict__ Aih,
                                               unsigned short* __restrict__ Ail) {
  int wave = threadIdx.x >> 6, lane = threadIdx.x & 63;
  int quad = lane >> 4;
  int n0w = blockIdx.x * 64 + wave * 16;
  int rowA = n0w + (lane & 15);
  const float4* xp = (const float4*)&x[(size_t)rowA * 32 + quad * 8];
  float4 xa = xp[0], xb = xp[1];
  float xv[8] = {xa.x, xa.y, xa.z, xa.w, xb.x, xb.y, xb.z, xb.w};
  bf16x8 ah, al;
#pragma unroll
  for (int j = 0; j < 8; ++j) {
    unsigned short hi, lo; split2(xv[j], hi, lo);
    ah[j] = (short)hi; al[j] = (short)lo;
  }
  *(bf16x8*)&Aih[(size_t)rowA * 96 + 64 + quad * 8] = ah;
  *(bf16x8*)&Ail[(size_t)rowA * 96 + 64 + quad * 8] = al;

  f32x4 acc[4] = {};
#pragma unroll
  for (int nt = 0; nt < 4; ++nt) {
    bf16x8 bh = *(const bf16x8*)&Wh[(nt * 64 + lane) * 8];
    bf16x8 bl = *(const bf16x8*)&Wl[(nt * 64 + lane) * 8];
    acc[nt] = MFMA(ah, bh, acc[nt]);
    acc[nt] = MFMA(ah, bl, acc[nt]);
    acc[nt] = MFMA(al, bh, acc[nt]);
  }
  int col0 = lane & 15;
#pragma unroll
  for (int nt = 0; nt < 4; ++nt) {
    float bv = bias[nt * 16 + col0];
#pragma unroll
    for (int r = 0; r < 4; ++r) {
      int node = n0w + quad * 4 + r;
      float v = acc[nt][r] + bv;
      size_t o = (size_t)node * 64 + nt * 16 + col0;
      unsigned short hi, lo; split2(v, hi, lo);
      hph[o] = hi; hpl[o] = lo;
    }
  }
}

// ---------------------------------------------------------------------------
// Fused GRU v10: round-9 fused kernel restructured to 512 threads / 8 waves,
// ONE 16-row tile per wave (was 4 waves x 2 tiles).  The grid (512 blocks =
// 2 blocks/CU) capped the old version at 2 waves/SIMD during the
// latency-bound gather; same block count with 8 waves = 4 waves/SIMD.
// Per-wave state halves (one accumulator set = 64 VGPRs) so the
// (512,4) 128-VGPR cap fits.  Per-node math identical -> bitwise output.
// LDS 48 KB x 2 blocks = 96 KB/CU.
// ---------------------------------------------------------------------------
__global__ __launch_bounds__(512, 4) void k_gru(const unsigned short* __restrict__ Aih,
                                                const unsigned short* __restrict__ Ail,
                                                const unsigned short* __restrict__ Hh,
                                                const unsigned short* __restrict__ Hl,
                                                const unsigned short* __restrict__ gw_h,
                                                const unsigned short* __restrict__ gw_l,
                                                const float* __restrict__ b_ih,
                                                const float* __restrict__ b_hh,
                                                const float* __restrict__ vfold,
                                                const int* __restrict__ rp,
                                                const int* __restrict__ srcs,
                                                unsigned short* __restrict__ nph,
                                                unsigned short* __restrict__ npl) {
  __shared__ unsigned short sW[2][12288];  // per buf: hi[0..6143] | lo[6144..]
  int tid = threadIdx.x;                   // 0..511
  int wave = tid >> 6, lane = tid & 63;
  int quad = lane >> 4;
  int rowA = blockIdx.x * 128 + wave * 16 + (lane & 15);  // this wave's tile row

  // ---- fused aggregate: gather S fragments for chunks 0,1 (one tile) ----
  bf16x8 fh[2], fl[2];  // [chunk]
  const size_t q8 = (size_t)(quad * 8);
  {
    int s = rp[rowA], e = rp[rowA + 1];
    int n = e - s;
    const int* sp = srcs + s;
    float acc0[8] = {}, acc1[8] = {};
    int i = 0;
    // 4-deep batched main loop: all loads issued before any accumulation,
    // accumulation strictly in edge order (bitwise == serial version).
    for (; i + 4 <= n; i += 4) {
      int s0 = sp[i], s1 = sp[i + 1], s2 = sp[i + 2], s3 = sp[i + 3];
      u16x8 a0 = *(const u16x8*)&Hh[(size_t)s0 * 64 + q8];
      u16x8 b0 = *(const u16x8*)&Hh[(size_t)s0 * 64 + 32 + q8];
      u16x8 a1 = *(const u16x8*)&Hh[(size_t)s1 * 64 + q8];
      u16x8 b1 = *(const u16x8*)&Hh[(size_t)s1 * 64 + 32 + q8];
      u16x8 a2 = *(const u16x8*)&Hh[(size_t)s2 * 64 + q8];
      u16x8 b2 = *(const u16x8*)&Hh[(size_t)s2 * 64 + 32 + q8];
      u16x8 a3 = *(const u16x8*)&Hh[(size_t)s3 * 64 + q8];
      u16x8 b3 = *(const u16x8*)&Hh[(size_t)s3 * 64 + 32 + q8];
#pragma unroll
      for (int j = 0; j < 8; ++j) {
        acc0[j] += bf16_tof(a0[j]);
        acc1[j] += bf16_tof(b0[j]);
      }
#pragma unroll
      for (int j = 0; j < 8; ++j) {
        acc0[j] += bf16_tof(a1[j]);
        acc1[j] += bf16_tof(b1[j]);
      }
#pragma unroll
      for (int j = 0; j < 8; ++j) {
        acc0[j] += bf16_tof(a2[j]);
        acc1[j] += bf16_tof(b2[j]);
      }
#pragma unroll
      for (int j = 0; j < 8; ++j) {
        acc0[j] += bf16_tof(a3[j]);
        acc1[j] += bf16_tof(b3[j]);
      }
    }
    for (; i < n; ++i) {
      int src = sp[i];
      u16x8 v0 = *(const u16x8*)&Hh[(size_t)src * 64 + q8];
      u16x8 v1 = *(const u16x8*)&Hh[(size_t)src * 64 + 32 + q8];
#pragma unroll
      for (int j = 0; j < 8; ++j) {
        acc0[j] += bf16_tof(v0[j]);
        acc1[j] += bf16_tof(v1[j]);
      }
    }
#pragma unroll
    for (int j = 0; j < 8; ++j) {
      unsigned short hi, lo;
      split2(acc0[j], hi, lo);
      fh[0][j] = (short)hi; fl[0][j] = (short)lo;
      split2(acc1[j], hi, lo);
      fh[1][j] = (short)hi; fl[1][j] = (short)lo;
    }
  }

  f32x4 acc[12] = {};     // gi r,z,n (gh r,z folded into 0..7)
  f32x4 aN[4] = {};       // gh n-gate

  // prologue: weights chunk 0 (768 16B-vectors staged by 512 threads)
  bf16x8 gvh0, gvl0, gvh1, gvl1;
  const bool two = (tid < 256);
  gvh0 = *(const bf16x8*)&gw_h[tid * 8];
  gvl0 = *(const bf16x8*)&gw_l[tid * 8];
  if (two) {
    gvh1 = *(const bf16x8*)&gw_h[(tid + 512) * 8];
    gvl1 = *(const bf16x8*)&gw_l[(tid + 512) * 8];
  }
  *(bf16x8*)&sW[0][tid * 8] = gvh0;
  *(bf16x8*)&sW[0][6144 + tid * 8] = gvl0;
  if (two) {
    *(bf16x8*)&sW[0][(tid + 512) * 8] = gvh1;
    *(bf16x8*)&sW[0][6144 + (tid + 512) * 8] = gvl1;
  }
  __syncthreads();

#pragma unroll
  for (int c = 0; c < 5; ++c) {
    const int buf = c & 1;
    if (c < 4) {  // prefetch chunk c+1 weights
      gvh0 = *(const bf16x8*)&gw_h[(c + 1) * 6144 + tid * 8];
      gvl0 = *(const bf16x8*)&gw_l[(c + 1) * 6144 + tid * 8];
      if (two) {
        gvh1 = *(const bf16x8*)&gw_h[(c + 1) * 6144 + (tid + 512) * 8];
        gvl1 = *(const bf16x8*)&gw_l[(c + 1) * 6144 + (tid + 512) * 8];
      }
    }
    // A fragment
    bf16x8 ah, al;
    if (c < 2) {            // gathered S fragments (registers)
      ah = fh[c]; al = fl[c];
    } else if (c == 2) {    // x columns from conv1 prep
      size_t b0 = (size_t)rowA * 96 + 64 + quad * 8;
      ah = *(const bf16x8*)&Aih[b0]; al = *(const bf16x8*)&Ail[b0];
    } else {                // h planes (Whh chunks)
      size_t b0 = (size_t)rowA * 64 + (c - 3) * 32 + quad * 8;
      ah = *(const bf16x8*)&Hh[b0]; al = *(const bf16x8*)&Hl[b0];
    }
    const unsigned short* sw = sW[buf];
#pragma unroll
    for (int nt = 0; nt < 12; ++nt) {
      bf16x8 bh = *(const bf16x8*)&sw[(nt * 64 + lane) * 8];
      bf16x8 bl = *(const bf16x8*)&sw[6144 + (nt * 64 + lane) * 8];
      if (c < 3 || nt < 8) {
        acc[nt] = MFMA(ah, bh, acc[nt]);
        acc[nt] = MFMA(ah, bl, acc[nt]);
        acc[nt] = MFMA(al, bh, acc[nt]);
      } else {
        aN[nt - 8] = MFMA(ah, bh, aN[nt - 8]);
        aN[nt - 8] = MFMA(ah, bl, aN[nt - 8]);
        aN[nt - 8] = MFMA(al, bh, aN[nt - 8]);
      }
    }
    if (c < 4) {
      *(bf16x8*)&sW[1 - buf][tid * 8] = gvh0;
      *(bf16x8*)&sW[1 - buf][6144 + tid * 8] = gvl0;
      if (two) {
        *(bf16x8*)&sW[1 - buf][(tid + 512) * 8] = gvh1;
        *(bf16x8*)&sW[1 - buf][6144 + (tid + 512) * 8] = gvl1;
      }
    }
    __syncthreads();
  }

  // epilogue: GRU nonlinearity + deg*vfold (folded conv bias) + plane store
  int col0 = lane & 15;
  int nb = blockIdx.x * 128 + wave * 16;
#pragma unroll
  for (int r = 0; r < 4; ++r) {
    int node = nb + quad * 4 + r;
    float degf = (float)(rp[node + 1] - rp[node]);
#pragma unroll
    for (int nt = 0; nt < 4; ++nt) {
      int g = nt * 16 + col0;
      size_t o = (size_t)node * 64 + g;
      float br  = b_ih[g] + b_hh[g] + degf * vfold[g];
      float bz  = b_ih[64 + g] + b_hh[64 + g] + degf * vfold[64 + g];
      float bin = b_ih[128 + g] + degf * vfold[128 + g];
      float bhn = b_hh[128 + g];
      float gr = acc[nt][r];
      float gz = acc[nt + 4][r];
      float gn = acc[nt + 8][r];
      float hn = aN[nt][r];
      float rr = sigf(gr + br);
      float zz = sigf(gz + bz);
      float nn = tanhf(gn + bin + rr * (hn + bhn));
      float h_old = recon(Hh[o], Hl[o]);
      float hv = (1.f - zz) * nn + zz * h_old;
      unsigned short hi, lo; split2(hv, hi, lo);
      nph[o] = hi; npl[o] = lo;
    }
  }
}

// ---------------------------------------------------------------------------
// CSR build v3: two-level bucket sort by dst.
// ---------------------------------------------------------------------------
__global__ __launch_bounds__(256) void k_bucket(const int* __restrict__ eidx,
                                                int* __restrict__ gcur,     // [NB*16]
                                                int* __restrict__ payload) {// [NB*BCAP]
  __shared__ int lcnt[NB];
  __shared__ int lcur[NB];
  int t = threadIdx.x;
  int e0 = blockIdx.x * 4096;
  lcnt[t] = 0;
  __syncthreads();
  int ds[16], ss[16];
#pragma unroll
  for (int i = 0; i < 16; ++i) {
    int e = e0 + i * 256 + t;
    ds[i] = eidx[Ne + e];
    ss[i] = eidx[e];
    atomicAdd(&lcnt[ds[i] >> 8], 1);
  }
  __syncthreads();
  lcur[t] = atomicAdd(&gcur[t * 16], lcnt[t]);  // reserve contiguous run
  __syncthreads();
#pragma unroll
  for (int i = 0; i < 16; ++i) {
    int b = ds[i] >> 8;
    int p = atomicAdd(&lcur[b], 1);
    if (p < BCAP) payload[b * BCAP + p] = (ss[i] << 8) | (ds[i] & 255);
  }
}

// One block per bucket: inline scan of gcur -> base, LDS hist -> rp slice,
// place srcs via LDS cursors (scatter window owned by one CU).
__global__ __launch_bounds__(256) void k_placeB(const int* __restrict__ gcur,
                                                const int* __restrict__ payload,
                                                int* __restrict__ rp,
                                                int* __restrict__ srcs) {
  __shared__ int sAll[NB];
  __shared__ int hst[NB];
  __shared__ int cur[NB];
  int b = blockIdx.x, t = threadIdx.x;
  sAll[t] = gcur[t * 16];
  hst[t] = 0;
  __syncthreads();
  int cnt = min(sAll[b], BCAP);
  for (int off = 1; off < NB; off <<= 1) {
    int v = (t >= off) ? sAll[t - off] : 0;
    __syncthreads();
    sAll[t] += v;
    __syncthreads();
  }
  int base = sAll[b] - gcur[b * 16];  // exclusive prefix (true counts)
  const int* pay = &payload[b * BCAP];
  for (int i = t; i < cnt; i += 256) atomicAdd(&hst[pay[i] & 255], 1);
  __syncthreads();
  int c = hst[t];
  cur[t] = c;
  __syncthreads();
  for (int off = 1; off < NB; off <<= 1) {
    int v = (t >= off) ? cur[t - off] : 0;
    __syncthreads();
    cur[t] += v;
    __syncthreads();
  }
  int excl = cur[t] - c;
  rp[b * 256 + t] = base + excl;
  cur[t] = base + excl;
  __syncthreads();
  for (int i = t; i < cnt; i += 256) {
    int pl = pay[i];
    int p = atomicAdd(&cur[pl & 255], 1);
    srcs[p] = pl >> 8;
  }
}

// ---------------------------------------------------------------------------
// Fused Set2Set (round-8, measured 56.7 us): all 3 iterations + head, one
// launch, 512 threads, h rows staged to f32 in dynamic LDS, per-wave emax.
// At its dependent-chain floor for this structure -- left untouched.
// ---------------------------------------------------------------------------
constexpr int LCAP = 448;
constexpr int LPAD = 68;    // padded hL row stride in floats
constexpr int S2T  = 512;   // threads (8 waves)
__global__ __launch_bounds__(S2T) void k_s2s(const unsigned short* __restrict__ hph,
                                             const unsigned short* __restrict__ hpl,
                                             const int* __restrict__ gp,
                                             const float* __restrict__ WihT,
                                             const float* __restrict__ WhhT,
                                             const float* __restrict__ b_ih,
                                             const float* __restrict__ b_hh,
                                             const float* __restrict__ W1T,
                                             const float* __restrict__ b1,
                                             const float* __restrict__ W2,
                                             const float* __restrict__ b2,
                                             float* __restrict__ outp) {
  extern __shared__ float hL[];   // [LCAP][LPAD] f32 staged h
  int g = blockIdx.x;
  int t = threadIdx.x;
  int w = t >> 6, lane = t & 63;
  __shared__ float qstar_s[128];  // [q | r] carried across iterations
  __shared__ float hs[64], cs[64], gates[256];
  __shared__ float eL[LCAP];
  __shared__ float partial[8][64];
  __shared__ float asum_p[8];
  __shared__ float l4[4];
  __shared__ float hid[64];

  if (t < 128) qstar_s[t] = 0.f;
  if (t < 64) { hs[t] = 0.f; cs[t] = 0.f; }
  int s = gp[g], e = gp[g + 1];
  int cnt = e - s;

  // ---- stage h rows once: hL[nd*LPAD+col] = recon(hph, hpl) ----
  {
    int total = cnt * 64;
    for (int j = t * 4; j < total; j += S2T * 4) {
      int nd = j >> 6, col = j & 63;
      ushort4 hh = *(const ushort4*)&hph[(size_t)s * 64 + j];
      ushort4 ll = *(const ushort4*)&hpl[(size_t)s * 64 + j];
      float4 v;
      v.x = recon(hh.x, ll.x); v.y = recon(hh.y, ll.y);
      v.z = recon(hh.z, ll.z); v.w = recon(hh.w, ll.w);
      *(float4*)&hL[nd * LPAD + col] = v;
    }
  }

  for (int it = 0; it < 3; ++it) {
    __syncthreads();   // state + staged hL visible

    // ---- LSTM cell (first 4 waves) ----
    if (t < 256) {
      float acc = b_ih[t] + b_hh[t];
      for (int k = 0; k < 128; ++k) acc = fmaf(WihT[k * 256 + t], qstar_s[k], acc);
      for (int k = 0; k < 64; ++k)  acc = fmaf(WhhT[k * 256 + t], hs[k], acc);
      gates[t] = acc;
    }
    __syncthreads();
    if (t < 64) {
      float ig = sigf(gates[t]),        fg = sigf(gates[64 + t]);
      float gg = tanhf(gates[128 + t]), og = sigf(gates[192 + t]);
      float c = fg * cs[t] + ig * gg;
      float q = og * tanhf(c);
      cs[t] = c;
      hs[t] = q;
      qstar_s[t] = q;
    }
    __syncthreads();

    // ---- attention phase A: e_i = h[i].q ----
    int c4 = (lane & 15) * 4;
    float4 qv = {qstar_s[c4], qstar_s[c4 + 1], qstar_s[c4 + 2], qstar_s[c4 + 3]};
    for (int i0 = s + w * 4; i0 < e; i0 += 32) {
      int node = i0 + (lane >> 4);
      float p = 0.f;
      if (node < e) {
        float4 hv = *(const float4*)&hL[(node - s) * LPAD + c4];
        p = hv.x * qv.x + hv.y * qv.y + hv.z * qv.z + hv.w * qv.w;
      }
      p += __shfl_xor(p, 1); p += __shfl_xor(p, 2);
      p += __shfl_xor(p, 4); p += __shfl_xor(p, 8);
      if (node < e && (lane & 15) == 0) eL[node - s] = p;
    }
    __syncthreads();

    // ---- phase B: segment max, per-wave (order-invariant) ----
    float m = -INFINITY;
    for (int i = lane; i < cnt; i += 64) m = fmaxf(m, eL[i]);
#pragma unroll
    for (int o = 32; o >= 1; o >>= 1) m = fmaxf(m, __shfl_xor(m, o));
    float emax = isfinite(m) ? m : 0.f;

    // ---- phase C: softmax-weighted feature sum ----
    float acc = 0.f, asum = 0.f;
    for (int i = s + w; i < e; i += 8) {
      float a = expf(eL[i - s] - emax);
      asum += a;
      acc = fmaf(a, hL[(i - s) * LPAD + lane], acc);
    }
    partial[w][lane] = acc;
    if (lane == 0) asum_p[w] = asum;
    __syncthreads();
    if (t < 64) {
      float r = 0.f, as = 0.f;
      for (int q = 0; q < 8; ++q) { r += partial[q][t]; as += asum_p[q]; }
      float rv = (cnt > 0) ? r / fmaxf(as, 1e-16f) : 0.f;
      qstar_s[64 + t] = rv;
    }
  }
  __syncthreads();

  // ---- head ----
  if (t < 64) {
    float a1 = b1[t];
    for (int k = 0; k < 64; ++k)   a1 = fmaf(W1T[k * 64 + t], qstar_s[k], a1);
    for (int k = 64; k < 128; ++k) a1 = fmaf(W1T[k * 64 + t], qstar_s[k], a1);
    hid[t] = fmaxf(a1, 0.f);
  }
  __syncthreads();
  if (t < 4) {
    float lg = b2[t];
    for (int d = 0; d < 64; ++d) lg = fmaf(W2[t * 64 + d], hid[d], lg);
    l4[t] = lg;
  }
  __syncthreads();
  if (t < 4) {
    float mx = fmaxf(fmaxf(l4[0], l4[1]), fmaxf(l4[2], l4[3]));
    float ssum = expf(l4[0] - mx) + expf(l4[1] - mx) + expf(l4[2] - mx) + expf(l4[3] - mx);
    outp[g * 4 + t] = l4[t] - mx - logf(ssum);
  }
}

// ---------------------------------------------------------------------------
extern "C" void kernel_launch(void* const* d_in, const int* in_sizes, int n_in,
                              void* d_out, int out_size, void* d_ws, size_t ws_size,
                              hipStream_t stream) {
  const float* x        = (const float*)d_in[0];
  const int*   eidx     = (const int*)d_in[1];
  const int*   batch    = (const int*)d_in[2];
  const float* W_mlp    = (const float*)d_in[3];
  const float* b_mlp    = (const float*)d_in[4];
  const float* W_conv   = (const float*)d_in[5];
  const float* b_conv   = (const float*)d_in[6];
  const float* gW_ih    = (const float*)d_in[7];
  const float* gW_hh    = (const float*)d_in[8];
  const float* gb_ih    = (const float*)d_in[9];
  const float* gb_hh    = (const float*)d_in[10];
  const float* lW_ih    = (const float*)d_in[11];
  const float* lW_hh    = (const float*)d_in[12];
  const float* lb_ih    = (const float*)d_in[13];
  const float* lb_hh    = (const float*)d_in[14];
  const float* W1       = (const float*)d_in[15];
  const float* b1       = (const float*)d_in[16];
  const float* W2       = (const float*)d_in[17];
  const float* b2       = (const float*)d_in[18];
  float* outp = (float*)d_out;

  // ---- workspace layout ----
  char* ws = (char*)d_ws;
  size_t off = 0;
  auto alloc = [&](size_t bytes) { size_t r = off; off = (off + bytes + 255) & ~(size_t)255; return r; };
  unsigned short* hpAh = (unsigned short*)(ws + alloc((size_t)Nn * 64 * 2));
  unsigned short* hpAl = (unsigned short*)(ws + alloc((size_t)Nn * 64 * 2));
  unsigned short* hpBh = (unsigned short*)(ws + alloc((size_t)Nn * 64 * 2));
  unsigned short* hpBl = (unsigned short*)(ws + alloc((size_t)Nn * 64 * 2));
  unsigned short* Aih  = (unsigned short*)(ws + alloc((size_t)Nn * 96 * 2));
  unsigned short* Ail  = (unsigned short*)(ws + alloc((size_t)Nn * 96 * 2));
  int*   rp    = (int*)(ws + alloc((size_t)(Nn + 1) * 4));
  int*   srcs  = (int*)(ws + alloc((size_t)Ne * 4));
  int*   gcur  = (int*)(ws + alloc((size_t)NB * 16 * 4));
  int*   payload = (int*)(ws + alloc((size_t)NB * BCAP * 4));
  int*   gp    = (int*)(ws + alloc((size_t)(Bg + 1) * 4));
  float* WihT  = (float*)(ws + alloc((size_t)128 * 256 * 4));
  float* WhhT  = (float*)(ws + alloc((size_t)64 * 256 * 4));
  float* W1T   = (float*)(ws + alloc((size_t)128 * 64 * 4));
  float* vfold = (float*)(ws + alloc(192 * 4));
  unsigned short* mlp_h = (unsigned short*)(ws + alloc(2048 * 2));
  unsigned short* mlp_l = (unsigned short*)(ws + alloc(2048 * 2));
  unsigned short* gw_h  = (unsigned short*)(ws + alloc(30720 * 2));
  unsigned short* gw_l  = (unsigned short*)(ws + alloc(30720 * 2));
  (void)in_sizes; (void)n_in; (void)out_size; (void)ws_size;

  hipMemsetAsync(gcur, 0, (size_t)NB * 16 * 4, stream);

  // CSR build (bucket sort) + prep (incl. W_conv folding)
  k_bucket<<<Ne / 4096, 256, 0, stream>>>(eidx, gcur, payload);
  k_placeB<<<NB, 256, 0, stream>>>(gcur, payload, rp, srcs);
  k_prepw<<<355, 256, 0, stream>>>(W_mlp, W_conv, gW_ih, gW_hh, b_conv,
                                   lW_ih, lW_hh, W1,
                                   mlp_h, mlp_l, gw_h, gw_l,
                                   WihT, WhhT, W1T, vfold, batch, gp, rp);

  // conv1 (+ x-column planes)
  k_conv1<<<Nn / 64, 256, 0, stream>>>(x, mlp_h, mlp_l, b_mlp, hpAh, hpAl, Aih, Ail);

  unsigned short *cph = hpAh, *cpl = hpAl, *nph = hpBh, *npl = hpBl;
  for (int step = 0; step < 2; ++step) {
    k_gru<<<Nn / 128, 512, 0, stream>>>(Aih, Ail, cph, cpl, gw_h, gw_l,
                                        gb_ih, gb_hh, vfold, rp, srcs, nph, npl);
    unsigned short* tu;
    tu = cph; cph = nph; nph = tu;
    tu = cpl; cpl = npl; npl = tu;
  }

  // Set2Set: all 3 iterations + head, one launch, 512 threads,
  // 448*68*4 = 121856 B dynamic LDS (padded rows)
  const size_t dynLds = (size_t)LCAP * LPAD * sizeof(float);
  static bool attr_set = false;
  if (!attr_set) {
    hipFuncSetAttribute((const void*)k_s2s,
                        hipFuncAttributeMaxDynamicSharedMemorySize,
                        (int)dynLds);
    attr_set = true;
  }
  k_s2s<<<Bg, S2T, dynLds, stream>>>(cph, cpl, gp, WihT, WhhT,
                                     lb_ih, lb_hh, W1T, b1, W2, b2, outp);
}

// Round 11
// 277.205 us; speedup vs baseline: 1.2478x; 1.0001x over previous
//
#include <hip/hip_runtime.h>
#include <math.h>

constexpr int Nn  = 65536;    // nodes
constexpr int Ne  = 1048576;  // edges
constexpr int Bg  = 256;      // graphs
constexpr int DIN = 32;
constexpr int D   = 64;

constexpr int NB   = 256;     // dst buckets (dst>>8)
constexpr int BCAP = 6144;    // bucket stream capacity (mean 4096, +36 sigma)

typedef __attribute__((ext_vector_type(8))) short bf16x8;
typedef __attribute__((ext_vector_type(8))) unsigned short u16x8;
typedef __attribute__((ext_vector_type(4))) float f32x4;

__device__ __forceinline__ float sigf(float x) { return 1.0f / (1.0f + expf(-x)); }

// ---- bf16 split helpers (RNE) ----
__device__ __forceinline__ unsigned short bf16_rne(float f) {
  unsigned u = __float_as_uint(f);
  unsigned r = u + 0x7FFFu + ((u >> 16) & 1u);
  return (unsigned short)(r >> 16);
}
__device__ __forceinline__ float bf16_tof(unsigned short h) {
  return __uint_as_float(((unsigned)h) << 16);
}
__device__ __forceinline__ void split2(float f, unsigned short& hi, unsigned short& lo) {
  hi = bf16_rne(f);
  lo = bf16_rne(f - bf16_tof(hi));
}
__device__ __forceinline__ float recon(unsigned short hi, unsigned short lo) {
  return bf16_tof(hi) + bf16_tof(lo);
}

#define MFMA(a, b, c) __builtin_amdgcn_mfma_f32_16x16x32_bf16(a, b, c, 0, 0, 0)

// ---------------------------------------------------------------------------
// Prep.  GRU weights chunk-major (5 chunks x 12nt x 64lane x 8j / plane):
//   chunks 0,1 = Wfold = Wih[:, :64] @ W_conv   (fused conv-linear)
//   chunk  2   = Wih[:, 64:96]  (x part)
//   chunks 3,4 = Whh
// Also: W_mlp pack, LSTM/W1 transposes, graphptr, rp[Nn], vfold.
// ---------------------------------------------------------------------------
__global__ void k_prepw(const float* __restrict__ W_mlp, const float* __restrict__ W_conv,
                        const float* __restrict__ gWih, const float* __restrict__ gWhh,
                        const float* __restrict__ b_conv,
                        const float* __restrict__ lW_ih, const float* __restrict__ lW_hh,
                        const float* __restrict__ W1,
                        unsigned short* __restrict__ mlp_h, unsigned short* __restrict__ mlp_l,
                        unsigned short* __restrict__ gw_h,  unsigned short* __restrict__ gw_l,
                        float* __restrict__ WihT, float* __restrict__ WhhT,
                        float* __restrict__ W1T, float* __restrict__ vfold,
                        const int* __restrict__ batch, int* __restrict__ gp,
                        int* __restrict__ rp) {
  int idx = blockIdx.x * 256 + threadIdx.x;
  if (idx < 30720) {  // GRU weights, chunk-major
    int c = idx / 6144, rem = idx % 6144;
    int nt = rem >> 9, lane = (rem >> 3) & 63, j = rem & 7;
    int n = nt * 16 + (lane & 15);
    int kk = c * 32 + (lane >> 4) * 8 + j;   // for c<3: k index into [S|x]
    float v;
    if (c < 2) {        // Wfold[n][kk] = sum_o Wih[n][o] * W_conv[o][kk]
      float s = 0.f;
      for (int o = 0; o < 64; ++o) s = fmaf(gWih[n * 96 + o], W_conv[o * 64 + kk], s);
      v = s;
    } else if (c == 2) {
      v = gWih[n * 96 + kk];                 // kk in 64..95 (x columns)
    } else {
      v = gWhh[n * 64 + (c - 3) * 32 + (lane >> 4) * 8 + j];
    }
    unsigned short hi, lo; split2(v, hi, lo);
    gw_h[idx] = hi; gw_l[idx] = lo;
    return;
  }
  if (idx < 32768) {  // W_mlp (KS=1)
    int lp = idx - 30720;
    int nt = lp >> 9, lane = (lp >> 3) & 63, j = lp & 7;
    int n = nt * 16 + (lane & 15);
    unsigned short hi, lo;
    split2(W_mlp[n * 32 + (lane >> 4) * 8 + j], hi, lo);
    mlp_h[lp] = hi; mlp_l[lp] = lo;
    return;
  }
  int t = idx - 32768;
  if (t < 32768) {                 // lstm W_ih [256][128] -> WihT [128][256]
    int row = t / 128, k = t % 128;
    WihT[k * 256 + row] = lW_ih[t];
  } else if (t < 49152) {          // lstm W_hh [256][64] -> WhhT [64][256]
    int j = t - 32768;
    int row = j / 64, k = j % 64;
    WhhT[k * 256 + row] = lW_hh[j];
  } else if (t < 57344) {          // W1 [64][128] -> W1T [128][64]
    int j = t - 49152;
    int row = j / 128, k = j % 128;
    W1T[k * 64 + row] = W1[j];
  } else if (t < 57344 + Bg + 1) { // graphptr + rp[Nn]
    int g = t - 57344;
    if (g == 0) rp[Nn] = Ne;
    int lo = 0, hi = Nn;
    while (lo < hi) {
      int mid = (lo + hi) >> 1;
      if (batch[mid] < g) lo = mid + 1; else hi = mid;
    }
    gp[g] = lo;
  } else if (t < 57344 + 257 + 192) { // vfold[192]
    int g = t - 57344 - 257;
    float s = 0.f;
    for (int o = 0; o < 64; ++o) s = fmaf(gWih[g * 96 + o], b_conv[o], s);
    vfold[g] = s;
  }
}

// ---------------------------------------------------------------------------
// conv1: h = x @ W_mlp^T + b  (K=32, N=64). Splits x in-kernel; also fills
// inp96 x-columns (64..95).  h stored as planes only.
// ---------------------------------------------------------------------------
__global__ __launch_bounds__(256) void k_conv1(const float* __restrict__ x,
                                               const unsigned short* __restrict__ Wh,
                                               const unsigned short* __restrict__ Wl,
                                               const float* __restrict__ bias,
                                               unsigned short* __restrict__ hph,
                                               unsigned short* __restrict__ hpl,
                                               unsigned short* __restrict__ Aih,
                                               unsigned short* __restrict__ Ail) {
  int wave = threadIdx.x >> 6, lane = threadIdx.x & 63;
  int quad = lane >> 4;
  int n0w = blockIdx.x * 64 + wave * 16;
  int rowA = n0w + (lane & 15);
  const float4* xp = (const float4*)&x[(size_t)rowA * 32 + quad * 8];
  float4 xa = xp[0], xb = xp[1];
  float xv[8] = {xa.x, xa.y, xa.z, xa.w, xb.x, xb.y, xb.z, xb.w};
  bf16x8 ah, al;
#pragma unroll
  for (int j = 0; j < 8; ++j) {
    unsigned short hi, lo; split2(xv[j], hi, lo);
    ah[j] = (short)hi; al[j] = (short)lo;
  }
  *(bf16x8*)&Aih[(size_t)rowA * 96 + 64 + quad * 8] = ah;
  *(bf16x8*)&Ail[(size_t)rowA * 96 + 64 + quad * 8] = al;

  f32x4 acc[4] = {};
#pragma unroll
  for (int nt = 0; nt < 4; ++nt) {
    bf16x8 bh = *(const bf16x8*)&Wh[(nt * 64 + lane) * 8];
    bf16x8 bl = *(const bf16x8*)&Wl[(nt * 64 + lane) * 8];
    acc[nt] = MFMA(ah, bh, acc[nt]);
    acc[nt] = MFMA(ah, bl, acc[nt]);
    acc[nt] = MFMA(al, bh, acc[nt]);
  }
  int col0 = lane & 15;
#pragma unroll
  for (int nt = 0; nt < 4; ++nt) {
    float bv = bias[nt * 16 + col0];
#pragma unroll
    for (int r = 0; r < 4; ++r) {
      int node = n0w + quad * 4 + r;
      float v = acc[nt][r] + bv;
      size_t o = (size_t)node * 64 + nt * 16 + col0;
      unsigned short hi, lo; split2(v, hi, lo);
      hph[o] = hi; hpl[o] = lo;
    }
  }
}

// ---------------------------------------------------------------------------
// Fused GRU v11: v10 (512 thr / 8 waves / 1 tile per wave) with the gather
// deepened 4 -> 8: 8 src indices + 16 u16x8 loads issued back-to-back
// (~16 lines in flight per wave; 64 at 4 waves/SIMD), accumulation strictly
// in edge order -> bitwise identical.  Freed accumulator VGPRs (one-tile
// restructure) pay for the deeper load batch under the (512,4) 128-VGPR cap.
// ---------------------------------------------------------------------------
__global__ __launch_bounds__(512, 4) void k_gru(const unsigned short* __restrict__ Aih,
                                                const unsigned short* __restrict__ Ail,
                                                const unsigned short* __restrict__ Hh,
                                                const unsigned short* __restrict__ Hl,
                                                const unsigned short* __restrict__ gw_h,
                                                const unsigned short* __restrict__ gw_l,
                                                const float* __restrict__ b_ih,
                                                const float* __restrict__ b_hh,
                                                const float* __restrict__ vfold,
                                                const int* __restrict__ rp,
                                                const int* __restrict__ srcs,
                                                unsigned short* __restrict__ nph,
                                                unsigned short* __restrict__ npl) {
  __shared__ unsigned short sW[2][12288];  // per buf: hi[0..6143] | lo[6144..]
  int tid = threadIdx.x;                   // 0..511
  int wave = tid >> 6, lane = tid & 63;
  int quad = lane >> 4;
  int rowA = blockIdx.x * 128 + wave * 16 + (lane & 15);  // this wave's tile row

  // ---- fused aggregate: gather S fragments for chunks 0,1 (one tile) ----
  bf16x8 fh[2], fl[2];  // [chunk]
  const size_t q8 = (size_t)(quad * 8);
  {
    int s = rp[rowA], e = rp[rowA + 1];
    int n = e - s;
    const int* sp = srcs + s;
    float acc0[8] = {}, acc1[8] = {};
    int i = 0;
    // 8-deep batched main loop: all 16 loads issued before any accumulation,
    // accumulation strictly in edge order (bitwise == serial version).
    for (; i + 8 <= n; i += 8) {
      int s0 = sp[i],     s1 = sp[i + 1], s2 = sp[i + 2], s3 = sp[i + 3];
      int s4 = sp[i + 4], s5 = sp[i + 5], s6 = sp[i + 6], s7 = sp[i + 7];
      u16x8 a0 = *(const u16x8*)&Hh[(size_t)s0 * 64 + q8];
      u16x8 b0 = *(const u16x8*)&Hh[(size_t)s0 * 64 + 32 + q8];
      u16x8 a1 = *(const u16x8*)&Hh[(size_t)s1 * 64 + q8];
      u16x8 b1 = *(const u16x8*)&Hh[(size_t)s1 * 64 + 32 + q8];
      u16x8 a2 = *(const u16x8*)&Hh[(size_t)s2 * 64 + q8];
      u16x8 b2 = *(const u16x8*)&Hh[(size_t)s2 * 64 + 32 + q8];
      u16x8 a3 = *(const u16x8*)&Hh[(size_t)s3 * 64 + q8];
      u16x8 b3 = *(const u16x8*)&Hh[(size_t)s3 * 64 + 32 + q8];
      u16x8 a4 = *(const u16x8*)&Hh[(size_t)s4 * 64 + q8];
      u16x8 b4 = *(const u16x8*)&Hh[(size_t)s4 * 64 + 32 + q8];
      u16x8 a5 = *(const u16x8*)&Hh[(size_t)s5 * 64 + q8];
      u16x8 b5 = *(const u16x8*)&Hh[(size_t)s5 * 64 + 32 + q8];
      u16x8 a6 = *(const u16x8*)&Hh[(size_t)s6 * 64 + q8];
      u16x8 b6 = *(const u16x8*)&Hh[(size_t)s6 * 64 + 32 + q8];
      u16x8 a7 = *(const u16x8*)&Hh[(size_t)s7 * 64 + q8];
      u16x8 b7 = *(const u16x8*)&Hh[(size_t)s7 * 64 + 32 + q8];
#pragma unroll
      for (int j = 0; j < 8; ++j) { acc0[j] += bf16_tof(a0[j]); acc1[j] += bf16_tof(b0[j]); }
#pragma unroll
      for (int j = 0; j < 8; ++j) { acc0[j] += bf16_tof(a1[j]); acc1[j] += bf16_tof(b1[j]); }
#pragma unroll
      for (int j = 0; j < 8; ++j) { acc0[j] += bf16_tof(a2[j]); acc1[j] += bf16_tof(b2[j]); }
#pragma unroll
      for (int j = 0; j < 8; ++j) { acc0[j] += bf16_tof(a3[j]); acc1[j] += bf16_tof(b3[j]); }
#pragma unroll
      for (int j = 0; j < 8; ++j) { acc0[j] += bf16_tof(a4[j]); acc1[j] += bf16_tof(b4[j]); }
#pragma unroll
      for (int j = 0; j < 8; ++j) { acc0[j] += bf16_tof(a5[j]); acc1[j] += bf16_tof(b5[j]); }
#pragma unroll
      for (int j = 0; j < 8; ++j) { acc0[j] += bf16_tof(a6[j]); acc1[j] += bf16_tof(b6[j]); }
#pragma unroll
      for (int j = 0; j < 8; ++j) { acc0[j] += bf16_tof(a7[j]); acc1[j] += bf16_tof(b7[j]); }
    }
    for (; i + 4 <= n; i += 4) {
      int s0 = sp[i], s1 = sp[i + 1], s2 = sp[i + 2], s3 = sp[i + 3];
      u16x8 a0 = *(const u16x8*)&Hh[(size_t)s0 * 64 + q8];
      u16x8 b0 = *(const u16x8*)&Hh[(size_t)s0 * 64 + 32 + q8];
      u16x8 a1 = *(const u16x8*)&Hh[(size_t)s1 * 64 + q8];
      u16x8 b1 = *(const u16x8*)&Hh[(size_t)s1 * 64 + 32 + q8];
      u16x8 a2 = *(const u16x8*)&Hh[(size_t)s2 * 64 + q8];
      u16x8 b2 = *(const u16x8*)&Hh[(size_t)s2 * 64 + 32 + q8];
      u16x8 a3 = *(const u16x8*)&Hh[(size_t)s3 * 64 + q8];
      u16x8 b3 = *(const u16x8*)&Hh[(size_t)s3 * 64 + 32 + q8];
#pragma unroll
      for (int j = 0; j < 8; ++j) { acc0[j] += bf16_tof(a0[j]); acc1[j] += bf16_tof(b0[j]); }
#pragma unroll
      for (int j = 0; j < 8; ++j) { acc0[j] += bf16_tof(a1[j]); acc1[j] += bf16_tof(b1[j]); }
#pragma unroll
      for (int j = 0; j < 8; ++j) { acc0[j] += bf16_tof(a2[j]); acc1[j] += bf16_tof(b2[j]); }
#pragma unroll
      for (int j = 0; j < 8; ++j) { acc0[j] += bf16_tof(a3[j]); acc1[j] += bf16_tof(b3[j]); }
    }
    for (; i < n; ++i) {
      int src = sp[i];
      u16x8 v0 = *(const u16x8*)&Hh[(size_t)src * 64 + q8];
      u16x8 v1 = *(const u16x8*)&Hh[(size_t)src * 64 + 32 + q8];
#pragma unroll
      for (int j = 0; j < 8; ++j) {
        acc0[j] += bf16_tof(v0[j]);
        acc1[j] += bf16_tof(v1[j]);
      }
    }
#pragma unroll
    for (int j = 0; j < 8; ++j) {
      unsigned short hi, lo;
      split2(acc0[j], hi, lo);
      fh[0][j] = (short)hi; fl[0][j] = (short)lo;
      split2(acc1[j], hi, lo);
      fh[1][j] = (short)hi; fl[1][j] = (short)lo;
    }
  }

  f32x4 acc[12] = {};     // gi r,z,n (gh r,z folded into 0..7)
  f32x4 aN[4] = {};       // gh n-gate

  // prologue: weights chunk 0 (768 16B-vectors staged by 512 threads)
  bf16x8 gvh0, gvl0, gvh1, gvl1;
  const bool two = (tid < 256);
  gvh0 = *(const bf16x8*)&gw_h[tid * 8];
  gvl0 = *(const bf16x8*)&gw_l[tid * 8];
  if (two) {
    gvh1 = *(const bf16x8*)&gw_h[(tid + 512) * 8];
    gvl1 = *(const bf16x8*)&gw_l[(tid + 512) * 8];
  }
  *(bf16x8*)&sW[0][tid * 8] = gvh0;
  *(bf16x8*)&sW[0][6144 + tid * 8] = gvl0;
  if (two) {
    *(bf16x8*)&sW[0][(tid + 512) * 8] = gvh1;
    *(bf16x8*)&sW[0][6144 + (tid + 512) * 8] = gvl1;
  }
  __syncthreads();

#pragma unroll
  for (int c = 0; c < 5; ++c) {
    const int buf = c & 1;
    if (c < 4) {  // prefetch chunk c+1 weights
      gvh0 = *(const bf16x8*)&gw_h[(c + 1) * 6144 + tid * 8];
      gvl0 = *(const bf16x8*)&gw_l[(c + 1) * 6144 + tid * 8];
      if (two) {
        gvh1 = *(const bf16x8*)&gw_h[(c + 1) * 6144 + (tid + 512) * 8];
        gvl1 = *(const bf16x8*)&gw_l[(c + 1) * 6144 + (tid + 512) * 8];
      }
    }
    // A fragment
    bf16x8 ah, al;
    if (c < 2) {            // gathered S fragments (registers)
      ah = fh[c]; al = fl[c];
    } else if (c == 2) {    // x columns from conv1 prep
      size_t b0 = (size_t)rowA * 96 + 64 + quad * 8;
      ah = *(const bf16x8*)&Aih[b0]; al = *(const bf16x8*)&Ail[b0];
    } else {                // h planes (Whh chunks)
      size_t b0 = (size_t)rowA * 64 + (c - 3) * 32 + quad * 8;
      ah = *(const bf16x8*)&Hh[b0]; al = *(const bf16x8*)&Hl[b0];
    }
    const unsigned short* sw = sW[buf];
#pragma unroll
    for (int nt = 0; nt < 12; ++nt) {
      bf16x8 bh = *(const bf16x8*)&sw[(nt * 64 + lane) * 8];
      bf16x8 bl = *(const bf16x8*)&sw[6144 + (nt * 64 + lane) * 8];
      if (c < 3 || nt < 8) {
        acc[nt] = MFMA(ah, bh, acc[nt]);
        acc[nt] = MFMA(ah, bl, acc[nt]);
        acc[nt] = MFMA(al, bh, acc[nt]);
      } else {
        aN[nt - 8] = MFMA(ah, bh, aN[nt - 8]);
        aN[nt - 8] = MFMA(ah, bl, aN[nt - 8]);
        aN[nt - 8] = MFMA(al, bh, aN[nt - 8]);
      }
    }
    if (c < 4) {
      *(bf16x8*)&sW[1 - buf][tid * 8] = gvh0;
      *(bf16x8*)&sW[1 - buf][6144 + tid * 8] = gvl0;
      if (two) {
        *(bf16x8*)&sW[1 - buf][(tid + 512) * 8] = gvh1;
        *(bf16x8*)&sW[1 - buf][6144 + (tid + 512) * 8] = gvl1;
      }
    }
    __syncthreads();
  }

  // epilogue: GRU nonlinearity + deg*vfold (folded conv bias) + plane store
  int col0 = lane & 15;
  int nb = blockIdx.x * 128 + wave * 16;
#pragma unroll
  for (int r = 0; r < 4; ++r) {
    int node = nb + quad * 4 + r;
    float degf = (float)(rp[node + 1] - rp[node]);
#pragma unroll
    for (int nt = 0; nt < 4; ++nt) {
      int g = nt * 16 + col0;
      size_t o = (size_t)node * 64 + g;
      float br  = b_ih[g] + b_hh[g] + degf * vfold[g];
      float bz  = b_ih[64 + g] + b_hh[64 + g] + degf * vfold[64 + g];
      float bin = b_ih[128 + g] + degf * vfold[128 + g];
      float bhn = b_hh[128 + g];
      float gr = acc[nt][r];
      float gz = acc[nt + 4][r];
      float gn = acc[nt + 8][r];
      float hn = aN[nt][r];
      float rr = sigf(gr + br);
      float zz = sigf(gz + bz);
      float nn = tanhf(gn + bin + rr * (hn + bhn));
      float h_old = recon(Hh[o], Hl[o]);
      float hv = (1.f - zz) * nn + zz * h_old;
      unsigned short hi, lo; split2(hv, hi, lo);
      nph[o] = hi; npl[o] = lo;
    }
  }
}

// ---------------------------------------------------------------------------
// CSR build v3: two-level bucket sort by dst.
// ---------------------------------------------------------------------------
__global__ __launch_bounds__(256) void k_bucket(const int* __restrict__ eidx,
                                                int* __restrict__ gcur,     // [NB*16]
                                                int* __restrict__ payload) {// [NB*BCAP]
  __shared__ int lcnt[NB];
  __shared__ int lcur[NB];
  int t = threadIdx.x;
  int e0 = blockIdx.x * 4096;
  lcnt[t] = 0;
  __syncthreads();
  int ds[16], ss[16];
#pragma unroll
  for (int i = 0; i < 16; ++i) {
    int e = e0 + i * 256 + t;
    ds[i] = eidx[Ne + e];
    ss[i] = eidx[e];
    atomicAdd(&lcnt[ds[i] >> 8], 1);
  }
  __syncthreads();
  lcur[t] = atomicAdd(&gcur[t * 16], lcnt[t]);  // reserve contiguous run
  __syncthreads();
#pragma unroll
  for (int i = 0; i < 16; ++i) {
    int b = ds[i] >> 8;
    int p = atomicAdd(&lcur[b], 1);
    if (p < BCAP) payload[b * BCAP + p] = (ss[i] << 8) | (ds[i] & 255);
  }
}

// One block per bucket: inline scan of gcur -> base, LDS hist -> rp slice,
// place srcs via LDS cursors (scatter window owned by one CU).
__global__ __launch_bounds__(256) void k_placeB(const int* __restrict__ gcur,
                                                const int* __restrict__ payload,
                                                int* __restrict__ rp,
                                                int* __restrict__ srcs) {
  __shared__ int sAll[NB];
  __shared__ int hst[NB];
  __shared__ int cur[NB];
  int b = blockIdx.x, t = threadIdx.x;
  sAll[t] = gcur[t * 16];
  hst[t] = 0;
  __syncthreads();
  int cnt = min(sAll[b], BCAP);
  for (int off = 1; off < NB; off <<= 1) {
    int v = (t >= off) ? sAll[t - off] : 0;
    __syncthreads();
    sAll[t] += v;
    __syncthreads();
  }
  int base = sAll[b] - gcur[b * 16];  // exclusive prefix (true counts)
  const int* pay = &payload[b * BCAP];
  for (int i = t; i < cnt; i += 256) atomicAdd(&hst[pay[i] & 255], 1);
  __syncthreads();
  int c = hst[t];
  cur[t] = c;
  __syncthreads();
  for (int off = 1; off < NB; off <<= 1) {
    int v = (t >= off) ? cur[t - off] : 0;
    __syncthreads();
    cur[t] += v;
    __syncthreads();
  }
  int excl = cur[t] - c;
  rp[b * 256 + t] = base + excl;
  cur[t] = base + excl;
  __syncthreads();
  for (int i = t; i < cnt; i += 256) {
    int pl = pay[i];
    int p = atomicAdd(&cur[pl & 255], 1);
    srcs[p] = pl >> 8;
  }
}

// ---------------------------------------------------------------------------
// Fused Set2Set (round-8, measured 56.7 us): all 3 iterations + head, one
// launch, 512 threads, h rows staged to f32 in dynamic LDS, per-wave emax.
// At its dependent-chain floor for this structure -- left untouched.
// ---------------------------------------------------------------------------
constexpr int LCAP = 448;
constexpr int LPAD = 68;    // padded hL row stride in floats
constexpr int S2T  = 512;   // threads (8 waves)
__global__ __launch_bounds__(S2T) void k_s2s(const unsigned short* __restrict__ hph,
                                             const unsigned short* __restrict__ hpl,
                                             const int* __restrict__ gp,
                                             const float* __restrict__ WihT,
                                             const float* __restrict__ WhhT,
                                             const float* __restrict__ b_ih,
                                             const float* __restrict__ b_hh,
                                             const float* __restrict__ W1T,
                                             const float* __restrict__ b1,
                                             const float* __restrict__ W2,
                                             const float* __restrict__ b2,
                                             float* __restrict__ outp) {
  extern __shared__ float hL[];   // [LCAP][LPAD] f32 staged h
  int g = blockIdx.x;
  int t = threadIdx.x;
  int w = t >> 6, lane = t & 63;
  __shared__ float qstar_s[128];  // [q | r] carried across iterations
  __shared__ float hs[64], cs[64], gates[256];
  __shared__ float eL[LCAP];
  __shared__ float partial[8][64];
  __shared__ float asum_p[8];
  __shared__ float l4[4];
  __shared__ float hid[64];

  if (t < 128) qstar_s[t] = 0.f;
  if (t < 64) { hs[t] = 0.f; cs[t] = 0.f; }
  int s = gp[g], e = gp[g + 1];
  int cnt = e - s;

  // ---- stage h rows once: hL[nd*LPAD+col] = recon(hph, hpl) ----
  {
    int total = cnt * 64;
    for (int j = t * 4; j < total; j += S2T * 4) {
      int nd = j >> 6, col = j & 63;
      ushort4 hh = *(const ushort4*)&hph[(size_t)s * 64 + j];
      ushort4 ll = *(const ushort4*)&hpl[(size_t)s * 64 + j];
      float4 v;
      v.x = recon(hh.x, ll.x); v.y = recon(hh.y, ll.y);
      v.z = recon(hh.z, ll.z); v.w = recon(hh.w, ll.w);
      *(float4*)&hL[nd * LPAD + col] = v;
    }
  }

  for (int it = 0; it < 3; ++it) {
    __syncthreads();   // state + staged hL visible

    // ---- LSTM cell (first 4 waves) ----
    if (t < 256) {
      float acc = b_ih[t] + b_hh[t];
      for (int k = 0; k < 128; ++k) acc = fmaf(WihT[k * 256 + t], qstar_s[k], acc);
      for (int k = 0; k < 64; ++k)  acc = fmaf(WhhT[k * 256 + t], hs[k], acc);
      gates[t] = acc;
    }
    __syncthreads();
    if (t < 64) {
      float ig = sigf(gates[t]),        fg = sigf(gates[64 + t]);
      float gg = tanhf(gates[128 + t]), og = sigf(gates[192 + t]);
      float c = fg * cs[t] + ig * gg;
      float q = og * tanhf(c);
      cs[t] = c;
      hs[t] = q;
      qstar_s[t] = q;
    }
    __syncthreads();

    // ---- attention phase A: e_i = h[i].q ----
    int c4 = (lane & 15) * 4;
    float4 qv = {qstar_s[c4], qstar_s[c4 + 1], qstar_s[c4 + 2], qstar_s[c4 + 3]};
    for (int i0 = s + w * 4; i0 < e; i0 += 32) {
      int node = i0 + (lane >> 4);
      float p = 0.f;
      if (node < e) {
        float4 hv = *(const float4*)&hL[(node - s) * LPAD + c4];
        p = hv.x * qv.x + hv.y * qv.y + hv.z * qv.z + hv.w * qv.w;
      }
      p += __shfl_xor(p, 1); p += __shfl_xor(p, 2);
      p += __shfl_xor(p, 4); p += __shfl_xor(p, 8);
      if (node < e && (lane & 15) == 0) eL[node - s] = p;
    }
    __syncthreads();

    // ---- phase B: segment max, per-wave (order-invariant) ----
    float m = -INFINITY;
    for (int i = lane; i < cnt; i += 64) m = fmaxf(m, eL[i]);
#pragma unroll
    for (int o = 32; o >= 1; o >>= 1) m = fmaxf(m, __shfl_xor(m, o));
    float emax = isfinite(m) ? m : 0.f;

    // ---- phase C: softmax-weighted feature sum ----
    float acc = 0.f, asum = 0.f;
    for (int i = s + w; i < e; i += 8) {
      float a = expf(eL[i - s] - emax);
      asum += a;
      acc = fmaf(a, hL[(i - s) * LPAD + lane], acc);
    }
    partial[w][lane] = acc;
    if (lane == 0) asum_p[w] = asum;
    __syncthreads();
    if (t < 64) {
      float r = 0.f, as = 0.f;
      for (int q = 0; q < 8; ++q) { r += partial[q][t]; as += asum_p[q]; }
      float rv = (cnt > 0) ? r / fmaxf(as, 1e-16f) : 0.f;
      qstar_s[64 + t] = rv;
    }
  }
  __syncthreads();

  // ---- head ----
  if (t < 64) {
    float a1 = b1[t];
    for (int k = 0; k < 64; ++k)   a1 = fmaf(W1T[k * 64 + t], qstar_s[k], a1);
    for (int k = 64; k < 128; ++k) a1 = fmaf(W1T[k * 64 + t], qstar_s[k], a1);
    hid[t] = fmaxf(a1, 0.f);
  }
  __syncthreads();
  if (t < 4) {
    float lg = b2[t];
    for (int d = 0; d < 64; ++d) lg = fmaf(W2[t * 64 + d], hid[d], lg);
    l4[t] = lg;
  }
  __syncthreads();
  if (t < 4) {
    float mx = fmaxf(fmaxf(l4[0], l4[1]), fmaxf(l4[2], l4[3]));
    float ssum = expf(l4[0] - mx) + expf(l4[1] - mx) + expf(l4[2] - mx) + expf(l4[3] - mx);
    outp[g * 4 + t] = l4[t] - mx - logf(ssum);
  }
}

// ---------------------------------------------------------------------------
extern "C" void kernel_launch(void* const* d_in, const int* in_sizes, int n_in,
                              void* d_out, int out_size, void* d_ws, size_t ws_size,
                              hipStream_t stream) {
  const float* x        = (const float*)d_in[0];
  const int*   eidx     = (const int*)d_in[1];
  const int*   batch    = (const int*)d_in[2];
  const float* W_mlp    = (const float*)d_in[3];
  const float* b_mlp    = (const float*)d_in[4];
  const float* W_conv   = (const float*)d_in[5];
  const float* b_conv   = (const float*)d_in[6];
  const float* gW_ih    = (const float*)d_in[7];
  const float* gW_hh    = (const float*)d_in[8];
  const float* gb_ih    = (const float*)d_in[9];
  const float* gb_hh    = (const float*)d_in[10];
  const float* lW_ih    = (const float*)d_in[11];
  const float* lW_hh    = (const float*)d_in[12];
  const float* lb_ih    = (const float*)d_in[13];
  const float* lb_hh    = (const float*)d_in[14];
  const float* W1       = (const float*)d_in[15];
  const float* b1       = (const float*)d_in[16];
  const float* W2       = (const float*)d_in[17];
  const float* b2       = (const float*)d_in[18];
  float* outp = (float*)d_out;

  // ---- workspace layout ----
  char* ws = (char*)d_ws;
  size_t off = 0;
  auto alloc = [&](size_t bytes) { size_t r = off; off = (off + bytes + 255) & ~(size_t)255; return r; };
  unsigned short* hpAh = (unsigned short*)(ws + alloc((size_t)Nn * 64 * 2));
  unsigned short* hpAl = (unsigned short*)(ws + alloc((size_t)Nn * 64 * 2));
  unsigned short* hpBh = (unsigned short*)(ws + alloc((size_t)Nn * 64 * 2));
  unsigned short* hpBl = (unsigned short*)(ws + alloc((size_t)Nn * 64 * 2));
  unsigned short* Aih  = (unsigned short*)(ws + alloc((size_t)Nn * 96 * 2));
  unsigned short* Ail  = (unsigned short*)(ws + alloc((size_t)Nn * 96 * 2));
  int*   rp    = (int*)(ws + alloc((size_t)(Nn + 1) * 4));
  int*   srcs  = (int*)(ws + alloc((size_t)Ne * 4));
  int*   gcur  = (int*)(ws + alloc((size_t)NB * 16 * 4));
  int*   payload = (int*)(ws + alloc((size_t)NB * BCAP * 4));
  int*   gp    = (int*)(ws + alloc((size_t)(Bg + 1) * 4));
  float* WihT  = (float*)(ws + alloc((size_t)128 * 256 * 4));
  float* WhhT  = (float*)(ws + alloc((size_t)64 * 256 * 4));
  float* W1T   = (float*)(ws + alloc((size_t)128 * 64 * 4));
  float* vfold = (float*)(ws + alloc(192 * 4));
  unsigned short* mlp_h = (unsigned short*)(ws + alloc(2048 * 2));
  unsigned short* mlp_l = (unsigned short*)(ws + alloc(2048 * 2));
  unsigned short* gw_h  = (unsigned short*)(ws + alloc(30720 * 2));
  unsigned short* gw_l  = (unsigned short*)(ws + alloc(30720 * 2));
  (void)in_sizes; (void)n_in; (void)out_size; (void)ws_size;

  hipMemsetAsync(gcur, 0, (size_t)NB * 16 * 4, stream);

  // CSR build (bucket sort) + prep (incl. W_conv folding)
  k_bucket<<<Ne / 4096, 256, 0, stream>>>(eidx, gcur, payload);
  k_placeB<<<NB, 256, 0, stream>>>(gcur, payload, rp, srcs);
  k_prepw<<<355, 256, 0, stream>>>(W_mlp, W_conv, gW_ih, gW_hh, b_conv,
                                   lW_ih, lW_hh, W1,
                                   mlp_h, mlp_l, gw_h, gw_l,
                                   WihT, WhhT, W1T, vfold, batch, gp, rp);

  // conv1 (+ x-column planes)
  k_conv1<<<Nn / 64, 256, 0, stream>>>(x, mlp_h, mlp_l, b_mlp, hpAh, hpAl, Aih, Ail);

  unsigned short *cph = hpAh, *cpl = hpAl, *nph = hpBh, *npl = hpBl;
  for (int step = 0; step < 2; ++step) {
    k_gru<<<Nn / 128, 512, 0, stream>>>(Aih, Ail, cph, cpl, gw_h, gw_l,
                                        gb_ih, gb_hh, vfold, rp, srcs, nph, npl);
    unsigned short* tu;
    tu = cph; cph = nph; nph = tu;
    tu = cpl; cpl = npl; npl = tu;
  }

  // Set2Set: all 3 iterations + head, one launch, 512 threads,
  // 448*68*4 = 121856 B dynamic LDS (padded rows)
  const size_t dynLds = (size_t)LCAP * LPAD * sizeof(float);
  static bool attr_set = false;
  if (!attr_set) {
    hipFuncSetAttribute((const void*)k_s2s,
                        hipFuncAttributeMaxDynamicSharedMemorySize,
                        (int)dynLds);
    attr_set = true;
  }
  k_s2s<<<Bg, S2T, dynLds, stream>>>(cph, cpl, gp, WihT, WhhT,
                                     lb_ih, lb_hh, W1T, b1, W2, b2, outp);
}

// Round 12
// 260.371 us; speedup vs baseline: 1.3284x; 1.0647x over previous
//
#include <hip/hip_runtime.h>
#include <math.h>

constexpr int Nn  = 65536;    // nodes
constexpr int Ne  = 1048576;  // edges
constexpr int Bg  = 256;      // graphs
constexpr int DIN = 32;
constexpr int D   = 64;

constexpr int NB   = 256;     // dst buckets (dst>>8)
constexpr int BCAP = 6144;    // bucket stream capacity (mean 4096, +36 sigma)

typedef __attribute__((ext_vector_type(8))) short bf16x8;
typedef __attribute__((ext_vector_type(8))) unsigned short u16x8;
typedef __attribute__((ext_vector_type(4))) float f32x4;

__device__ __forceinline__ float sigf(float x) { return 1.0f / (1.0f + expf(-x)); }

// ---- bf16 split helpers (RNE) ----
__device__ __forceinline__ unsigned short bf16_rne(float f) {
  unsigned u = __float_as_uint(f);
  unsigned r = u + 0x7FFFu + ((u >> 16) & 1u);
  return (unsigned short)(r >> 16);
}
__device__ __forceinline__ float bf16_tof(unsigned short h) {
  return __uint_as_float(((unsigned)h) << 16);
}
__device__ __forceinline__ void split2(float f, unsigned short& hi, unsigned short& lo) {
  hi = bf16_rne(f);
  lo = bf16_rne(f - bf16_tof(hi));
}
__device__ __forceinline__ float recon(unsigned short hi, unsigned short lo) {
  return bf16_tof(hi) + bf16_tof(lo);
}

#define MFMA(a, b, c) __builtin_amdgcn_mfma_f32_16x16x32_bf16(a, b, c, 0, 0, 0)

// ---------------------------------------------------------------------------
// Prep body (idx-indexed).  GRU weights chunk-major; W_mlp pack; LSTM/W1
// transposes; graphptr; rp[Nn]; vfold.  Unchanged math.
// ---------------------------------------------------------------------------
__device__ void prepw_body(int idx,
                           const float* __restrict__ W_mlp, const float* __restrict__ W_conv,
                           const float* __restrict__ gWih, const float* __restrict__ gWhh,
                           const float* __restrict__ b_conv,
                           const float* __restrict__ lW_ih, const float* __restrict__ lW_hh,
                           const float* __restrict__ W1,
                           unsigned short* __restrict__ mlp_h, unsigned short* __restrict__ mlp_l,
                           unsigned short* __restrict__ gw_h,  unsigned short* __restrict__ gw_l,
                           float* __restrict__ WihT, float* __restrict__ WhhT,
                           float* __restrict__ W1T, float* __restrict__ vfold,
                           const int* __restrict__ batch, int* __restrict__ gp,
                           int* __restrict__ rp) {
  if (idx < 30720) {  // GRU weights, chunk-major
    int c = idx / 6144, rem = idx % 6144;
    int nt = rem >> 9, lane = (rem >> 3) & 63, j = rem & 7;
    int n = nt * 16 + (lane & 15);
    int kk = c * 32 + (lane >> 4) * 8 + j;   // for c<3: k index into [S|x]
    float v;
    if (c < 2) {        // Wfold[n][kk] = sum_o Wih[n][o] * W_conv[o][kk]
      float s = 0.f;
      for (int o = 0; o < 64; ++o) s = fmaf(gWih[n * 96 + o], W_conv[o * 64 + kk], s);
      v = s;
    } else if (c == 2) {
      v = gWih[n * 96 + kk];                 // kk in 64..95 (x columns)
    } else {
      v = gWhh[n * 64 + (c - 3) * 32 + (lane >> 4) * 8 + j];
    }
    unsigned short hi, lo; split2(v, hi, lo);
    gw_h[idx] = hi; gw_l[idx] = lo;
    return;
  }
  if (idx < 32768) {  // W_mlp (KS=1)
    int lp = idx - 30720;
    int nt = lp >> 9, lane = (lp >> 3) & 63, j = lp & 7;
    int n = nt * 16 + (lane & 15);
    unsigned short hi, lo;
    split2(W_mlp[n * 32 + (lane >> 4) * 8 + j], hi, lo);
    mlp_h[lp] = hi; mlp_l[lp] = lo;
    return;
  }
  int t = idx - 32768;
  if (t < 32768) {                 // lstm W_ih [256][128] -> WihT [128][256]
    int row = t / 128, k = t % 128;
    WihT[k * 256 + row] = lW_ih[t];
  } else if (t < 49152) {          // lstm W_hh [256][64] -> WhhT [64][256]
    int j = t - 32768;
    int row = j / 64, k = j % 64;
    WhhT[k * 256 + row] = lW_hh[j];
  } else if (t < 57344) {          // W1 [64][128] -> W1T [128][64]
    int j = t - 49152;
    int row = j / 128, k = j % 128;
    W1T[k * 64 + row] = W1[j];
  } else if (t < 57344 + Bg + 1) { // graphptr + rp[Nn]
    int g = t - 57344;
    if (g == 0) rp[Nn] = Ne;
    int lo = 0, hi = Nn;
    while (lo < hi) {
      int mid = (lo + hi) >> 1;
      if (batch[mid] < g) lo = mid + 1; else hi = mid;
    }
    gp[g] = lo;
  } else if (t < 57344 + 257 + 192) { // vfold[192]
    int g = t - 57344 - 257;
    float s = 0.f;
    for (int o = 0; o < 64; ++o) s = fmaf(gWih[g * 96 + o], b_conv[o], s);
    vfold[g] = s;
  }
}

// ---------------------------------------------------------------------------
// Bucket body (bid 0..255): two-level bucket sort by dst, pass 1.
// ---------------------------------------------------------------------------
__device__ void bucket_body(int bid,
                            const int* __restrict__ eidx,
                            int* __restrict__ gcur,
                            int* __restrict__ payload) {
  __shared__ int lcnt[NB];
  __shared__ int lcur[NB];
  int t = threadIdx.x;
  int e0 = bid * 4096;
  lcnt[t] = 0;
  __syncthreads();
  int ds[16], ss[16];
#pragma unroll
  for (int i = 0; i < 16; ++i) {
    int e = e0 + i * 256 + t;
    ds[i] = eidx[Ne + e];
    ss[i] = eidx[e];
    atomicAdd(&lcnt[ds[i] >> 8], 1);
  }
  __syncthreads();
  lcur[t] = atomicAdd(&gcur[t * 16], lcnt[t]);  // reserve contiguous run
  __syncthreads();
#pragma unroll
  for (int i = 0; i < 16; ++i) {
    int b = ds[i] >> 8;
    int p = atomicAdd(&lcur[b], 1);
    if (p < BCAP) payload[b * BCAP + p] = (ss[i] << 8) | (ds[i] & 255);
  }
}

// ---------------------------------------------------------------------------
// placeB body (bid 0..255): inline scan of gcur -> base, LDS hist -> rp
// slice, place srcs via LDS cursors.
// ---------------------------------------------------------------------------
__device__ void placeB_body(int b,
                            const int* __restrict__ gcur,
                            const int* __restrict__ payload,
                            int* __restrict__ rp,
                            int* __restrict__ srcs) {
  __shared__ int sAll[NB];
  __shared__ int hst[NB];
  __shared__ int cur[NB];
  int t = threadIdx.x;
  sAll[t] = gcur[t * 16];
  hst[t] = 0;
  __syncthreads();
  int cnt = min(sAll[b], BCAP);
  for (int off = 1; off < NB; off <<= 1) {
    int v = (t >= off) ? sAll[t - off] : 0;
    __syncthreads();
    sAll[t] += v;
    __syncthreads();
  }
  int base = sAll[b] - gcur[b * 16];  // exclusive prefix (true counts)
  const int* pay = &payload[b * BCAP];
  for (int i = t; i < cnt; i += 256) atomicAdd(&hst[pay[i] & 255], 1);
  __syncthreads();
  int c = hst[t];
  cur[t] = c;
  __syncthreads();
  for (int off = 1; off < NB; off <<= 1) {
    int v = (t >= off) ? cur[t - off] : 0;
    __syncthreads();
    cur[t] += v;
    __syncthreads();
  }
  int excl = cur[t] - c;
  rp[b * 256 + t] = base + excl;
  cur[t] = base + excl;
  __syncthreads();
  for (int i = t; i < cnt; i += 256) {
    int pl = pay[i];
    int p = atomicAdd(&cur[pl & 255], 1);
    srcs[p] = pl >> 8;
  }
}

// ---------------------------------------------------------------------------
// conv1 body (bid 0..1023): h = x @ W_mlp^T + b; also fills inp96 x-columns.
// ---------------------------------------------------------------------------
__device__ void conv1_body(int bid,
                           const float* __restrict__ x,
                           const unsigned short* __restrict__ Wh,
                           const unsigned short* __restrict__ Wl,
                           const float* __restrict__ bias,
                           unsigned short* __restrict__ hph,
                           unsigned short* __restrict__ hpl,
                           unsigned short* __restrict__ Aih,
                           unsigned short* __restrict__ Ail) {
  int wave = threadIdx.x >> 6, lane = threadIdx.x & 63;
  int quad = lane >> 4;
  int n0w = bid * 64 + wave * 16;
  int rowA = n0w + (lane & 15);
  const float4* xp = (const float4*)&x[(size_t)rowA * 32 + quad * 8];
  float4 xa = xp[0], xb = xp[1];
  float xv[8] = {xa.x, xa.y, xa.z, xa.w, xb.x, xb.y, xb.z, xb.w};
  bf16x8 ah, al;
#pragma unroll
  for (int j = 0; j < 8; ++j) {
    unsigned short hi, lo; split2(xv[j], hi, lo);
    ah[j] = (short)hi; al[j] = (short)lo;
  }
  *(bf16x8*)&Aih[(size_t)rowA * 96 + 64 + quad * 8] = ah;
  *(bf16x8*)&Ail[(size_t)rowA * 96 + 64 + quad * 8] = al;

  f32x4 acc[4] = {};
#pragma unroll
  for (int nt = 0; nt < 4; ++nt) {
    bf16x8 bh = *(const bf16x8*)&Wh[(nt * 64 + lane) * 8];
    bf16x8 bl = *(const bf16x8*)&Wl[(nt * 64 + lane) * 8];
    acc[nt] = MFMA(ah, bh, acc[nt]);
    acc[nt] = MFMA(ah, bl, acc[nt]);
    acc[nt] = MFMA(al, bh, acc[nt]);
  }
  int col0 = lane & 15;
#pragma unroll
  for (int nt = 0; nt < 4; ++nt) {
    float bv = bias[nt * 16 + col0];
#pragma unroll
    for (int r = 0; r < 4; ++r) {
      int node = n0w + quad * 4 + r;
      float v = acc[nt][r] + bv;
      size_t o = (size_t)node * 64 + nt * 16 + col0;
      unsigned short hi, lo; split2(v, hi, lo);
      hph[o] = hi; hpl[o] = lo;
    }
  }
}

// ---------------------------------------------------------------------------
// Merged launch 1: blocks 0..255 = bucket pass, blocks 256..610 = prep.
// The two halves touch disjoint data; branch is block-uniform.
// ---------------------------------------------------------------------------
__global__ __launch_bounds__(256) void k_build1(const int* __restrict__ eidx,
                                                int* __restrict__ gcur,
                                                int* __restrict__ payload,
                                                const float* __restrict__ W_mlp,
                                                const float* __restrict__ W_conv,
                                                const float* __restrict__ gWih,
                                                const float* __restrict__ gWhh,
                                                const float* __restrict__ b_conv,
                                                const float* __restrict__ lW_ih,
                                                const float* __restrict__ lW_hh,
                                                const float* __restrict__ W1,
                                                unsigned short* __restrict__ mlp_h,
                                                unsigned short* __restrict__ mlp_l,
                                                unsigned short* __restrict__ gw_h,
                                                unsigned short* __restrict__ gw_l,
                                                float* __restrict__ WihT,
                                                float* __restrict__ WhhT,
                                                float* __restrict__ W1T,
                                                float* __restrict__ vfold,
                                                const int* __restrict__ batch,
                                                int* __restrict__ gp,
                                                int* __restrict__ rp) {
  if (blockIdx.x < 256) {
    bucket_body(blockIdx.x, eidx, gcur, payload);
  } else {
    prepw_body((blockIdx.x - 256) * 256 + threadIdx.x,
               W_mlp, W_conv, gWih, gWhh, b_conv, lW_ih, lW_hh, W1,
               mlp_h, mlp_l, gw_h, gw_l, WihT, WhhT, W1T, vfold, batch, gp, rp);
  }
}

// ---------------------------------------------------------------------------
// Merged launch 2: blocks 0..255 = placeB, blocks 256..1279 = conv1.
// placeB consumes launch-1 bucket output; conv1 consumes launch-1 prep
// output; the two halves are mutually independent.
// ---------------------------------------------------------------------------
__global__ __launch_bounds__(256) void k_build2(const int* __restrict__ gcur,
                                                const int* __restrict__ payload,
                                                int* __restrict__ rp,
                                                int* __restrict__ srcs,
                                                const float* __restrict__ x,
                                                const unsigned short* __restrict__ mlp_h,
                                                const unsigned short* __restrict__ mlp_l,
                                                const float* __restrict__ b_mlp,
                                                unsigned short* __restrict__ hph,
                                                unsigned short* __restrict__ hpl,
                                                unsigned short* __restrict__ Aih,
                                                unsigned short* __restrict__ Ail) {
  if (blockIdx.x < 256) {
    placeB_body(blockIdx.x, gcur, payload, rp, srcs);
  } else {
    conv1_body(blockIdx.x - 256, x, mlp_h, mlp_l, b_mlp, hph, hpl, Aih, Ail);
  }
}

// ---------------------------------------------------------------------------
// Fused GRU v11 (round-11, ~45 us/step): 512 thr / 8 waves / 1 tile per
// wave, 8-deep gather batching, accumulation strictly in edge order.
// ---------------------------------------------------------------------------
__global__ __launch_bounds__(512, 4) void k_gru(const unsigned short* __restrict__ Aih,
                                                const unsigned short* __restrict__ Ail,
                                                const unsigned short* __restrict__ Hh,
                                                const unsigned short* __restrict__ Hl,
                                                const unsigned short* __restrict__ gw_h,
                                                const unsigned short* __restrict__ gw_l,
                                                const float* __restrict__ b_ih,
                                                const float* __restrict__ b_hh,
                                                const float* __restrict__ vfold,
                                                const int* __restrict__ rp,
                                                const int* __restrict__ srcs,
                                                unsigned short* __restrict__ nph,
                                                unsigned short* __restrict__ npl) {
  __shared__ unsigned short sW[2][12288];  // per buf: hi[0..6143] | lo[6144..]
  int tid = threadIdx.x;                   // 0..511
  int wave = tid >> 6, lane = tid & 63;
  int quad = lane >> 4;
  int rowA = blockIdx.x * 128 + wave * 16 + (lane & 15);  // this wave's tile row

  // ---- fused aggregate: gather S fragments for chunks 0,1 (one tile) ----
  bf16x8 fh[2], fl[2];  // [chunk]
  const size_t q8 = (size_t)(quad * 8);
  {
    int s = rp[rowA], e = rp[rowA + 1];
    int n = e - s;
    const int* sp = srcs + s;
    float acc0[8] = {}, acc1[8] = {};
    int i = 0;
    for (; i + 8 <= n; i += 8) {
      int s0 = sp[i],     s1 = sp[i + 1], s2 = sp[i + 2], s3 = sp[i + 3];
      int s4 = sp[i + 4], s5 = sp[i + 5], s6 = sp[i + 6], s7 = sp[i + 7];
      u16x8 a0 = *(const u16x8*)&Hh[(size_t)s0 * 64 + q8];
      u16x8 b0 = *(const u16x8*)&Hh[(size_t)s0 * 64 + 32 + q8];
      u16x8 a1 = *(const u16x8*)&Hh[(size_t)s1 * 64 + q8];
      u16x8 b1 = *(const u16x8*)&Hh[(size_t)s1 * 64 + 32 + q8];
      u16x8 a2 = *(const u16x8*)&Hh[(size_t)s2 * 64 + q8];
      u16x8 b2 = *(const u16x8*)&Hh[(size_t)s2 * 64 + 32 + q8];
      u16x8 a3 = *(const u16x8*)&Hh[(size_t)s3 * 64 + q8];
      u16x8 b3 = *(const u16x8*)&Hh[(size_t)s3 * 64 + 32 + q8];
      u16x8 a4 = *(const u16x8*)&Hh[(size_t)s4 * 64 + q8];
      u16x8 b4 = *(const u16x8*)&Hh[(size_t)s4 * 64 + 32 + q8];
      u16x8 a5 = *(const u16x8*)&Hh[(size_t)s5 * 64 + q8];
      u16x8 b5 = *(const u16x8*)&Hh[(size_t)s5 * 64 + 32 + q8];
      u16x8 a6 = *(const u16x8*)&Hh[(size_t)s6 * 64 + q8];
      u16x8 b6 = *(const u16x8*)&Hh[(size_t)s6 * 64 + 32 + q8];
      u16x8 a7 = *(const u16x8*)&Hh[(size_t)s7 * 64 + q8];
      u16x8 b7 = *(const u16x8*)&Hh[(size_t)s7 * 64 + 32 + q8];
#pragma unroll
      for (int j = 0; j < 8; ++j) { acc0[j] += bf16_tof(a0[j]); acc1[j] += bf16_tof(b0[j]); }
#pragma unroll
      for (int j = 0; j < 8; ++j) { acc0[j] += bf16_tof(a1[j]); acc1[j] += bf16_tof(b1[j]); }
#pragma unroll
      for (int j = 0; j < 8; ++j) { acc0[j] += bf16_tof(a2[j]); acc1[j] += bf16_tof(b2[j]); }
#pragma unroll
      for (int j = 0; j < 8; ++j) { acc0[j] += bf16_tof(a3[j]); acc1[j] += bf16_tof(b3[j]); }
#pragma unroll
      for (int j = 0; j < 8; ++j) { acc0[j] += bf16_tof(a4[j]); acc1[j] += bf16_tof(b4[j]); }
#pragma unroll
      for (int j = 0; j < 8; ++j) { acc0[j] += bf16_tof(a5[j]); acc1[j] += bf16_tof(b5[j]); }
#pragma unroll
      for (int j = 0; j < 8; ++j) { acc0[j] += bf16_tof(a6[j]); acc1[j] += bf16_tof(b6[j]); }
#pragma unroll
      for (int j = 0; j < 8; ++j) { acc0[j] += bf16_tof(a7[j]); acc1[j] += bf16_tof(b7[j]); }
    }
    for (; i + 4 <= n; i += 4) {
      int s0 = sp[i], s1 = sp[i + 1], s2 = sp[i + 2], s3 = sp[i + 3];
      u16x8 a0 = *(const u16x8*)&Hh[(size_t)s0 * 64 + q8];
      u16x8 b0 = *(const u16x8*)&Hh[(size_t)s0 * 64 + 32 + q8];
      u16x8 a1 = *(const u16x8*)&Hh[(size_t)s1 * 64 + q8];
      u16x8 b1 = *(const u16x8*)&Hh[(size_t)s1 * 64 + 32 + q8];
      u16x8 a2 = *(const u16x8*)&Hh[(size_t)s2 * 64 + q8];
      u16x8 b2 = *(const u16x8*)&Hh[(size_t)s2 * 64 + 32 + q8];
      u16x8 a3 = *(const u16x8*)&Hh[(size_t)s3 * 64 + q8];
      u16x8 b3 = *(const u16x8*)&Hh[(size_t)s3 * 64 + 32 + q8];
#pragma unroll
      for (int j = 0; j < 8; ++j) { acc0[j] += bf16_tof(a0[j]); acc1[j] += bf16_tof(b0[j]); }
#pragma unroll
      for (int j = 0; j < 8; ++j) { acc0[j] += bf16_tof(a1[j]); acc1[j] += bf16_tof(b1[j]); }
#pragma unroll
      for (int j = 0; j < 8; ++j) { acc0[j] += bf16_tof(a2[j]); acc1[j] += bf16_tof(b2[j]); }
#pragma unroll
      for (int j = 0; j < 8; ++j) { acc0[j] += bf16_tof(a3[j]); acc1[j] += bf16_tof(b3[j]); }
    }
    for (; i < n; ++i) {
      int src = sp[i];
      u16x8 v0 = *(const u16x8*)&Hh[(size_t)src * 64 + q8];
      u16x8 v1 = *(const u16x8*)&Hh[(size_t)src * 64 + 32 + q8];
#pragma unroll
      for (int j = 0; j < 8; ++j) {
        acc0[j] += bf16_tof(v0[j]);
        acc1[j] += bf16_tof(v1[j]);
      }
    }
#pragma unroll
    for (int j = 0; j < 8; ++j) {
      unsigned short hi, lo;
      split2(acc0[j], hi, lo);
      fh[0][j] = (short)hi; fl[0][j] = (short)lo;
      split2(acc1[j], hi, lo);
      fh[1][j] = (short)hi; fl[1][j] = (short)lo;
    }
  }

  f32x4 acc[12] = {};     // gi r,z,n (gh r,z folded into 0..7)
  f32x4 aN[4] = {};       // gh n-gate

  // prologue: weights chunk 0 (768 16B-vectors staged by 512 threads)
  bf16x8 gvh0, gvl0, gvh1, gvl1;
  const bool two = (tid < 256);
  gvh0 = *(const bf16x8*)&gw_h[tid * 8];
  gvl0 = *(const bf16x8*)&gw_l[tid * 8];
  if (two) {
    gvh1 = *(const bf16x8*)&gw_h[(tid + 512) * 8];
    gvl1 = *(const bf16x8*)&gw_l[(tid + 512) * 8];
  }
  *(bf16x8*)&sW[0][tid * 8] = gvh0;
  *(bf16x8*)&sW[0][6144 + tid * 8] = gvl0;
  if (two) {
    *(bf16x8*)&sW[0][(tid + 512) * 8] = gvh1;
    *(bf16x8*)&sW[0][6144 + (tid + 512) * 8] = gvl1;
  }
  __syncthreads();

#pragma unroll
  for (int c = 0; c < 5; ++c) {
    const int buf = c & 1;
    if (c < 4) {  // prefetch chunk c+1 weights
      gvh0 = *(const bf16x8*)&gw_h[(c + 1) * 6144 + tid * 8];
      gvl0 = *(const bf16x8*)&gw_l[(c + 1) * 6144 + tid * 8];
      if (two) {
        gvh1 = *(const bf16x8*)&gw_h[(c + 1) * 6144 + (tid + 512) * 8];
        gvl1 = *(const bf16x8*)&gw_l[(c + 1) * 6144 + (tid + 512) * 8];
      }
    }
    // A fragment
    bf16x8 ah, al;
    if (c < 2) {            // gathered S fragments (registers)
      ah = fh[c]; al = fl[c];
    } else if (c == 2) {    // x columns from conv1 prep
      size_t b0 = (size_t)rowA * 96 + 64 + quad * 8;
      ah = *(const bf16x8*)&Aih[b0]; al = *(const bf16x8*)&Ail[b0];
    } else {                // h planes (Whh chunks)
      size_t b0 = (size_t)rowA * 64 + (c - 3) * 32 + quad * 8;
      ah = *(const bf16x8*)&Hh[b0]; al = *(const bf16x8*)&Hl[b0];
    }
    const unsigned short* sw = sW[buf];
#pragma unroll
    for (int nt = 0; nt < 12; ++nt) {
      bf16x8 bh = *(const bf16x8*)&sw[(nt * 64 + lane) * 8];
      bf16x8 bl = *(const bf16x8*)&sw[6144 + (nt * 64 + lane) * 8];
      if (c < 3 || nt < 8) {
        acc[nt] = MFMA(ah, bh, acc[nt]);
        acc[nt] = MFMA(ah, bl, acc[nt]);
        acc[nt] = MFMA(al, bh, acc[nt]);
      } else {
        aN[nt - 8] = MFMA(ah, bh, aN[nt - 8]);
        aN[nt - 8] = MFMA(ah, bl, aN[nt - 8]);
        aN[nt - 8] = MFMA(al, bh, aN[nt - 8]);
      }
    }
    if (c < 4) {
      *(bf16x8*)&sW[1 - buf][tid * 8] = gvh0;
      *(bf16x8*)&sW[1 - buf][6144 + tid * 8] = gvl0;
      if (two) {
        *(bf16x8*)&sW[1 - buf][(tid + 512) * 8] = gvh1;
        *(bf16x8*)&sW[1 - buf][6144 + (tid + 512) * 8] = gvl1;
      }
    }
    __syncthreads();
  }

  // epilogue: GRU nonlinearity + deg*vfold (folded conv bias) + plane store
  int col0 = lane & 15;
  int nb = blockIdx.x * 128 + wave * 16;
#pragma unroll
  for (int r = 0; r < 4; ++r) {
    int node = nb + quad * 4 + r;
    float degf = (float)(rp[node + 1] - rp[node]);
#pragma unroll
    for (int nt = 0; nt < 4; ++nt) {
      int g = nt * 16 + col0;
      size_t o = (size_t)node * 64 + g;
      float br  = b_ih[g] + b_hh[g] + degf * vfold[g];
      float bz  = b_ih[64 + g] + b_hh[64 + g] + degf * vfold[64 + g];
      float bin = b_ih[128 + g] + degf * vfold[128 + g];
      float bhn = b_hh[128 + g];
      float gr = acc[nt][r];
      float gz = acc[nt + 4][r];
      float gn = acc[nt + 8][r];
      float hn = aN[nt][r];
      float rr = sigf(gr + br);
      float zz = sigf(gz + bz);
      float nn = tanhf(gn + bin + rr * (hn + bhn));
      float h_old = recon(Hh[o], Hl[o]);
      float hv = (1.f - zz) * nn + zz * h_old;
      unsigned short hi, lo; split2(hv, hi, lo);
      nph[o] = hi; npl[o] = lo;
    }
  }
}

// ---------------------------------------------------------------------------
// Fused Set2Set (round-8, measured 56.7 us): all 3 iterations + head, one
// launch, 512 threads, h rows staged to f32 in dynamic LDS, per-wave emax.
// At its dependent-chain floor for this structure -- left untouched.
// ---------------------------------------------------------------------------
constexpr int LCAP = 448;
constexpr int LPAD = 68;    // padded hL row stride in floats
constexpr int S2T  = 512;   // threads (8 waves)
__global__ __launch_bounds__(S2T) void k_s2s(const unsigned short* __restrict__ hph,
                                             const unsigned short* __restrict__ hpl,
                                             const int* __restrict__ gp,
                                             const float* __restrict__ WihT,
                                             const float* __restrict__ WhhT,
                                             const float* __restrict__ b_ih,
                                             const float* __restrict__ b_hh,
                                             const float* __restrict__ W1T,
                                             const float* __restrict__ b1,
                                             const float* __restrict__ W2,
                                             const float* __restrict__ b2,
                                             float* __restrict__ outp) {
  extern __shared__ float hL[];   // [LCAP][LPAD] f32 staged h
  int g = blockIdx.x;
  int t = threadIdx.x;
  int w = t >> 6, lane = t & 63;
  __shared__ float qstar_s[128];  // [q | r] carried across iterations
  __shared__ float hs[64], cs[64], gates[256];
  __shared__ float eL[LCAP];
  __shared__ float partial[8][64];
  __shared__ float asum_p[8];
  __shared__ float l4[4];
  __shared__ float hid[64];

  if (t < 128) qstar_s[t] = 0.f;
  if (t < 64) { hs[t] = 0.f; cs[t] = 0.f; }
  int s = gp[g], e = gp[g + 1];
  int cnt = e - s;

  // ---- stage h rows once: hL[nd*LPAD+col] = recon(hph, hpl) ----
  {
    int total = cnt * 64;
    for (int j = t * 4; j < total; j += S2T * 4) {
      int nd = j >> 6, col = j & 63;
      ushort4 hh = *(const ushort4*)&hph[(size_t)s * 64 + j];
      ushort4 ll = *(const ushort4*)&hpl[(size_t)s * 64 + j];
      float4 v;
      v.x = recon(hh.x, ll.x); v.y = recon(hh.y, ll.y);
      v.z = recon(hh.z, ll.z); v.w = recon(hh.w, ll.w);
      *(float4*)&hL[nd * LPAD + col] = v;
    }
  }

  for (int it = 0; it < 3; ++it) {
    __syncthreads();   // state + staged hL visible

    // ---- LSTM cell (first 4 waves) ----
    if (t < 256) {
      float acc = b_ih[t] + b_hh[t];
      for (int k = 0; k < 128; ++k) acc = fmaf(WihT[k * 256 + t], qstar_s[k], acc);
      for (int k = 0; k < 64; ++k)  acc = fmaf(WhhT[k * 256 + t], hs[k], acc);
      gates[t] = acc;
    }
    __syncthreads();
    if (t < 64) {
      float ig = sigf(gates[t]),        fg = sigf(gates[64 + t]);
      float gg = tanhf(gates[128 + t]), og = sigf(gates[192 + t]);
      float c = fg * cs[t] + ig * gg;
      float q = og * tanhf(c);
      cs[t] = c;
      hs[t] = q;
      qstar_s[t] = q;
    }
    __syncthreads();

    // ---- attention phase A: e_i = h[i].q ----
    int c4 = (lane & 15) * 4;
    float4 qv = {qstar_s[c4], qstar_s[c4 + 1], qstar_s[c4 + 2], qstar_s[c4 + 3]};
    for (int i0 = s + w * 4; i0 < e; i0 += 32) {
      int node = i0 + (lane >> 4);
      float p = 0.f;
      if (node < e) {
        float4 hv = *(const float4*)&hL[(node - s) * LPAD + c4];
        p = hv.x * qv.x + hv.y * qv.y + hv.z * qv.z + hv.w * qv.w;
      }
      p += __shfl_xor(p, 1); p += __shfl_xor(p, 2);
      p += __shfl_xor(p, 4); p += __shfl_xor(p, 8);
      if (node < e && (lane & 15) == 0) eL[node - s] = p;
    }
    __syncthreads();

    // ---- phase B: segment max, per-wave (order-invariant) ----
    float m = -INFINITY;
    for (int i = lane; i < cnt; i += 64) m = fmaxf(m, eL[i]);
#pragma unroll
    for (int o = 32; o >= 1; o >>= 1) m = fmaxf(m, __shfl_xor(m, o));
    float emax = isfinite(m) ? m : 0.f;

    // ---- phase C: softmax-weighted feature sum ----
    float acc = 0.f, asum = 0.f;
    for (int i = s + w; i < e; i += 8) {
      float a = expf(eL[i - s] - emax);
      asum += a;
      acc = fmaf(a, hL[(i - s) * LPAD + lane], acc);
    }
    partial[w][lane] = acc;
    if (lane == 0) asum_p[w] = asum;
    __syncthreads();
    if (t < 64) {
      float r = 0.f, as = 0.f;
      for (int q = 0; q < 8; ++q) { r += partial[q][t]; as += asum_p[q]; }
      float rv = (cnt > 0) ? r / fmaxf(as, 1e-16f) : 0.f;
      qstar_s[64 + t] = rv;
    }
  }
  __syncthreads();

  // ---- head ----
  if (t < 64) {
    float a1 = b1[t];
    for (int k = 0; k < 64; ++k)   a1 = fmaf(W1T[k * 64 + t], qstar_s[k], a1);
    for (int k = 64; k < 128; ++k) a1 = fmaf(W1T[k * 64 + t], qstar_s[k], a1);
    hid[t] = fmaxf(a1, 0.f);
  }
  __syncthreads();
  if (t < 4) {
    float lg = b2[t];
    for (int d = 0; d < 64; ++d) lg = fmaf(W2[t * 64 + d], hid[d], lg);
    l4[t] = lg;
  }
  __syncthreads();
  if (t < 4) {
    float mx = fmaxf(fmaxf(l4[0], l4[1]), fmaxf(l4[2], l4[3]));
    float ssum = expf(l4[0] - mx) + expf(l4[1] - mx) + expf(l4[2] - mx) + expf(l4[3] - mx);
    outp[g * 4 + t] = l4[t] - mx - logf(ssum);
  }
}

// ---------------------------------------------------------------------------
extern "C" void kernel_launch(void* const* d_in, const int* in_sizes, int n_in,
                              void* d_out, int out_size, void* d_ws, size_t ws_size,
                              hipStream_t stream) {
  const float* x        = (const float*)d_in[0];
  const int*   eidx     = (const int*)d_in[1];
  const int*   batch    = (const int*)d_in[2];
  const float* W_mlp    = (const float*)d_in[3];
  const float* b_mlp    = (const float*)d_in[4];
  const float* W_conv   = (const float*)d_in[5];
  const float* b_conv   = (const float*)d_in[6];
  const float* gW_ih    = (const float*)d_in[7];
  const float* gW_hh    = (const float*)d_in[8];
  const float* gb_ih    = (const float*)d_in[9];
  const float* gb_hh    = (const float*)d_in[10];
  const float* lW_ih    = (const float*)d_in[11];
  const float* lW_hh    = (const float*)d_in[12];
  const float* lb_ih    = (const float*)d_in[13];
  const float* lb_hh    = (const float*)d_in[14];
  const float* W1       = (const float*)d_in[15];
  const float* b1       = (const float*)d_in[16];
  const float* W2       = (const float*)d_in[17];
  const float* b2       = (const float*)d_in[18];
  float* outp = (float*)d_out;

  // ---- workspace layout ----
  char* ws = (char*)d_ws;
  size_t off = 0;
  auto alloc = [&](size_t bytes) { size_t r = off; off = (off + bytes + 255) & ~(size_t)255; return r; };
  unsigned short* hpAh = (unsigned short*)(ws + alloc((size_t)Nn * 64 * 2));
  unsigned short* hpAl = (unsigned short*)(ws + alloc((size_t)Nn * 64 * 2));
  unsigned short* hpBh = (unsigned short*)(ws + alloc((size_t)Nn * 64 * 2));
  unsigned short* hpBl = (unsigned short*)(ws + alloc((size_t)Nn * 64 * 2));
  unsigned short* Aih  = (unsigned short*)(ws + alloc((size_t)Nn * 96 * 2));
  unsigned short* Ail  = (unsigned short*)(ws + alloc((size_t)Nn * 96 * 2));
  int*   rp    = (int*)(ws + alloc((size_t)(Nn + 1) * 4));
  int*   srcs  = (int*)(ws + alloc((size_t)Ne * 4));
  int*   gcur  = (int*)(ws + alloc((size_t)NB * 16 * 4));
  int*   payload = (int*)(ws + alloc((size_t)NB * BCAP * 4));
  int*   gp    = (int*)(ws + alloc((size_t)(Bg + 1) * 4));
  float* WihT  = (float*)(ws + alloc((size_t)128 * 256 * 4));
  float* WhhT  = (float*)(ws + alloc((size_t)64 * 256 * 4));
  float* W1T   = (float*)(ws + alloc((size_t)128 * 64 * 4));
  float* vfold = (float*)(ws + alloc(192 * 4));
  unsigned short* mlp_h = (unsigned short*)(ws + alloc(2048 * 2));
  unsigned short* mlp_l = (unsigned short*)(ws + alloc(2048 * 2));
  unsigned short* gw_h  = (unsigned short*)(ws + alloc(30720 * 2));
  unsigned short* gw_l  = (unsigned short*)(ws + alloc(30720 * 2));
  (void)in_sizes; (void)n_in; (void)out_size; (void)ws_size;

  hipMemsetAsync(gcur, 0, (size_t)NB * 16 * 4, stream);

  // Merged launch 1: bucket pass (blocks 0..255) || prep (blocks 256..610)
  k_build1<<<256 + 355, 256, 0, stream>>>(eidx, gcur, payload,
                                          W_mlp, W_conv, gW_ih, gW_hh, b_conv,
                                          lW_ih, lW_hh, W1,
                                          mlp_h, mlp_l, gw_h, gw_l,
                                          WihT, WhhT, W1T, vfold, batch, gp, rp);

  // Merged launch 2: placeB (blocks 0..255) || conv1 (blocks 256..1279)
  k_build2<<<256 + Nn / 64, 256, 0, stream>>>(gcur, payload, rp, srcs,
                                              x, mlp_h, mlp_l, b_mlp,
                                              hpAh, hpAl, Aih, Ail);

  unsigned short *cph = hpAh, *cpl = hpAl, *nph = hpBh, *npl = hpBl;
  for (int step = 0; step < 2; ++step) {
    k_gru<<<Nn / 128, 512, 0, stream>>>(Aih, Ail, cph, cpl, gw_h, gw_l,
                                        gb_ih, gb_hh, vfold, rp, srcs, nph, npl);
    unsigned short* tu;
    tu = cph; cph = nph; nph = tu;
    tu = cpl; cpl = npl; npl = tu;
  }

  // Set2Set: all 3 iterations + head, one launch, 512 threads,
  // 448*68*4 = 121856 B dynamic LDS (padded rows)
  const size_t dynLds = (size_t)LCAP * LPAD * sizeof(float);
  static bool attr_set = false;
  if (!attr_set) {
    hipFuncSetAttribute((const void*)k_s2s,
                        hipFuncAttributeMaxDynamicSharedMemorySize,
                        (int)dynLds);
    attr_set = true;
  }
  k_s2s<<<Bg, S2T, dynLds, stream>>>(cph, cpl, gp, WihT, WhhT,
                                     lb_ih, lb_hh, W1T, b1, W2, b2, outp);
}